// Round 10
// baseline (344.352 us; speedup 1.0000x reference)
//
#include <hip/hip_runtime.h>
#include <hip/hip_bf16.h>

// Problem constants (reference: B,N1,N2,C,COUT,NS = 2,8192,8192,128,128,16)
#define BB  2
#define NN1 8192
#define NN2 8192
#define CC  128
#define SS  16

typedef unsigned short u16;
typedef unsigned int u32;
typedef short bf16x8 __attribute__((ext_vector_type(8)));
typedef float f32x4  __attribute__((ext_vector_type(4)));

__device__ __forceinline__ u16 f2bf(float f) {
  __hip_bfloat16 h = __float2bfloat16(f);      // RNE
  return *(u16*)&h;
}
__device__ __forceinline__ float bf2f(u16 u) {
  union { float f; unsigned int u; } v; v.u = ((unsigned int)u) << 16;
  return v.f;
}
__device__ __forceinline__ float bflo(u32 w) {
  union { float f; unsigned int u; } v; v.u = w << 16; return v.f;
}
__device__ __forceinline__ float bfhi(u32 w) {
  union { float f; unsigned int u; } v; v.u = w & 0xFFFF0000u; return v.f;
}
__device__ __forceinline__ float leaky(float x) { return x >= 0.0f ? x : 0.1f * x; }

// ---------------------------------------------------------------------------
// prep: convert qk_w/v_w to bf16; pack xyz -> float4{x,y,z,|p|2}; accumulate
// per-(cloud,batch) xyz moments (9 sums) for analytic GroupNorm stats.
__global__ __launch_bounds__(256)
void k_prep(const float* __restrict__ qkw, const float* __restrict__ vw,
            u16* __restrict__ oa, u16* __restrict__ ob,
            const float* __restrict__ xyz1, const float* __restrict__ xyz2,
            float4* __restrict__ px1, float4* __restrict__ px2,
            float* __restrict__ mom) {
  int bx = blockIdx.x, t = threadIdx.x;
  if (bx < 128) {
    int e = bx * 256 + t;
    if (e < 16384) oa[e] = f2bf(qkw[e]);
    else ob[e - 16384] = f2bf(vw[e - 16384]);
    return;
  }
  const float* xyz; float4* px; int e, cl;
  if (bx < 192) { e = (bx - 128) * 256 + t; xyz = xyz1; px = px1; cl = 0; }
  else          { e = (bx - 192) * 256 + t; xyz = xyz2; px = px2; cl = 1; }
  int b = e >> 13, n = e & 8191;
  float x = xyz[(b * 3 + 0) * 8192 + n];
  float y = xyz[(b * 3 + 1) * 8192 + n];
  float z = xyz[(b * 3 + 2) * 8192 + n];
  px[e] = make_float4(x, y, z, x * x + y * y + z * z);
  float s0 = x, s1 = y, s2 = z, s3 = x * x, s4 = y * y, s5 = z * z;
  float s6 = x * y, s7 = x * z, s8 = y * z;
#pragma unroll
  for (int o = 1; o < 64; o <<= 1) {
    s0 += __shfl_xor(s0, o); s1 += __shfl_xor(s1, o); s2 += __shfl_xor(s2, o);
    s3 += __shfl_xor(s3, o); s4 += __shfl_xor(s4, o); s5 += __shfl_xor(s5, o);
    s6 += __shfl_xor(s6, o); s7 += __shfl_xor(s7, o); s8 += __shfl_xor(s8, o);
  }
  if ((t & 63) == 0) {
    float* mp = mom + (cl * 2 + b) * 9;
    atomicAdd(&mp[0], s0); atomicAdd(&mp[1], s1); atomicAdd(&mp[2], s2);
    atomicAdd(&mp[3], s3); atomicAdd(&mp[4], s4); atomicAdd(&mp[5], s5);
    atomicAdd(&mp[6], s6); atomicAdd(&mp[7], s7); atomicAdd(&mp[8], s8);
  }
}

// Analytic GN stats for pos-enc.
__global__ __launch_bounds__(512)
void k_gnstats(const float* __restrict__ mom, const float* __restrict__ pw,
               const float* __restrict__ pb, float2* __restrict__ gnp) {
  int t = threadIdx.x;                 // 512: cloud(2) x b(2) x c(128)
  int cl = t >> 8, b = (t >> 7) & 1, c = t & 127;
  const float* M = mom + (cl * 2 + b) * 9;
  const float inv = 1.0f / 8192.0f;
  float mx = M[0] * inv, my = M[1] * inv, mz = M[2] * inv;
  float sxx = M[3] * inv, syy = M[4] * inv, szz = M[5] * inv;
  float sxy = M[6] * inv, sxz = M[7] * inv, syz = M[8] * inv;
  float w0 = pw[c * 3], w1 = pw[c * 3 + 1], w2 = pw[c * 3 + 2], bc = pb[c];
  float wm = w0 * mx + w1 * my + w2 * mz;
  float Eh = wm + bc;
  float wSw = w0 * w0 * sxx + w1 * w1 * syy + w2 * w2 * szz
            + 2.0f * (w0 * w1 * sxy + w0 * w2 * sxz + w1 * w2 * syz);
  float Eh2 = wSw + 2.0f * bc * wm + bc * bc;
#pragma unroll
  for (int o = 1; o < 16; o <<= 1) { Eh += __shfl_xor(Eh, o); Eh2 += __shfl_xor(Eh2, o); }
  if ((c & 15) == 0) {
    float mu = Eh * 0.0625f;
    float var = Eh2 * 0.0625f - mu * mu;
    gnp[cl * 16 + b * 8 + (c >> 4)] = make_float2(mu, rsqrtf(var + 1e-5f));
  }
}

// Fused pos-enc (single pass, both clouds): featp = feat + leaky(GN(W.xyz+b)).
// cloud1 -> f32, cloud2 -> bf16.
__global__ __launch_bounds__(256)
void k_posenc(const float* __restrict__ xyz1, const float* __restrict__ xyz2,
              const float* __restrict__ feat1, const float* __restrict__ feat2,
              const float* __restrict__ pw, const float* __restrict__ pb,
              const float* __restrict__ gam, const float* __restrict__ bet,
              const float2* __restrict__ gnp,
              float* __restrict__ outf, u16* __restrict__ outb) {
  int t = threadIdx.x, bx = blockIdx.x;
  const float* xyz; const float* feat; const float2* gp; int asbf;
  if (bx < 1024) { xyz = xyz1; feat = feat1; gp = gnp;      asbf = 0; }
  else           { xyz = xyz2; feat = feat2; gp = gnp + 16; asbf = 1; bx -= 1024; }
  const int N = 8192;
  int b = bx / 512, n0 = (bx % 512) * 16;
  __shared__ float T[128][17];
  for (int it = 0; it < 8; ++it) {
    int j = t & 15, c = it * 16 + (t >> 4);
    T[c][j] = feat[(b * 128 + c) * N + n0 + j];
  }
  int c = t & 127;
  float w0 = pw[c * 3], w1 = pw[c * 3 + 1], w2 = pw[c * 3 + 2], bc = pb[c];
  float2 g2 = gp[b * 8 + (c >> 4)];
  float gm = gam[c], b2 = bet[c];
  __syncthreads();
  for (int it = 0; it < 8; ++it) {
    int j = it * 2 + (t >> 7);
    int n = n0 + j;
    float xs = xyz[(b * 3 + 0) * N + n];
    float ys = xyz[(b * 3 + 1) * N + n];
    float zs = xyz[(b * 3 + 2) * N + n];
    float hv = w0 * xs + w1 * ys + w2 * zs + bc;
    float xo = (hv - g2.x) * g2.y * gm + b2;
    float r = T[c][j] + leaky(xo);
    if (asbf) outb[(size_t)(b * N + n) * 128 + c] = f2bf(r);
    else      outf[(size_t)(b * N + n) * 128 + c] = r;
  }
}

// ---------------------------------------------------------------------------
// KNN. Packed key: (f32 distance^2 bits & 0xFFFFE000) | index (13 bits).

__device__ __forceinline__ void sort16(u32 (&e)[16]) {
#pragma unroll
  for (int k = 2; k <= 16; k <<= 1) {
#pragma unroll
    for (int j = k >> 1; j > 0; j >>= 1) {
#pragma unroll
      for (int i = 0; i < 16; ++i) {
        int l = i ^ j;
        if (l > i) {
          bool up = ((i & k) == 0);
          u32 x = e[i], y = e[l];
          u32 mn = x < y ? x : y;
          u32 mx = x < y ? y : x;
          e[i] = up ? mn : mx;
          e[l] = up ? mx : mn;
        }
      }
    }
  }
}

__device__ __forceinline__ void merge16(u32 (&A)[16], const u32 (&S)[16]) {
  u32 t[16];
#pragma unroll
  for (int i = 0; i < 16; ++i) {
    u32 a = A[i], s = S[15 - i];
    t[i] = a < s ? a : s;
  }
#pragma unroll
  for (int j = 8; j > 0; j >>= 1) {
#pragma unroll
    for (int i = 0; i < 16; ++i) {
      if ((i & j) == 0) {
        u32 x = t[i], y = t[i | j];
        t[i] = x < y ? x : y;
        t[i | j] = x < y ? y : x;
      }
    }
  }
#pragma unroll
  for (int i = 0; i < 16; ++i) A[i] = t[i];
}

// Stage 1: 4 waves/block, wave = one 512-candidate slice, lane = query.
__global__ __launch_bounds__(256, 8)
void k_knn1(const float4* __restrict__ px1, const float4* __restrict__ px2,
            u32* __restrict__ out) {
  int bx = blockIdx.x;                  // 1024 = b(2) * g(128) * sb(4)
  int w = threadIdx.x >> 6, l = threadIdx.x & 63;
  int sb = bx & 3, g = (bx >> 2) & 127, b = bx >> 9;
  int slice = sb * 4 + w;
  int q = g * 64 + l;
  float4 qv = px1[b * NN1 + q];
  u32 A[16];
#pragma unroll
  for (int i = 0; i < 16; ++i) A[i] = 0xFFFFFFFFu;
  const float4* cp = px2 + b * NN2 + slice * 512;
  for (int it = 0; it < 32; ++it) {
    u32 S[16];
#pragma unroll
    for (int kk = 0; kk < 16; ++kk) {
      float4 c = cp[it * 16 + kk];      // uniform -> scalar load
      float m = fmaf(qv.x, c.x, fmaf(qv.y, c.y, qv.z * c.z));
      float d = fmaf(-2.0f, m, qv.w + c.w);
      d = fmaxf(d, 0.0f);
      S[kk] = (__float_as_uint(d) & 0xFFFFE000u) |
              (u32)(slice * 512 + it * 16 + kk);
    }
    sort16(S);
    merge16(A, S);
  }
  u32* op = out + ((b * NN1 + q) * 16 + slice) * 16;
#pragma unroll
  for (int i = 0; i < 4; ++i)
    *(uint4*)&op[i * 4] = make_uint4(A[i * 4], A[i * 4 + 1], A[i * 4 + 2], A[i * 4 + 3]);
}

// Stage 2: one thread per query merges 16 sorted lists -> indices.
__global__ __launch_bounds__(256)
void k_knn2(const u32* __restrict__ in, int* __restrict__ idxout) {
  int e = blockIdx.x * 256 + threadIdx.x;
  const u32* p = in + (size_t)e * 256;
  u32 A[16];
#pragma unroll
  for (int i = 0; i < 4; ++i) {
    uint4 v = *(const uint4*)&p[i * 4];
    A[i * 4] = v.x; A[i * 4 + 1] = v.y; A[i * 4 + 2] = v.z; A[i * 4 + 3] = v.w;
  }
  for (int s = 1; s < 16; ++s) {
    u32 S[16];
#pragma unroll
    for (int i = 0; i < 4; ++i) {
      uint4 v = *(const uint4*)&p[s * 16 + i * 4];
      S[i * 4] = v.x; S[i * 4 + 1] = v.y; S[i * 4 + 2] = v.z; S[i * 4 + 3] = v.w;
    }
    merge16(A, S);
  }
  int* op = idxout + e * 16;
#pragma unroll
  for (int i = 0; i < 4; ++i) {
    int4 o = make_int4((int)(A[i * 4] & 8191u), (int)(A[i * 4 + 1] & 8191u),
                       (int)(A[i * 4 + 2] & 8191u), (int)(A[i * 4 + 3] & 8191u));
    *(int4*)&op[i * 4] = o;
  }
}

// ---------------------------------------------------------------------------
// Fused attention: wave-local, 2 points per wave, no f2 LDS staging; encoder
// params + f1 in small LDS; f2 read directly from global (L2-resident with
// XCD swizzle). (256,6): VGPR budget ~85 >= natural 80 -> no spill, 6 waves/EU.
__device__ __forceinline__ float4 ld_enc(const float* encS, int e, int c) {
  int xe = e ^ ((c >> 3) & 3);
  return *(const float4*)&encS[c * 16 + xe * 4];
}

__global__ __launch_bounds__(256, 6)
void k_attn(const float4* __restrict__ px1, const float4* __restrict__ px2,
            const float* __restrict__ f1p, const u16* __restrict__ f2p,
            const int* __restrict__ idxb,
            const u16* __restrict__ wq, const u16* __restrict__ wvm,
            const float* __restrict__ eqw, const float* __restrict__ eqb,
            const float* __restrict__ ekw, const float* __restrict__ ekb,
            const float* __restrict__ ev1w, const float* __restrict__ ev1b,
            const float* __restrict__ ev2w, const float* __restrict__ ev2b,
            float* __restrict__ outp) {
  const int t = threadIdx.x;
  // XCD-aware bijective swizzle: grid 2048 (% 8 == 0). Blocks with the same
  // (blockIdx % 8) land on one XCD; give each XCD a contiguous point range.
  const int bx = ((blockIdx.x & 7) << 8) | (blockIdx.x >> 3);
  const int b = bx >> 10;              // 1024 work-ids per batch
  const int base8 = (bx & 1023) * 8;   // 8 points per block (2 per wave)
  const int w = t >> 6, l = t & 63, l15 = l & 15, l4 = l >> 4;

  __shared__ float encS[128 * 16];     // 8 KB, XOR-interleaved
  __shared__ float f1s[8 * 132];       // 4.2 KB

  // stage encoder params + f1 rows
  for (int i = t; i < 512; i += 256) {
    int e = i >> 7, c = i & 127;
    const float* wsrc = (e == 0) ? eqw : (e == 1) ? ekw : (e == 2) ? ev1w : ev2w;
    const float* bsrc = (e == 0) ? eqb : (e == 1) ? ekb : (e == 2) ? ev1b : ev2b;
    int xe = e ^ ((c >> 3) & 3);
    float* dst = &encS[c * 16 + xe * 4];
    dst[0] = wsrc[c * 3]; dst[1] = wsrc[c * 3 + 1];
    dst[2] = wsrc[c * 3 + 2]; dst[3] = bsrc[c];
  }
  for (int i = t; i < 1024; i += 256) {
    int p = i >> 7, c = i & 127;
    f1s[p * 132 + c] = f1p[(size_t)(b * NN1 + base8 + p) * 128 + c];
  }

  // per-lane neighbor indices + relative coords (sample = l15)
  const int pt0 = base8 + w * 2, pt1 = pt0 + 1;
  const int j0 = idxb[(b * NN1 + pt0) * 16 + l15];
  const int j1 = idxb[(b * NN1 + pt1) * 16 + l15];
  float4 qc0 = px1[b * NN1 + pt0];
  float4 qc1 = px1[b * NN1 + pt1];
  float4 cc0 = px2[b * NN2 + j0];
  float4 cc1 = px2[b * NN2 + j1];
  float r0[2], r1[2], r2[2];
  r0[0] = cc0.x - qc0.x; r1[0] = cc0.y - qc0.y; r2[0] = cc0.z - qc0.z;
  r0[1] = cc1.x - qc1.x; r1[1] = cc1.y - qc1.y; r2[1] = cc1.z - qc1.z;

  const u16* row0 = f2p + (size_t)(b * NN2 + j0) * 128;
  const u16* row1 = f2p + (size_t)(b * NN2 + j1) * 128;
  __syncthreads();

  // ---- build bq fragments: qin = f1 * leaky(eq.r + b), B-layout ----
  bf16x8 bq[2][4];
#pragma unroll
  for (int ks = 0; ks < 4; ++ks) {
#pragma unroll
    for (int j = 0; j < 8; ++j) {
      int c = ks * 32 + l4 * 8 + j;
      float4 ew = ld_enc(encS, 0, c);
      float f10 = f1s[(w * 2 + 0) * 132 + c];
      float f11 = f1s[(w * 2 + 1) * 132 + c];
      float e0 = leaky(ew.x * r0[0] + ew.y * r1[0] + ew.z * r2[0] + ew.w);
      float e1 = leaky(ew.x * r0[1] + ew.y * r1[1] + ew.z * r2[1] + ew.w);
      bq[0][ks][j] = (short)f2bf(f10 * e0);
      bq[1][ks][j] = (short)f2bf(f11 * e1);
    }
  }

  // ---- GEMM1 (q = Wq @ qin) interleaved with attention dot per mt;
  //      kd rolling 2-deep prefetch ----
  float dp0 = 0.0f, dp1 = 0.0f;
  uint2 kc0 = *(const uint2*)(row0 + l4 * 4);
  uint2 kc1 = *(const uint2*)(row1 + l4 * 4);
#pragma unroll
  for (int mt = 0; mt < 8; ++mt) {
    uint2 kn0 = kc0, kn1 = kc1;
    if (mt < 7) {
      kn0 = *(const uint2*)(row0 + (mt + 1) * 16 + l4 * 4);
      kn1 = *(const uint2*)(row1 + (mt + 1) * 16 + l4 * 4);
    }
    f32x4 a0 = (f32x4){0.f, 0.f, 0.f, 0.f};
    f32x4 a1 = (f32x4){0.f, 0.f, 0.f, 0.f};
#pragma unroll
    for (int ks = 0; ks < 4; ++ks) {
      bf16x8 af = *(const bf16x8*)&wq[(mt * 16 + l15) * 128 + ks * 32 + l4 * 8];
      a0 = __builtin_amdgcn_mfma_f32_16x16x32_bf16(af, bq[0][ks], a0, 0, 0, 0);
      a1 = __builtin_amdgcn_mfma_f32_16x16x32_bf16(af, bq[1][ks], a1, 0, 0, 0);
    }
    float f2v0[4] = { bflo(kc0.x), bfhi(kc0.x), bflo(kc0.y), bfhi(kc0.y) };
    float f2v1[4] = { bflo(kc1.x), bfhi(kc1.x), bflo(kc1.y), bfhi(kc1.y) };
#pragma unroll
    for (int r = 0; r < 4; ++r) {
      int c = mt * 16 + l4 * 4 + r;
      float4 ew = ld_enc(encS, 1, c);
      float ek0 = leaky(ew.x * r0[0] + ew.y * r1[0] + ew.z * r2[0] + ew.w);
      float ek1 = leaky(ew.x * r0[1] + ew.y * r1[1] + ew.z * r2[1] + ew.w);
      dp0 += a0[r] * (f2v0[r] * ek0);
      dp1 += a1[r] * (f2v1[r] * ek1);
    }
    kc0 = kn0; kc1 = kn1;
  }

  // V-path gather (B-layout fragments), issued before softmax to hide latency
  bf16x8 fB[2][4];
#pragma unroll
  for (int ks = 0; ks < 4; ++ks) {
    fB[0][ks] = *(const bf16x8*)(row0 + ks * 32 + l4 * 8);
    fB[1][ks] = *(const bf16x8*)(row1 + ks * 32 + l4 * 8);
  }

  // reduce dot over l4 groups, then 16-lane softmax
  dp0 += __shfl_xor(dp0, 16); dp0 += __shfl_xor(dp0, 32);
  dp1 += __shfl_xor(dp1, 16); dp1 += __shfl_xor(dp1, 32);
  float aw0, aw1;
  {
    float x = dp0 * 0.08838834764831845f;
    float m = x;
#pragma unroll
    for (int o = 1; o < 16; o <<= 1) m = fmaxf(m, __shfl_xor(m, o));
    float e = __expf(x - m);
    float s = e;
#pragma unroll
    for (int o = 1; o < 16; o <<= 1) s += __shfl_xor(s, o);
    aw0 = e / s;
  }
  {
    float x = dp1 * 0.08838834764831845f;
    float m = x;
#pragma unroll
    for (int o = 1; o < 16; o <<= 1) m = fmaxf(m, __shfl_xor(m, o));
    float e = __expf(x - m);
    float s = e;
#pragma unroll
    for (int o = 1; o < 16; o <<= 1) s += __shfl_xor(s, o);
    aw1 = e / s;
  }

  // ---- build bv fragments: vin = f2 * leaky(ev1.r + b) ----
  bf16x8 bv[2][4];
#pragma unroll
  for (int ks = 0; ks < 4; ++ks) {
#pragma unroll
    for (int j = 0; j < 8; ++j) {
      int c = ks * 32 + l4 * 8 + j;
      float4 ew = ld_enc(encS, 2, c);
      float e0 = leaky(ew.x * r0[0] + ew.y * r1[0] + ew.z * r2[0] + ew.w);
      float e1 = leaky(ew.x * r0[1] + ew.y * r1[1] + ew.z * r2[1] + ew.w);
      bv[0][ks][j] = (short)f2bf(bf2f((u16)fB[0][ks][j]) * e0);
      bv[1][ks][j] = (short)f2bf(bf2f((u16)fB[1][ks][j]) * e1);
    }
  }

  // ---- GEMM2 (v = Wv @ vin) + ev2 scale + atten-weighted reduce + store ----
#pragma unroll
  for (int mt = 0; mt < 8; ++mt) {
    f32x4 a0 = (f32x4){0.f, 0.f, 0.f, 0.f};
    f32x4 a1 = (f32x4){0.f, 0.f, 0.f, 0.f};
#pragma unroll
    for (int ks = 0; ks < 4; ++ks) {
      bf16x8 af = *(const bf16x8*)&wvm[(mt * 16 + l15) * 128 + ks * 32 + l4 * 8];
      a0 = __builtin_amdgcn_mfma_f32_16x16x32_bf16(af, bv[0][ks], a0, 0, 0, 0);
      a1 = __builtin_amdgcn_mfma_f32_16x16x32_bf16(af, bv[1][ks], a1, 0, 0, 0);
    }
    int m0 = mt * 16 + l4 * 4;
    float s0[4], s1[4];
#pragma unroll
    for (int r = 0; r < 4; ++r) {
      float4 ew = ld_enc(encS, 3, m0 + r);
      float v0 = leaky(ew.x * r0[0] + ew.y * r1[0] + ew.z * r2[0] + ew.w);
      float v1 = leaky(ew.x * r0[1] + ew.y * r1[1] + ew.z * r2[1] + ew.w);
      s0[r] = a0[r] * v0 * aw0;
      s1[r] = a1[r] * v1 * aw1;
    }
#pragma unroll
    for (int o = 1; o < 16; o <<= 1) {
      s0[0] += __shfl_xor(s0[0], o); s0[1] += __shfl_xor(s0[1], o);
      s0[2] += __shfl_xor(s0[2], o); s0[3] += __shfl_xor(s0[3], o);
      s1[0] += __shfl_xor(s1[0], o); s1[1] += __shfl_xor(s1[1], o);
      s1[2] += __shfl_xor(s1[2], o); s1[3] += __shfl_xor(s1[3], o);
    }
    if (l15 == 0) {
      const float4 f1v0 = *(const float4*)&f1s[(w * 2 + 0) * 132 + m0];
      const float4 f1v1 = *(const float4*)&f1s[(w * 2 + 1) * 132 + m0];
      float4 o0 = { s0[0] + f1v0.x, s0[1] + f1v0.y, s0[2] + f1v0.z, s0[3] + f1v0.w };
      float4 o1 = { s1[0] + f1v1.x, s1[1] + f1v1.y, s1[2] + f1v1.z, s1[3] + f1v1.w };
      *(float4*)&outp[(size_t)(b * NN1 + pt0) * 128 + m0] = o0;
      *(float4*)&outp[(size_t)(b * NN1 + pt1) * 128 + m0] = o1;
    }
  }
}

// ---------------------------------------------------------------------------
// FF: h[b][d][n] = ff_w[d,:].feat_new[b][n][:] + ff_b[d]; per-block GN
// partials written non-atomically to pstat[block][8][2].
__global__ __launch_bounds__(256)
void k_ff(const float* __restrict__ xin, const float* __restrict__ ffw,
          const float* __restrict__ ffb, float* __restrict__ hout,
          float* __restrict__ pstat) {
  int t = threadIdx.x, bx = blockIdx.x;
  int b = bx / (NN1 / 32), n0 = (bx % (NN1 / 32)) * 32;
  __shared__ float XT[128][34];
  for (int e = t; e < 4096; e += 256) {
    int c = e & 127, nn = e >> 7;
    XT[c][nn] = xin[(b * NN1 + n0 + nn) * 128 + c];
  }
  __syncthreads();
  int d = t >> 1, nh = t & 1;
  float acc[16];
#pragma unroll
  for (int j = 0; j < 16; ++j) acc[j] = 0.0f;
  for (int c0 = 0; c0 < 128; c0 += 4) {
    float4 w4 = *(const float4*)&ffw[d * 128 + c0];
    const float wa[4] = { w4.x, w4.y, w4.z, w4.w };
#pragma unroll
    for (int k = 0; k < 4; ++k) {
      int c = c0 + k;
#pragma unroll
      for (int j2 = 0; j2 < 8; ++j2) {
        float2 xv = *(const float2*)&XT[c][nh * 16 + j2 * 2];
        acc[j2 * 2 + 0] += wa[k] * xv.x;
        acc[j2 * 2 + 1] += wa[k] * xv.y;
      }
    }
  }
  float bias = ffb[d];
  float ls = 0.0f, lss = 0.0f;
  float out[16];
#pragma unroll
  for (int j = 0; j < 16; ++j) { float h = acc[j] + bias; out[j] = h; ls += h; lss += h * h; }
#pragma unroll
  for (int j4 = 0; j4 < 4; ++j4) {
    float4 o = { out[j4 * 4], out[j4 * 4 + 1], out[j4 * 4 + 2], out[j4 * 4 + 3] };
    *(float4*)&hout[(b * 128 + d) * NN1 + n0 + nh * 16 + j4 * 4] = o;
  }
#pragma unroll
  for (int o = 1; o <= 16; o <<= 1) { ls += __shfl_xor(ls, o); lss += __shfl_xor(lss, o); }
  if ((t & 31) == 0) {
    int g = t >> 5;
    pstat[bx * 16 + g * 2 + 0] = ls;
    pstat[bx * 16 + g * 2 + 1] = lss;
  }
}

// Reduce pstat[512][16] -> gnf[2][8][2].
__global__ __launch_bounds__(512)
void k_ffred(const float* __restrict__ pstat, float* __restrict__ gnf) {
  __shared__ float red[512];
  int t = threadIdx.x;
  int b = t >> 8, i = t & 15, chunk = (t >> 4) & 15;
  float s = 0.0f;
#pragma unroll
  for (int k = 0; k < 16; ++k)
    s += pstat[(b * 256 + chunk * 16 + k) * 16 + i];
  red[t] = s;
  __syncthreads();
  if (chunk == 0) {
    float tot = 0.0f;
#pragma unroll
    for (int k2 = 0; k2 < 16; ++k2) tot += red[(b << 8) | (k2 << 4) | i];
    gnf[b * 16 + i] = tot;
  }
}

// Final GN + leaky + f32 store; also writes the xyz1 passthrough (blocks >= 8192).
__global__ __launch_bounds__(256)
void k_final(const float* __restrict__ h, const float* __restrict__ gnf,
             const float* __restrict__ g, const float* __restrict__ bt,
             const float* __restrict__ xyz1, float* __restrict__ out) {
  int bx = blockIdx.x;
  if (bx >= 8192) {
    int e = (bx - 8192) * 256 + threadIdx.x;   // < BB*3*NN1 = 49152
    out[e] = xyz1[e];
    return;
  }
  int e = bx * 256 + threadIdx.x;              // < BB*128*NN1 = 2097152
  int d = (e / NN1) & 127;
  int b = e / (128 * NN1);
  int gi = b * 16 + (d >> 4) * 2;
  float cnt = 16.0f * (float)NN1;
  float mu = gnf[gi] / cnt;
  float var = gnf[gi + 1] / cnt - mu * mu;
  float rs = rsqrtf(var + 1e-5f);
  float x = (h[e] - mu) * rs * g[d] + bt[d];
  out[BB * 3 * NN1 + e] = leaky(x);
}

// ---------------------------------------------------------------------------
extern "C" void kernel_launch(void* const* d_in, const int* in_sizes, int n_in,
                              void* d_out, int out_size, void* d_ws, size_t ws_size,
                              hipStream_t stream) {
  const float* xyz1   = (const float*)d_in[0];
  const float* xyz2   = (const float*)d_in[1];
  const float* feat1  = (const float*)d_in[2];
  const float* feat2  = (const float*)d_in[3];
  const float* pos_w  = (const float*)d_in[4];
  const float* pos_b  = (const float*)d_in[5];
  const float* pos_g  = (const float*)d_in[6];
  const float* pos_bt = (const float*)d_in[7];
  const float* ek_w   = (const float*)d_in[8];
  const float* ek_b   = (const float*)d_in[9];
  const float* eq_w   = (const float*)d_in[10];
  const float* eq_b   = (const float*)d_in[11];
  const float* ev1_w  = (const float*)d_in[12];
  const float* ev1_b  = (const float*)d_in[13];
  const float* ev2_w  = (const float*)d_in[14];
  const float* ev2_b  = (const float*)d_in[15];
  const float* qk_w   = (const float*)d_in[16];
  const float* v_w    = (const float*)d_in[17];
  const float* ff_w   = (const float*)d_in[18];
  const float* ff_b   = (const float*)d_in[19];
  const float* ff_g   = (const float*)d_in[20];
  const float* ff_bt  = (const float*)d_in[21];
  (void)in_sizes; (void)n_in; (void)out_size; (void)ws_size;

  char* ws = (char*)d_ws;          // ~31 MB used
  float*  feat1p   = (float*)(ws);                        // [B][N1][C] f32   8388608 B
  u16*    feat2pb  = (u16*)  (ws + 8388608);              // [B][N2][C] bf16  4194304 B
  float*  attn_out = (float*)(ws + 12582912);             // feat_new (after knn_tmp dead)
  float*  h_ff     = (float*)(ws + 20971520);             // FF out [B][C][N1]
  u32*    knn_tmp  = (u32*)  (ws + 12582912);             // 16 MiB, consumed pre-attn
  int*    idxb     = (int*)  (ws + 29360128);             // [B][N1][16]      1048576 B
  u16*    wqk      = (u16*)  (ws + 30408704);             // bf16 qk_w        32768 B
  u16*    wv       = (u16*)  (ws + 30441472);             // bf16 v_w         32768 B
  float*  mom      = (float*)(ws + 30474240);             // 36 floats (+pad) 160 B
  float2* gnp      = (float2*)(ws + 30474400);            // 32 float2        256 B
  float*  pstat    = (float*)(ws + 30474656);             // 512*16 floats    32768 B
  float*  gnf      = (float*)(ws + 30507424);             // 32 floats        128 B
  float4* px1      = (float4*)(ws + 30507552);            // [B][N1] packed   262144 B
  float4* px2      = (float4*)(ws + 30769696);            // [B][N2] packed   262144 B

  hipMemsetAsync(mom, 0, 160, stream);
  k_prep<<<256, 256, 0, stream>>>(qk_w, v_w, wqk, wv, xyz1, xyz2, px1, px2, mom);
  k_gnstats<<<1, 512, 0, stream>>>(mom, pos_w, pos_b, gnp);
  k_posenc<<<2048, 256, 0, stream>>>(xyz1, xyz2, feat1, feat2, pos_w, pos_b,
                                     pos_g, pos_bt, gnp, feat1p, feat2pb);
  k_knn1<<<1024, 256, 0, stream>>>(px1, px2, knn_tmp);
  k_knn2<<<64, 256, 0, stream>>>(knn_tmp, idxb);
  k_attn<<<2048, 256, 0, stream>>>(px1, px2, feat1p, feat2pb, idxb, wqk, wv,
                                   eq_w, eq_b, ek_w, ek_b, ev1_w, ev1_b, ev2_w, ev2_b,
                                   attn_out);
  k_ff<<<512, 256, 0, stream>>>(attn_out, ff_w, ff_b, h_ff, pstat);
  k_ffred<<<1, 512, 0, stream>>>(pstat, gnf);
  k_final<<<8384, 256, 0, stream>>>(h_ff, gnf, ff_g, ff_bt, xyz1, (float*)d_out);
}

// Round 11
// 325.007 us; speedup vs baseline: 1.0595x; 1.0595x over previous
//
#include <hip/hip_runtime.h>
#include <hip/hip_bf16.h>

// Problem constants (reference: B,N1,N2,C,COUT,NS = 2,8192,8192,128,128,16)
#define BB  2
#define NN1 8192
#define NN2 8192
#define CC  128
#define SS  16

typedef unsigned short u16;
typedef unsigned int u32;
typedef short bf16x8 __attribute__((ext_vector_type(8)));
typedef float f32x4  __attribute__((ext_vector_type(4)));

__device__ __forceinline__ u16 f2bf(float f) {
  __hip_bfloat16 h = __float2bfloat16(f);      // RNE
  return *(u16*)&h;
}
__device__ __forceinline__ float bf2f(u16 u) {
  union { float f; unsigned int u; } v; v.u = ((unsigned int)u) << 16;
  return v.f;
}
__device__ __forceinline__ float bflo(u32 w) {
  union { float f; unsigned int u; } v; v.u = w << 16; return v.f;
}
__device__ __forceinline__ float bfhi(u32 w) {
  union { float f; unsigned int u; } v; v.u = w & 0xFFFF0000u; return v.f;
}
__device__ __forceinline__ float leaky(float x) { return x >= 0.0f ? x : 0.1f * x; }

// ---------------------------------------------------------------------------
// prep: convert qk_w/v_w to bf16; pack xyz -> float4{x,y,z,|p|2}; accumulate
// per-(cloud,batch) xyz moments (9 sums) for analytic GroupNorm stats.
__global__ __launch_bounds__(256)
void k_prep(const float* __restrict__ qkw, const float* __restrict__ vw,
            u16* __restrict__ oa, u16* __restrict__ ob,
            const float* __restrict__ xyz1, const float* __restrict__ xyz2,
            float4* __restrict__ px1, float4* __restrict__ px2,
            float* __restrict__ mom) {
  int bx = blockIdx.x, t = threadIdx.x;
  if (bx < 128) {
    int e = bx * 256 + t;
    if (e < 16384) oa[e] = f2bf(qkw[e]);
    else ob[e - 16384] = f2bf(vw[e - 16384]);
    return;
  }
  const float* xyz; float4* px; int e, cl;
  if (bx < 192) { e = (bx - 128) * 256 + t; xyz = xyz1; px = px1; cl = 0; }
  else          { e = (bx - 192) * 256 + t; xyz = xyz2; px = px2; cl = 1; }
  int b = e >> 13, n = e & 8191;
  float x = xyz[(b * 3 + 0) * 8192 + n];
  float y = xyz[(b * 3 + 1) * 8192 + n];
  float z = xyz[(b * 3 + 2) * 8192 + n];
  px[e] = make_float4(x, y, z, x * x + y * y + z * z);
  float s0 = x, s1 = y, s2 = z, s3 = x * x, s4 = y * y, s5 = z * z;
  float s6 = x * y, s7 = x * z, s8 = y * z;
#pragma unroll
  for (int o = 1; o < 64; o <<= 1) {
    s0 += __shfl_xor(s0, o); s1 += __shfl_xor(s1, o); s2 += __shfl_xor(s2, o);
    s3 += __shfl_xor(s3, o); s4 += __shfl_xor(s4, o); s5 += __shfl_xor(s5, o);
    s6 += __shfl_xor(s6, o); s7 += __shfl_xor(s7, o); s8 += __shfl_xor(s8, o);
  }
  if ((t & 63) == 0) {
    float* mp = mom + (cl * 2 + b) * 9;
    atomicAdd(&mp[0], s0); atomicAdd(&mp[1], s1); atomicAdd(&mp[2], s2);
    atomicAdd(&mp[3], s3); atomicAdd(&mp[4], s4); atomicAdd(&mp[5], s5);
    atomicAdd(&mp[6], s6); atomicAdd(&mp[7], s7); atomicAdd(&mp[8], s8);
  }
}

// Analytic GN stats for pos-enc.
__global__ __launch_bounds__(512)
void k_gnstats(const float* __restrict__ mom, const float* __restrict__ pw,
               const float* __restrict__ pb, float2* __restrict__ gnp) {
  int t = threadIdx.x;                 // 512: cloud(2) x b(2) x c(128)
  int cl = t >> 8, b = (t >> 7) & 1, c = t & 127;
  const float* M = mom + (cl * 2 + b) * 9;
  const float inv = 1.0f / 8192.0f;
  float mx = M[0] * inv, my = M[1] * inv, mz = M[2] * inv;
  float sxx = M[3] * inv, syy = M[4] * inv, szz = M[5] * inv;
  float sxy = M[6] * inv, sxz = M[7] * inv, syz = M[8] * inv;
  float w0 = pw[c * 3], w1 = pw[c * 3 + 1], w2 = pw[c * 3 + 2], bc = pb[c];
  float wm = w0 * mx + w1 * my + w2 * mz;
  float Eh = wm + bc;
  float wSw = w0 * w0 * sxx + w1 * w1 * syy + w2 * w2 * szz
            + 2.0f * (w0 * w1 * sxy + w0 * w2 * sxz + w1 * w2 * syz);
  float Eh2 = wSw + 2.0f * bc * wm + bc * bc;
#pragma unroll
  for (int o = 1; o < 16; o <<= 1) { Eh += __shfl_xor(Eh, o); Eh2 += __shfl_xor(Eh2, o); }
  if ((c & 15) == 0) {
    float mu = Eh * 0.0625f;
    float var = Eh2 * 0.0625f - mu * mu;
    gnp[cl * 16 + b * 8 + (c >> 4)] = make_float2(mu, rsqrtf(var + 1e-5f));
  }
}

// Fused pos-enc (single pass, both clouds): featp = feat + leaky(GN(W.xyz+b)).
// cloud1 -> f32, cloud2 -> bf16.
__global__ __launch_bounds__(256)
void k_posenc(const float* __restrict__ xyz1, const float* __restrict__ xyz2,
              const float* __restrict__ feat1, const float* __restrict__ feat2,
              const float* __restrict__ pw, const float* __restrict__ pb,
              const float* __restrict__ gam, const float* __restrict__ bet,
              const float2* __restrict__ gnp,
              float* __restrict__ outf, u16* __restrict__ outb) {
  int t = threadIdx.x, bx = blockIdx.x;
  const float* xyz; const float* feat; const float2* gp; int asbf;
  if (bx < 1024) { xyz = xyz1; feat = feat1; gp = gnp;      asbf = 0; }
  else           { xyz = xyz2; feat = feat2; gp = gnp + 16; asbf = 1; bx -= 1024; }
  const int N = 8192;
  int b = bx / 512, n0 = (bx % 512) * 16;
  __shared__ float T[128][17];
  for (int it = 0; it < 8; ++it) {
    int j = t & 15, c = it * 16 + (t >> 4);
    T[c][j] = feat[(b * 128 + c) * N + n0 + j];
  }
  int c = t & 127;
  float w0 = pw[c * 3], w1 = pw[c * 3 + 1], w2 = pw[c * 3 + 2], bc = pb[c];
  float2 g2 = gp[b * 8 + (c >> 4)];
  float gm = gam[c], b2 = bet[c];
  __syncthreads();
  for (int it = 0; it < 8; ++it) {
    int j = it * 2 + (t >> 7);
    int n = n0 + j;
    float xs = xyz[(b * 3 + 0) * N + n];
    float ys = xyz[(b * 3 + 1) * N + n];
    float zs = xyz[(b * 3 + 2) * N + n];
    float hv = w0 * xs + w1 * ys + w2 * zs + bc;
    float xo = (hv - g2.x) * g2.y * gm + b2;
    float r = T[c][j] + leaky(xo);
    if (asbf) outb[(size_t)(b * N + n) * 128 + c] = f2bf(r);
    else      outf[(size_t)(b * N + n) * 128 + c] = r;
  }
}

// ---------------------------------------------------------------------------
// KNN. Packed key: (f32 distance^2 bits & 0xFFFFE000) | index (13 bits).

__device__ __forceinline__ void sort16(u32 (&e)[16]) {
#pragma unroll
  for (int k = 2; k <= 16; k <<= 1) {
#pragma unroll
    for (int j = k >> 1; j > 0; j >>= 1) {
#pragma unroll
      for (int i = 0; i < 16; ++i) {
        int l = i ^ j;
        if (l > i) {
          bool up = ((i & k) == 0);
          u32 x = e[i], y = e[l];
          u32 mn = x < y ? x : y;
          u32 mx = x < y ? y : x;
          e[i] = up ? mn : mx;
          e[l] = up ? mx : mn;
        }
      }
    }
  }
}

__device__ __forceinline__ void merge16(u32 (&A)[16], const u32 (&S)[16]) {
  u32 t[16];
#pragma unroll
  for (int i = 0; i < 16; ++i) {
    u32 a = A[i], s = S[15 - i];
    t[i] = a < s ? a : s;
  }
#pragma unroll
  for (int j = 8; j > 0; j >>= 1) {
#pragma unroll
    for (int i = 0; i < 16; ++i) {
      if ((i & j) == 0) {
        u32 x = t[i], y = t[i | j];
        t[i] = x < y ? x : y;
        t[i | j] = x < y ? y : x;
      }
    }
  }
#pragma unroll
  for (int i = 0; i < 16; ++i) A[i] = t[i];
}

// Stage 1: 4 waves/block, wave = one 512-candidate slice, lane = query.
__global__ __launch_bounds__(256)
void k_knn1(const float4* __restrict__ px1, const float4* __restrict__ px2,
            u32* __restrict__ out) {
  int bx = blockIdx.x;                  // 1024 = b(2) * g(128) * sb(4)
  int w = threadIdx.x >> 6, l = threadIdx.x & 63;
  int sb = bx & 3, g = (bx >> 2) & 127, b = bx >> 9;
  int slice = sb * 4 + w;
  int q = g * 64 + l;
  float4 qv = px1[b * NN1 + q];
  u32 A[16];
#pragma unroll
  for (int i = 0; i < 16; ++i) A[i] = 0xFFFFFFFFu;
  const float4* cp = px2 + b * NN2 + slice * 512;
  for (int it = 0; it < 32; ++it) {
    u32 S[16];
#pragma unroll
    for (int kk = 0; kk < 16; ++kk) {
      float4 c = cp[it * 16 + kk];      // uniform -> scalar load
      float m = fmaf(qv.x, c.x, fmaf(qv.y, c.y, qv.z * c.z));
      float d = fmaf(-2.0f, m, qv.w + c.w);
      d = fmaxf(d, 0.0f);
      S[kk] = (__float_as_uint(d) & 0xFFFFE000u) |
              (u32)(slice * 512 + it * 16 + kk);
    }
    sort16(S);
    merge16(A, S);
  }
  u32* op = out + ((b * NN1 + q) * 16 + slice) * 16;
#pragma unroll
  for (int i = 0; i < 4; ++i)
    *(uint4*)&op[i * 4] = make_uint4(A[i * 4], A[i * 4 + 1], A[i * 4 + 2], A[i * 4 + 3]);
}

// Stage 2: one thread per query merges 16 sorted lists -> indices.
__global__ __launch_bounds__(256)
void k_knn2(const u32* __restrict__ in, int* __restrict__ idxout) {
  int e = blockIdx.x * 256 + threadIdx.x;
  const u32* p = in + (size_t)e * 256;
  u32 A[16];
#pragma unroll
  for (int i = 0; i < 4; ++i) {
    uint4 v = *(const uint4*)&p[i * 4];
    A[i * 4] = v.x; A[i * 4 + 1] = v.y; A[i * 4 + 2] = v.z; A[i * 4 + 3] = v.w;
  }
  for (int s = 1; s < 16; ++s) {
    u32 S[16];
#pragma unroll
    for (int i = 0; i < 4; ++i) {
      uint4 v = *(const uint4*)&p[s * 16 + i * 4];
      S[i * 4] = v.x; S[i * 4 + 1] = v.y; S[i * 4 + 2] = v.z; S[i * 4 + 3] = v.w;
    }
    merge16(A, S);
  }
  int* op = idxout + e * 16;
#pragma unroll
  for (int i = 0; i < 4; ++i) {
    int4 o = make_int4((int)(A[i * 4] & 8191u), (int)(A[i * 4 + 1] & 8191u),
                       (int)(A[i * 4 + 2] & 8191u), (int)(A[i * 4 + 3] & 8191u));
    *(int4*)&op[i * 4] = o;
  }
}

// ---------------------------------------------------------------------------
// Fused attention, 1 point per wave (grid 4096 x 256 = 16384 points).
// Halved per-wave register state targets natural VGPR <= 64 (the occupancy
// cliff: VGPR>64 -> 128-chunk -> 4 waves/SIMD cap). (256,4) budget = 128,
// cannot clamp below natural demand -> no spill possible.
__device__ __forceinline__ float4 ld_enc(const float* encS, int e, int c) {
  int xe = e ^ ((c >> 3) & 3);
  return *(const float4*)&encS[c * 16 + xe * 4];
}

__global__ __launch_bounds__(256, 4)
void k_attn(const float4* __restrict__ px1, const float4* __restrict__ px2,
            const float* __restrict__ f1p, const u16* __restrict__ f2p,
            const int* __restrict__ idxb,
            const u16* __restrict__ wq, const u16* __restrict__ wvm,
            const float* __restrict__ eqw, const float* __restrict__ eqb,
            const float* __restrict__ ekw, const float* __restrict__ ekb,
            const float* __restrict__ ev1w, const float* __restrict__ ev1b,
            const float* __restrict__ ev2w, const float* __restrict__ ev2b,
            float* __restrict__ outp) {
  const int t = threadIdx.x;
  // XCD-aware bijective swizzle (grid 4096 % 8 == 0): contiguous 512-block
  // ranges per XCD so neighboring points share L2 for the f2 gathers.
  const int bx = ((blockIdx.x & 7) << 9) | (blockIdx.x >> 3);
  const int w = t >> 6, l = t & 63, l15 = l & 15, l4 = l >> 4;
  const int pt = bx * 4 + w;           // global point id, 0..16383
  const int b = pt >> 13;

  __shared__ float encS[128 * 16];     // 8 KB: eq, ek, ev1, ev2 (XOR slots)
  __shared__ float f1s[4 * 132];       // 2.1 KB: f1 rows for 4 points

  for (int i = t; i < 512; i += 256) {
    int e = i >> 7, c = i & 127;
    const float* wsrc = (e == 0) ? eqw : (e == 1) ? ekw : (e == 2) ? ev1w : ev2w;
    const float* bsrc = (e == 0) ? eqb : (e == 1) ? ekb : (e == 2) ? ev1b : ev2b;
    int xe = e ^ ((c >> 3) & 3);
    float* dst = &encS[c * 16 + xe * 4];
    dst[0] = wsrc[c * 3]; dst[1] = wsrc[c * 3 + 1];
    dst[2] = wsrc[c * 3 + 2]; dst[3] = bsrc[c];
  }
  for (int i = t; i < 512; i += 256) {
    int p = i >> 7, c = i & 127;
    f1s[p * 132 + c] = f1p[(size_t)(bx * 4 + p) * 128 + c];
  }

  // per-lane neighbor (sample = l15) + relative coords
  const int j = idxb[pt * 16 + l15];
  float4 qc = px1[pt];
  float4 cc = px2[(b << 13) + j];
  const float r0 = cc.x - qc.x, r1 = cc.y - qc.y, r2 = cc.z - qc.z;
  const u16* row = f2p + ((size_t)(b << 13) + j) * 128;
  __syncthreads();

  // ---- q-path: bq fragments (B-layout), qin = f1 * leaky(eq.r + b) ----
  bf16x8 bq[4];
#pragma unroll
  for (int ks = 0; ks < 4; ++ks) {
#pragma unroll
    for (int jj = 0; jj < 8; ++jj) {
      int c = ks * 32 + l4 * 8 + jj;
      float4 ew = ld_enc(encS, 0, c);
      float e = leaky(ew.x * r0 + ew.y * r1 + ew.z * r2 + ew.w);
      bq[ks][jj] = (short)f2bf(f1s[w * 132 + c] * e);
    }
  }

  // ---- GEMM1 per mt + attention dot (C/D layout), kd rolling prefetch ----
  float dp = 0.0f;
  uint2 kc = *(const uint2*)(row + l4 * 4);
#pragma unroll
  for (int mt = 0; mt < 8; ++mt) {
    uint2 kn = kc;
    if (mt < 7) kn = *(const uint2*)(row + (mt + 1) * 16 + l4 * 4);
    f32x4 a0 = (f32x4){0.f, 0.f, 0.f, 0.f};
#pragma unroll
    for (int ks = 0; ks < 4; ++ks) {
      bf16x8 af = *(const bf16x8*)&wq[(mt * 16 + l15) * 128 + ks * 32 + l4 * 8];
      a0 = __builtin_amdgcn_mfma_f32_16x16x32_bf16(af, bq[ks], a0, 0, 0, 0);
    }
    float f2v[4] = { bflo(kc.x), bfhi(kc.x), bflo(kc.y), bfhi(kc.y) };
#pragma unroll
    for (int r = 0; r < 4; ++r) {
      int c = mt * 16 + l4 * 4 + r;
      float4 ew = ld_enc(encS, 1, c);
      float ek = leaky(ew.x * r0 + ew.y * r1 + ew.z * r2 + ew.w);
      dp += a0[r] * (f2v[r] * ek);
    }
    kc = kn;
  }
  dp += __shfl_xor(dp, 16); dp += __shfl_xor(dp, 32);

  // 16-lane softmax
  float aw;
  {
    float x = dp * 0.08838834764831845f;
    float m = x;
#pragma unroll
    for (int o = 1; o < 16; o <<= 1) m = fmaxf(m, __shfl_xor(m, o));
    float e = __expf(x - m);
    float s = e;
#pragma unroll
    for (int o = 1; o < 16; o <<= 1) s += __shfl_xor(s, o);
    aw = e / s;
  }

  // ---- v-path: bv fragments, vin = f2 * leaky(ev1.r + b) (fB transient) ----
  bf16x8 bv[4];
#pragma unroll
  for (int ks = 0; ks < 4; ++ks) {
    bf16x8 fBk = *(const bf16x8*)(row + ks * 32 + l4 * 8);
#pragma unroll
    for (int jj = 0; jj < 8; ++jj) {
      int c = ks * 32 + l4 * 8 + jj;
      float4 ew = ld_enc(encS, 2, c);
      float e = leaky(ew.x * r0 + ew.y * r1 + ew.z * r2 + ew.w);
      bv[ks][jj] = (short)f2bf(bf2f((u16)fBk[jj]) * e);
    }
  }

  // ---- GEMM2 per mt + ev2 scale + atten-weighted reduce + store ----
#pragma unroll
  for (int mt = 0; mt < 8; ++mt) {
    f32x4 a0 = (f32x4){0.f, 0.f, 0.f, 0.f};
#pragma unroll
    for (int ks = 0; ks < 4; ++ks) {
      bf16x8 af = *(const bf16x8*)&wvm[(mt * 16 + l15) * 128 + ks * 32 + l4 * 8];
      a0 = __builtin_amdgcn_mfma_f32_16x16x32_bf16(af, bv[ks], a0, 0, 0, 0);
    }
    int m0 = mt * 16 + l4 * 4;
    float s0, s1, s2, s3;
    {
      float4 e0 = ld_enc(encS, 3, m0 + 0);
      float4 e1 = ld_enc(encS, 3, m0 + 1);
      float4 e2 = ld_enc(encS, 3, m0 + 2);
      float4 e3 = ld_enc(encS, 3, m0 + 3);
      s0 = a0[0] * leaky(e0.x * r0 + e0.y * r1 + e0.z * r2 + e0.w) * aw;
      s1 = a0[1] * leaky(e1.x * r0 + e1.y * r1 + e1.z * r2 + e1.w) * aw;
      s2 = a0[2] * leaky(e2.x * r0 + e2.y * r1 + e2.z * r2 + e2.w) * aw;
      s3 = a0[3] * leaky(e3.x * r0 + e3.y * r1 + e3.z * r2 + e3.w) * aw;
    }
#pragma unroll
    for (int o = 1; o < 16; o <<= 1) {
      s0 += __shfl_xor(s0, o); s1 += __shfl_xor(s1, o);
      s2 += __shfl_xor(s2, o); s3 += __shfl_xor(s3, o);
    }
    if (l15 == 0) {
      const float4 f1v = *(const float4*)&f1s[w * 132 + m0];
      float4 ov = { s0 + f1v.x, s1 + f1v.y, s2 + f1v.z, s3 + f1v.w };
      *(float4*)&outp[(size_t)pt * 128 + m0] = ov;
    }
  }
}

// ---------------------------------------------------------------------------
// FF: h[b][d][n] = ff_w[d,:].feat_new[b][n][:] + ff_b[d]; per-block GN
// partials written non-atomically to pstat[block][8][2].
__global__ __launch_bounds__(256)
void k_ff(const float* __restrict__ xin, const float* __restrict__ ffw,
          const float* __restrict__ ffb, float* __restrict__ hout,
          float* __restrict__ pstat) {
  int t = threadIdx.x, bx = blockIdx.x;
  int b = bx / (NN1 / 32), n0 = (bx % (NN1 / 32)) * 32;
  __shared__ float XT[128][34];
  for (int e = t; e < 4096; e += 256) {
    int c = e & 127, nn = e >> 7;
    XT[c][nn] = xin[(b * NN1 + n0 + nn) * 128 + c];
  }
  __syncthreads();
  int d = t >> 1, nh = t & 1;
  float acc[16];
#pragma unroll
  for (int j = 0; j < 16; ++j) acc[j] = 0.0f;
  for (int c0 = 0; c0 < 128; c0 += 4) {
    float4 w4 = *(const float4*)&ffw[d * 128 + c0];
    const float wa[4] = { w4.x, w4.y, w4.z, w4.w };
#pragma unroll
    for (int k = 0; k < 4; ++k) {
      int c = c0 + k;
#pragma unroll
      for (int j2 = 0; j2 < 8; ++j2) {
        float2 xv = *(const float2*)&XT[c][nh * 16 + j2 * 2];
        acc[j2 * 2 + 0] += wa[k] * xv.x;
        acc[j2 * 2 + 1] += wa[k] * xv.y;
      }
    }
  }
  float bias = ffb[d];
  float ls = 0.0f, lss = 0.0f;
  float out[16];
#pragma unroll
  for (int j = 0; j < 16; ++j) { float h = acc[j] + bias; out[j] = h; ls += h; lss += h * h; }
#pragma unroll
  for (int j4 = 0; j4 < 4; ++j4) {
    float4 o = { out[j4 * 4], out[j4 * 4 + 1], out[j4 * 4 + 2], out[j4 * 4 + 3] };
    *(float4*)&hout[(b * 128 + d) * NN1 + n0 + nh * 16 + j4 * 4] = o;
  }
#pragma unroll
  for (int o = 1; o <= 16; o <<= 1) { ls += __shfl_xor(ls, o); lss += __shfl_xor(lss, o); }
  if ((t & 31) == 0) {
    int g = t >> 5;
    pstat[bx * 16 + g * 2 + 0] = ls;
    pstat[bx * 16 + g * 2 + 1] = lss;
  }
}

// Reduce pstat[512][16] -> gnf[2][8][2].
__global__ __launch_bounds__(512)
void k_ffred(const float* __restrict__ pstat, float* __restrict__ gnf) {
  __shared__ float red[512];
  int t = threadIdx.x;
  int b = t >> 8, i = t & 15, chunk = (t >> 4) & 15;
  float s = 0.0f;
#pragma unroll
  for (int k = 0; k < 16; ++k)
    s += pstat[(b * 256 + chunk * 16 + k) * 16 + i];
  red[t] = s;
  __syncthreads();
  if (chunk == 0) {
    float tot = 0.0f;
#pragma unroll
    for (int k2 = 0; k2 < 16; ++k2) tot += red[(b << 8) | (k2 << 4) | i];
    gnf[b * 16 + i] = tot;
  }
}

// Final GN + leaky + f32 store; also writes the xyz1 passthrough (blocks >= 8192).
__global__ __launch_bounds__(256)
void k_final(const float* __restrict__ h, const float* __restrict__ gnf,
             const float* __restrict__ g, const float* __restrict__ bt,
             const float* __restrict__ xyz1, float* __restrict__ out) {
  int bx = blockIdx.x;
  if (bx >= 8192) {
    int e = (bx - 8192) * 256 + threadIdx.x;   // < BB*3*NN1 = 49152
    out[e] = xyz1[e];
    return;
  }
  int e = bx * 256 + threadIdx.x;              // < BB*128*NN1 = 2097152
  int d = (e / NN1) & 127;
  int b = e / (128 * NN1);
  int gi = b * 16 + (d >> 4) * 2;
  float cnt = 16.0f * (float)NN1;
  float mu = gnf[gi] / cnt;
  float var = gnf[gi + 1] / cnt - mu * mu;
  float rs = rsqrtf(var + 1e-5f);
  float x = (h[e] - mu) * rs * g[d] + bt[d];
  out[BB * 3 * NN1 + e] = leaky(x);
}

// ---------------------------------------------------------------------------
extern "C" void kernel_launch(void* const* d_in, const int* in_sizes, int n_in,
                              void* d_out, int out_size, void* d_ws, size_t ws_size,
                              hipStream_t stream) {
  const float* xyz1   = (const float*)d_in[0];
  const float* xyz2   = (const float*)d_in[1];
  const float* feat1  = (const float*)d_in[2];
  const float* feat2  = (const float*)d_in[3];
  const float* pos_w  = (const float*)d_in[4];
  const float* pos_b  = (const float*)d_in[5];
  const float* pos_g  = (const float*)d_in[6];
  const float* pos_bt = (const float*)d_in[7];
  const float* ek_w   = (const float*)d_in[8];
  const float* ek_b   = (const float*)d_in[9];
  const float* eq_w   = (const float*)d_in[10];
  const float* eq_b   = (const float*)d_in[11];
  const float* ev1_w  = (const float*)d_in[12];
  const float* ev1_b  = (const float*)d_in[13];
  const float* ev2_w  = (const float*)d_in[14];
  const float* ev2_b  = (const float*)d_in[15];
  const float* qk_w   = (const float*)d_in[16];
  const float* v_w    = (const float*)d_in[17];
  const float* ff_w   = (const float*)d_in[18];
  const float* ff_b   = (const float*)d_in[19];
  const float* ff_g   = (const float*)d_in[20];
  const float* ff_bt  = (const float*)d_in[21];
  (void)in_sizes; (void)n_in; (void)out_size; (void)ws_size;

  char* ws = (char*)d_ws;          // ~31 MB used
  float*  feat1p   = (float*)(ws);                        // [B][N1][C] f32   8388608 B
  u16*    feat2pb  = (u16*)  (ws + 8388608);              // [B][N2][C] bf16  4194304 B
  float*  attn_out = (float*)(ws + 12582912);             // feat_new (after knn_tmp dead)
  float*  h_ff     = (float*)(ws + 20971520);             // FF out [B][C][N1]
  u32*    knn_tmp  = (u32*)  (ws + 12582912);             // 16 MiB, consumed pre-attn
  int*    idxb     = (int*)  (ws + 29360128);             // [B][N1][16]      1048576 B
  u16*    wqk      = (u16*)  (ws + 30408704);             // bf16 qk_w        32768 B
  u16*    wv       = (u16*)  (ws + 30441472);             // bf16 v_w         32768 B
  float*  mom      = (float*)(ws + 30474240);             // 36 floats (+pad) 160 B
  float2* gnp      = (float2*)(ws + 30474400);            // 32 float2        256 B
  float*  pstat    = (float*)(ws + 30474656);             // 512*16 floats    32768 B
  float*  gnf      = (float*)(ws + 30507424);             // 32 floats        128 B
  float4* px1      = (float4*)(ws + 30507552);            // [B][N1] packed   262144 B
  float4* px2      = (float4*)(ws + 30769696);            // [B][N2] packed   262144 B

  hipMemsetAsync(mom, 0, 160, stream);
  k_prep<<<256, 256, 0, stream>>>(qk_w, v_w, wqk, wv, xyz1, xyz2, px1, px2, mom);
  k_gnstats<<<1, 512, 0, stream>>>(mom, pos_w, pos_b, gnp);
  k_posenc<<<2048, 256, 0, stream>>>(xyz1, xyz2, feat1, feat2, pos_w, pos_b,
                                     pos_g, pos_bt, gnp, feat1p, feat2pb);
  k_knn1<<<1024, 256, 0, stream>>>(px1, px2, knn_tmp);
  k_knn2<<<64, 256, 0, stream>>>(knn_tmp, idxb);
  k_attn<<<4096, 256, 0, stream>>>(px1, px2, feat1p, feat2pb, idxb, wqk, wv,
                                   eq_w, eq_b, ek_w, ek_b, ev1_w, ev1_b, ev2_w, ev2_b,
                                   attn_out);
  k_ff<<<512, 256, 0, stream>>>(attn_out, ff_w, ff_b, h_ff, pstat);
  k_ffred<<<1, 512, 0, stream>>>(pstat, gnf);
  k_final<<<8384, 256, 0, stream>>>(h_ff, gnf, ff_g, ff_bt, xyz1, (float*)d_out);
}

// Round 12
// 267.590 us; speedup vs baseline: 1.2869x; 1.2146x over previous
//
#include <hip/hip_runtime.h>
#include <hip/hip_bf16.h>

// Problem constants (reference: B,N1,N2,C,COUT,NS = 2,8192,8192,128,128,16)
#define BB  2
#define NN1 8192
#define NN2 8192
#define CC  128
#define SS  16

typedef unsigned short u16;
typedef unsigned int u32;
typedef short bf16x8 __attribute__((ext_vector_type(8)));
typedef float f32x4  __attribute__((ext_vector_type(4)));

__device__ __forceinline__ u16 f2bf(float f) {
  __hip_bfloat16 h = __float2bfloat16(f);      // RNE
  return *(u16*)&h;
}
__device__ __forceinline__ float bf2f(u16 u) {
  union { float f; unsigned int u; } v; v.u = ((unsigned int)u) << 16;
  return v.f;
}
__device__ __forceinline__ float bflo(u32 w) {
  union { float f; unsigned int u; } v; v.u = w << 16; return v.f;
}
__device__ __forceinline__ float bfhi(u32 w) {
  union { float f; unsigned int u; } v; v.u = w & 0xFFFF0000u; return v.f;
}
__device__ __forceinline__ float leaky(float x) { return x >= 0.0f ? x : 0.1f * x; }

// ---------------------------------------------------------------------------
// prep: convert qk_w/v_w to bf16; pack xyz -> float4{x,y,z,|p|2}; accumulate
// per-(cloud,batch) xyz moments (9 sums) for analytic GroupNorm stats.
__global__ __launch_bounds__(256)
void k_prep(const float* __restrict__ qkw, const float* __restrict__ vw,
            u16* __restrict__ oa, u16* __restrict__ ob,
            const float* __restrict__ xyz1, const float* __restrict__ xyz2,
            float4* __restrict__ px1, float4* __restrict__ px2,
            float* __restrict__ mom) {
  int bx = blockIdx.x, t = threadIdx.x;
  if (bx < 128) {
    int e = bx * 256 + t;
    if (e < 16384) oa[e] = f2bf(qkw[e]);
    else ob[e - 16384] = f2bf(vw[e - 16384]);
    return;
  }
  const float* xyz; float4* px; int e, cl;
  if (bx < 192) { e = (bx - 128) * 256 + t; xyz = xyz1; px = px1; cl = 0; }
  else          { e = (bx - 192) * 256 + t; xyz = xyz2; px = px2; cl = 1; }
  int b = e >> 13, n = e & 8191;
  float x = xyz[(b * 3 + 0) * 8192 + n];
  float y = xyz[(b * 3 + 1) * 8192 + n];
  float z = xyz[(b * 3 + 2) * 8192 + n];
  px[e] = make_float4(x, y, z, x * x + y * y + z * z);
  float s0 = x, s1 = y, s2 = z, s3 = x * x, s4 = y * y, s5 = z * z;
  float s6 = x * y, s7 = x * z, s8 = y * z;
#pragma unroll
  for (int o = 1; o < 64; o <<= 1) {
    s0 += __shfl_xor(s0, o); s1 += __shfl_xor(s1, o); s2 += __shfl_xor(s2, o);
    s3 += __shfl_xor(s3, o); s4 += __shfl_xor(s4, o); s5 += __shfl_xor(s5, o);
    s6 += __shfl_xor(s6, o); s7 += __shfl_xor(s7, o); s8 += __shfl_xor(s8, o);
  }
  if ((t & 63) == 0) {
    float* mp = mom + (cl * 2 + b) * 9;
    atomicAdd(&mp[0], s0); atomicAdd(&mp[1], s1); atomicAdd(&mp[2], s2);
    atomicAdd(&mp[3], s3); atomicAdd(&mp[4], s4); atomicAdd(&mp[5], s5);
    atomicAdd(&mp[6], s6); atomicAdd(&mp[7], s7); atomicAdd(&mp[8], s8);
  }
}

// Analytic GN stats for pos-enc.
__global__ __launch_bounds__(512)
void k_gnstats(const float* __restrict__ mom, const float* __restrict__ pw,
               const float* __restrict__ pb, float2* __restrict__ gnp) {
  int t = threadIdx.x;                 // 512: cloud(2) x b(2) x c(128)
  int cl = t >> 8, b = (t >> 7) & 1, c = t & 127;
  const float* M = mom + (cl * 2 + b) * 9;
  const float inv = 1.0f / 8192.0f;
  float mx = M[0] * inv, my = M[1] * inv, mz = M[2] * inv;
  float sxx = M[3] * inv, syy = M[4] * inv, szz = M[5] * inv;
  float sxy = M[6] * inv, sxz = M[7] * inv, syz = M[8] * inv;
  float w0 = pw[c * 3], w1 = pw[c * 3 + 1], w2 = pw[c * 3 + 2], bc = pb[c];
  float wm = w0 * mx + w1 * my + w2 * mz;
  float Eh = wm + bc;
  float wSw = w0 * w0 * sxx + w1 * w1 * syy + w2 * w2 * szz
            + 2.0f * (w0 * w1 * sxy + w0 * w2 * sxz + w1 * w2 * syz);
  float Eh2 = wSw + 2.0f * bc * wm + bc * bc;
#pragma unroll
  for (int o = 1; o < 16; o <<= 1) { Eh += __shfl_xor(Eh, o); Eh2 += __shfl_xor(Eh2, o); }
  if ((c & 15) == 0) {
    float mu = Eh * 0.0625f;
    float var = Eh2 * 0.0625f - mu * mu;
    gnp[cl * 16 + b * 8 + (c >> 4)] = make_float2(mu, rsqrtf(var + 1e-5f));
  }
}

// Fused pos-enc (single pass, both clouds): featp = feat + leaky(GN(W.xyz+b)).
// cloud1 -> f32, cloud2 -> bf16.
__global__ __launch_bounds__(256)
void k_posenc(const float* __restrict__ xyz1, const float* __restrict__ xyz2,
              const float* __restrict__ feat1, const float* __restrict__ feat2,
              const float* __restrict__ pw, const float* __restrict__ pb,
              const float* __restrict__ gam, const float* __restrict__ bet,
              const float2* __restrict__ gnp,
              float* __restrict__ outf, u16* __restrict__ outb) {
  int t = threadIdx.x, bx = blockIdx.x;
  const float* xyz; const float* feat; const float2* gp; int asbf;
  if (bx < 1024) { xyz = xyz1; feat = feat1; gp = gnp;      asbf = 0; }
  else           { xyz = xyz2; feat = feat2; gp = gnp + 16; asbf = 1; bx -= 1024; }
  const int N = 8192;
  int b = bx / 512, n0 = (bx % 512) * 16;
  __shared__ float T[128][17];
  for (int it = 0; it < 8; ++it) {
    int j = t & 15, c = it * 16 + (t >> 4);
    T[c][j] = feat[(b * 128 + c) * N + n0 + j];
  }
  int c = t & 127;
  float w0 = pw[c * 3], w1 = pw[c * 3 + 1], w2 = pw[c * 3 + 2], bc = pb[c];
  float2 g2 = gp[b * 8 + (c >> 4)];
  float gm = gam[c], b2 = bet[c];
  __syncthreads();
  for (int it = 0; it < 8; ++it) {
    int j = it * 2 + (t >> 7);
    int n = n0 + j;
    float xs = xyz[(b * 3 + 0) * N + n];
    float ys = xyz[(b * 3 + 1) * N + n];
    float zs = xyz[(b * 3 + 2) * N + n];
    float hv = w0 * xs + w1 * ys + w2 * zs + bc;
    float xo = (hv - g2.x) * g2.y * gm + b2;
    float r = T[c][j] + leaky(xo);
    if (asbf) outb[(size_t)(b * N + n) * 128 + c] = f2bf(r);
    else      outf[(size_t)(b * N + n) * 128 + c] = r;
  }
}

// ---------------------------------------------------------------------------
// KNN. Packed key: (f32 distance^2 bits & 0xFFFFE000) | index (13 bits).

__device__ __forceinline__ void sort16(u32 (&e)[16]) {
#pragma unroll
  for (int k = 2; k <= 16; k <<= 1) {
#pragma unroll
    for (int j = k >> 1; j > 0; j >>= 1) {
#pragma unroll
      for (int i = 0; i < 16; ++i) {
        int l = i ^ j;
        if (l > i) {
          bool up = ((i & k) == 0);
          u32 x = e[i], y = e[l];
          u32 mn = x < y ? x : y;
          u32 mx = x < y ? y : x;
          e[i] = up ? mn : mx;
          e[l] = up ? mx : mn;
        }
      }
    }
  }
}

__device__ __forceinline__ void merge16(u32 (&A)[16], const u32 (&S)[16]) {
  u32 t[16];
#pragma unroll
  for (int i = 0; i < 16; ++i) {
    u32 a = A[i], s = S[15 - i];
    t[i] = a < s ? a : s;
  }
#pragma unroll
  for (int j = 8; j > 0; j >>= 1) {
#pragma unroll
    for (int i = 0; i < 16; ++i) {
      if ((i & j) == 0) {
        u32 x = t[i], y = t[i | j];
        t[i] = x < y ? x : y;
        t[i | j] = x < y ? y : x;
      }
    }
  }
#pragma unroll
  for (int i = 0; i < 16; ++i) A[i] = t[i];
}

// Stage 1: 4 waves/block, wave = one 512-candidate slice, lane = query.
__global__ __launch_bounds__(256)
void k_knn1(const float4* __restrict__ px1, const float4* __restrict__ px2,
            u32* __restrict__ out) {
  int bx = blockIdx.x;                  // 1024 = b(2) * g(128) * sb(4)
  int w = threadIdx.x >> 6, l = threadIdx.x & 63;
  int sb = bx & 3, g = (bx >> 2) & 127, b = bx >> 9;
  int slice = sb * 4 + w;
  int q = g * 64 + l;
  float4 qv = px1[b * NN1 + q];
  u32 A[16];
#pragma unroll
  for (int i = 0; i < 16; ++i) A[i] = 0xFFFFFFFFu;
  const float4* cp = px2 + b * NN2 + slice * 512;
  for (int it = 0; it < 32; ++it) {
    u32 S[16];
#pragma unroll
    for (int kk = 0; kk < 16; ++kk) {
      float4 c = cp[it * 16 + kk];      // uniform -> scalar load
      float m = fmaf(qv.x, c.x, fmaf(qv.y, c.y, qv.z * c.z));
      float d = fmaf(-2.0f, m, qv.w + c.w);
      d = fmaxf(d, 0.0f);
      S[kk] = (__float_as_uint(d) & 0xFFFFE000u) |
              (u32)(slice * 512 + it * 16 + kk);
    }
    sort16(S);
    merge16(A, S);
  }
  u32* op = out + ((b * NN1 + q) * 16 + slice) * 16;
#pragma unroll
  for (int i = 0; i < 4; ++i)
    *(uint4*)&op[i * 4] = make_uint4(A[i * 4], A[i * 4 + 1], A[i * 4 + 2], A[i * 4 + 3]);
}

// Stage 2: one thread per query merges 16 sorted lists -> indices.
__global__ __launch_bounds__(256)
void k_knn2(const u32* __restrict__ in, int* __restrict__ idxout) {
  int e = blockIdx.x * 256 + threadIdx.x;
  const u32* p = in + (size_t)e * 256;
  u32 A[16];
#pragma unroll
  for (int i = 0; i < 4; ++i) {
    uint4 v = *(const uint4*)&p[i * 4];
    A[i * 4] = v.x; A[i * 4 + 1] = v.y; A[i * 4 + 2] = v.z; A[i * 4 + 3] = v.w;
  }
  for (int s = 1; s < 16; ++s) {
    u32 S[16];
#pragma unroll
    for (int i = 0; i < 4; ++i) {
      uint4 v = *(const uint4*)&p[s * 16 + i * 4];
      S[i * 4] = v.x; S[i * 4 + 1] = v.y; S[i * 4 + 2] = v.z; S[i * 4 + 3] = v.w;
    }
    merge16(A, S);
  }
  int* op = idxout + e * 16;
#pragma unroll
  for (int i = 0; i < 4; ++i) {
    int4 o = make_int4((int)(A[i * 4] & 8191u), (int)(A[i * 4 + 1] & 8191u),
                       (int)(A[i * 4 + 2] & 8191u), (int)(A[i * 4 + 3] & 8191u));
    *(int4*)&op[i * 4] = o;
  }
}

// ---------------------------------------------------------------------------
// Fused attention (r6/r9 structure + swapped GEMM2 epilogue): wave-local,
// 2 points per wave, f2 read directly from global. GEMM2 computes
// D = vin^T . Wv^T so each lane holds v[m=mt*16+l15][s=l4*4+r]; the
// sum-over-s becomes 4 local adds + 2 shuffles (was a 4-step tree per reg),
// ev2 params load once per mt, and stores are coalesced 64B segments.
__device__ __forceinline__ float4 ld_enc(const float* encS, int e, int c) {
  int xe = e ^ ((c >> 3) & 3);
  return *(const float4*)&encS[c * 16 + xe * 4];
}

__global__ __launch_bounds__(256, 2)
void k_attn(const float4* __restrict__ px1, const float4* __restrict__ px2,
            const float* __restrict__ f1p, const u16* __restrict__ f2p,
            const int* __restrict__ idxb,
            const u16* __restrict__ wq, const u16* __restrict__ wvm,
            const float* __restrict__ eqw, const float* __restrict__ eqb,
            const float* __restrict__ ekw, const float* __restrict__ ekb,
            const float* __restrict__ ev1w, const float* __restrict__ ev1b,
            const float* __restrict__ ev2w, const float* __restrict__ ev2b,
            float* __restrict__ outp) {
  const int t = threadIdx.x, bx = blockIdx.x;
  const int b = bx >> 10;              // 1024 blocks per batch
  const int base8 = (bx & 1023) * 8;   // 8 points per block (2 per wave)
  const int w = t >> 6, l = t & 63, l15 = l & 15, l4 = l >> 4;

  __shared__ float encS[128 * 16];     // 8 KB: eq, ek, ev1 (XOR slots)
  __shared__ float f1s[8 * 132];       // 4.2 KB
  __shared__ float4 e3S[128];          // 2 KB: ev2 {w0,w1,w2,b}, stride-4
  __shared__ float4 relS[8 * 16];      // 2 KB: per (pt-in-block, s) {r0,r1,r2,aw}

  // stage encoder params (eq,ek,ev1 in encS; ev2 in e3S) + f1 rows
  for (int i = t; i < 384; i += 256) {
    int e = i >> 7, c = i & 127;
    const float* wsrc = (e == 0) ? eqw : (e == 1) ? ekw : ev1w;
    const float* bsrc = (e == 0) ? eqb : (e == 1) ? ekb : ev1b;
    int xe = e ^ ((c >> 3) & 3);
    float* dst = &encS[c * 16 + xe * 4];
    dst[0] = wsrc[c * 3]; dst[1] = wsrc[c * 3 + 1];
    dst[2] = wsrc[c * 3 + 2]; dst[3] = bsrc[c];
  }
  if (t < 128)
    e3S[t] = make_float4(ev2w[t * 3], ev2w[t * 3 + 1], ev2w[t * 3 + 2], ev2b[t]);
  for (int i = t; i < 1024; i += 256) {
    int p = i >> 7, c = i & 127;
    f1s[p * 132 + c] = f1p[(size_t)(b * NN1 + base8 + p) * 128 + c];
  }

  // per-lane neighbor indices + relative coords (sample = l15)
  const int pt0 = base8 + w * 2, pt1 = pt0 + 1;
  const int j0 = idxb[(b * NN1 + pt0) * 16 + l15];
  const int j1 = idxb[(b * NN1 + pt1) * 16 + l15];
  float4 qc0 = px1[b * NN1 + pt0];
  float4 qc1 = px1[b * NN1 + pt1];
  float4 cc0 = px2[b * NN2 + j0];
  float4 cc1 = px2[b * NN2 + j1];
  float r0[2], r1[2], r2[2];
  r0[0] = cc0.x - qc0.x; r1[0] = cc0.y - qc0.y; r2[0] = cc0.z - qc0.z;
  r0[1] = cc1.x - qc1.x; r1[1] = cc1.y - qc1.y; r2[1] = cc1.z - qc1.z;

  const u16* row0 = f2p + (size_t)(b * NN2 + j0) * 128;
  const u16* row1 = f2p + (size_t)(b * NN2 + j1) * 128;
  __syncthreads();

  // ---- build bq fragments: qin = f1 * leaky(eq.r + b), B-layout ----
  bf16x8 bq[2][4];
#pragma unroll
  for (int ks = 0; ks < 4; ++ks) {
#pragma unroll
    for (int j = 0; j < 8; ++j) {
      int c = ks * 32 + l4 * 8 + j;
      float4 ew = ld_enc(encS, 0, c);
      float f10 = f1s[(w * 2 + 0) * 132 + c];
      float f11 = f1s[(w * 2 + 1) * 132 + c];
      float e0 = leaky(ew.x * r0[0] + ew.y * r1[0] + ew.z * r2[0] + ew.w);
      float e1 = leaky(ew.x * r0[1] + ew.y * r1[1] + ew.z * r2[1] + ew.w);
      bq[0][ks][j] = (short)f2bf(f10 * e0);
      bq[1][ks][j] = (short)f2bf(f11 * e1);
    }
  }

  // ---- GEMM1 (q = Wq @ qin) interleaved with attention dot per mt;
  //      kd rolling 2-deep prefetch ----
  float dp0 = 0.0f, dp1 = 0.0f;
  uint2 kc0 = *(const uint2*)(row0 + l4 * 4);
  uint2 kc1 = *(const uint2*)(row1 + l4 * 4);
#pragma unroll
  for (int mt = 0; mt < 8; ++mt) {
    uint2 kn0 = kc0, kn1 = kc1;
    if (mt < 7) {
      kn0 = *(const uint2*)(row0 + (mt + 1) * 16 + l4 * 4);
      kn1 = *(const uint2*)(row1 + (mt + 1) * 16 + l4 * 4);
    }
    f32x4 a0 = (f32x4){0.f, 0.f, 0.f, 0.f};
    f32x4 a1 = (f32x4){0.f, 0.f, 0.f, 0.f};
#pragma unroll
    for (int ks = 0; ks < 4; ++ks) {
      bf16x8 af = *(const bf16x8*)&wq[(mt * 16 + l15) * 128 + ks * 32 + l4 * 8];
      a0 = __builtin_amdgcn_mfma_f32_16x16x32_bf16(af, bq[0][ks], a0, 0, 0, 0);
      a1 = __builtin_amdgcn_mfma_f32_16x16x32_bf16(af, bq[1][ks], a1, 0, 0, 0);
    }
    float f2v0[4] = { bflo(kc0.x), bfhi(kc0.x), bflo(kc0.y), bfhi(kc0.y) };
    float f2v1[4] = { bflo(kc1.x), bfhi(kc1.x), bflo(kc1.y), bfhi(kc1.y) };
#pragma unroll
    for (int r = 0; r < 4; ++r) {
      int c = mt * 16 + l4 * 4 + r;
      float4 ew = ld_enc(encS, 1, c);
      float ek0 = leaky(ew.x * r0[0] + ew.y * r1[0] + ew.z * r2[0] + ew.w);
      float ek1 = leaky(ew.x * r0[1] + ew.y * r1[1] + ew.z * r2[1] + ew.w);
      dp0 += a0[r] * (f2v0[r] * ek0);
      dp1 += a1[r] * (f2v1[r] * ek1);
    }
    kc0 = kn0; kc1 = kn1;
  }

  // V-path gather (B-layout fragments), issued before softmax to hide latency
  bf16x8 fB[2][4];
#pragma unroll
  for (int ks = 0; ks < 4; ++ks) {
    fB[0][ks] = *(const bf16x8*)(row0 + ks * 32 + l4 * 8);
    fB[1][ks] = *(const bf16x8*)(row1 + ks * 32 + l4 * 8);
  }

  // reduce dot over l4 groups, then 16-lane softmax
  dp0 += __shfl_xor(dp0, 16); dp0 += __shfl_xor(dp0, 32);
  dp1 += __shfl_xor(dp1, 16); dp1 += __shfl_xor(dp1, 32);
  float aw0, aw1;
  {
    float x = dp0 * 0.08838834764831845f;
    float m = x;
#pragma unroll
    for (int o = 1; o < 16; o <<= 1) m = fmaxf(m, __shfl_xor(m, o));
    float e = __expf(x - m);
    float s = e;
#pragma unroll
    for (int o = 1; o < 16; o <<= 1) s += __shfl_xor(s, o);
    aw0 = e / s;
  }
  {
    float x = dp1 * 0.08838834764831845f;
    float m = x;
#pragma unroll
    for (int o = 1; o < 16; o <<= 1) m = fmaxf(m, __shfl_xor(m, o));
    float e = __expf(x - m);
    float s = e;
#pragma unroll
    for (int o = 1; o < 16; o <<= 1) s += __shfl_xor(s, o);
    aw1 = e / s;
  }

  // stage {rel, aw} per (point, sample) for the transposed epilogue.
  // Wave-local write/read: lanes 0-15 cover s = 0..15.
  if (l < 16) {
    relS[(w * 2 + 0) * 16 + l] = make_float4(r0[0], r1[0], r2[0], aw0);
    relS[(w * 2 + 1) * 16 + l] = make_float4(r0[1], r1[1], r2[1], aw1);
  }

  // ---- build bv fragments: vin = f2 * leaky(ev1.r + b) ----
  bf16x8 bv[2][4];
#pragma unroll
  for (int ks = 0; ks < 4; ++ks) {
#pragma unroll
    for (int j = 0; j < 8; ++j) {
      int c = ks * 32 + l4 * 8 + j;
      float4 ew = ld_enc(encS, 2, c);
      float e0 = leaky(ew.x * r0[0] + ew.y * r1[0] + ew.z * r2[0] + ew.w);
      float e1 = leaky(ew.x * r0[1] + ew.y * r1[1] + ew.z * r2[1] + ew.w);
      bv[0][ks][j] = (short)f2bf(bf2f((u16)fB[0][ks][j]) * e0);
      bv[1][ks][j] = (short)f2bf(bf2f((u16)fB[1][ks][j]) * e1);
    }
  }

  // ---- GEMM2 swapped: D = vin^T . Wv^T -> lane holds v[m][s=l4*4+r] ----
#pragma unroll
  for (int mt = 0; mt < 8; ++mt) {
    f32x4 a0 = (f32x4){0.f, 0.f, 0.f, 0.f};
    f32x4 a1 = (f32x4){0.f, 0.f, 0.f, 0.f};
#pragma unroll
    for (int ks = 0; ks < 4; ++ks) {
      // B-fragment: B[k=c][col=m] = Wv[m][c] — same global reads as before.
      bf16x8 bf = *(const bf16x8*)&wvm[(mt * 16 + l15) * 128 + ks * 32 + l4 * 8];
      a0 = __builtin_amdgcn_mfma_f32_16x16x32_bf16(bv[0][ks], bf, a0, 0, 0, 0);
      a1 = __builtin_amdgcn_mfma_f32_16x16x32_bf16(bv[1][ks], bf, a1, 0, 0, 0);
    }
    const int m = mt * 16 + l15;
    float4 ew = e3S[m];                 // one ev2-param load per mt
    float acc0 = 0.0f, acc1 = 0.0f;
#pragma unroll
    for (int r = 0; r < 4; ++r) {
      float4 ra = relS[(w * 2 + 0) * 16 + l4 * 4 + r];   // broadcast in group
      float4 rb = relS[(w * 2 + 1) * 16 + l4 * 4 + r];
      float e0 = leaky(ew.x * ra.x + ew.y * ra.y + ew.z * ra.z + ew.w);
      float e1 = leaky(ew.x * rb.x + ew.y * rb.y + ew.z * rb.z + ew.w);
      acc0 += a0[r] * e0 * ra.w;        // .w carries the softmax weight
      acc1 += a1[r] * e1 * rb.w;
    }
    acc0 += __shfl_xor(acc0, 16); acc0 += __shfl_xor(acc0, 32);
    acc1 += __shfl_xor(acc1, 16); acc1 += __shfl_xor(acc1, 32);
    if (l < 16) {                       // coalesced 64B segment per (mt, pt)
      outp[(size_t)(b * NN1 + pt0) * 128 + m] = acc0 + f1s[(w * 2 + 0) * 132 + m];
      outp[(size_t)(b * NN1 + pt1) * 128 + m] = acc1 + f1s[(w * 2 + 1) * 132 + m];
    }
  }
}

// ---------------------------------------------------------------------------
// FF: h[b][d][n] = ff_w[d,:].feat_new[b][n][:] + ff_b[d]; per-block GN
// partials written non-atomically to pstat[block][8][2].
__global__ __launch_bounds__(256)
void k_ff(const float* __restrict__ xin, const float* __restrict__ ffw,
          const float* __restrict__ ffb, float* __restrict__ hout,
          float* __restrict__ pstat) {
  int t = threadIdx.x, bx = blockIdx.x;
  int b = bx / (NN1 / 32), n0 = (bx % (NN1 / 32)) * 32;
  __shared__ float XT[128][34];
  for (int e = t; e < 4096; e += 256) {
    int c = e & 127, nn = e >> 7;
    XT[c][nn] = xin[(b * NN1 + n0 + nn) * 128 + c];
  }
  __syncthreads();
  int d = t >> 1, nh = t & 1;
  float acc[16];
#pragma unroll
  for (int j = 0; j < 16; ++j) acc[j] = 0.0f;
  for (int c0 = 0; c0 < 128; c0 += 4) {
    float4 w4 = *(const float4*)&ffw[d * 128 + c0];
    const float wa[4] = { w4.x, w4.y, w4.z, w4.w };
#pragma unroll
    for (int k = 0; k < 4; ++k) {
      int c = c0 + k;
#pragma unroll
      for (int j2 = 0; j2 < 8; ++j2) {
        float2 xv = *(const float2*)&XT[c][nh * 16 + j2 * 2];
        acc[j2 * 2 + 0] += wa[k] * xv.x;
        acc[j2 * 2 + 1] += wa[k] * xv.y;
      }
    }
  }
  float bias = ffb[d];
  float ls = 0.0f, lss = 0.0f;
  float out[16];
#pragma unroll
  for (int j = 0; j < 16; ++j) { float h = acc[j] + bias; out[j] = h; ls += h; lss += h * h; }
#pragma unroll
  for (int j4 = 0; j4 < 4; ++j4) {
    float4 o = { out[j4 * 4], out[j4 * 4 + 1], out[j4 * 4 + 2], out[j4 * 4 + 3] };
    *(float4*)&hout[(b * 128 + d) * NN1 + n0 + nh * 16 + j4 * 4] = o;
  }
#pragma unroll
  for (int o = 1; o <= 16; o <<= 1) { ls += __shfl_xor(ls, o); lss += __shfl_xor(lss, o); }
  if ((t & 31) == 0) {
    int g = t >> 5;
    pstat[bx * 16 + g * 2 + 0] = ls;
    pstat[bx * 16 + g * 2 + 1] = lss;
  }
}

// Reduce pstat[512][16] -> gnf[2][8][2].
__global__ __launch_bounds__(512)
void k_ffred(const float* __restrict__ pstat, float* __restrict__ gnf) {
  __shared__ float red[512];
  int t = threadIdx.x;
  int b = t >> 8, i = t & 15, chunk = (t >> 4) & 15;
  float s = 0.0f;
#pragma unroll
  for (int k = 0; k < 16; ++k)
    s += pstat[(b * 256 + chunk * 16 + k) * 16 + i];
  red[t] = s;
  __syncthreads();
  if (chunk == 0) {
    float tot = 0.0f;
#pragma unroll
    for (int k2 = 0; k2 < 16; ++k2) tot += red[(b << 8) | (k2 << 4) | i];
    gnf[b * 16 + i] = tot;
  }
}

// Final GN + leaky + f32 store; also writes the xyz1 passthrough (blocks >= 8192).
__global__ __launch_bounds__(256)
void k_final(const float* __restrict__ h, const float* __restrict__ gnf,
             const float* __restrict__ g, const float* __restrict__ bt,
             const float* __restrict__ xyz1, float* __restrict__ out) {
  int bx = blockIdx.x;
  if (bx >= 8192) {
    int e = (bx - 8192) * 256 + threadIdx.x;   // < BB*3*NN1 = 49152
    out[e] = xyz1[e];
    return;
  }
  int e = bx * 256 + threadIdx.x;              // < BB*128*NN1 = 2097152
  int d = (e / NN1) & 127;
  int b = e / (128 * NN1);
  int gi = b * 16 + (d >> 4) * 2;
  float cnt = 16.0f * (float)NN1;
  float mu = gnf[gi] / cnt;
  float var = gnf[gi + 1] / cnt - mu * mu;
  float rs = rsqrtf(var + 1e-5f);
  float x = (h[e] - mu) * rs * g[d] + bt[d];
  out[BB * 3 * NN1 + e] = leaky(x);
}

// ---------------------------------------------------------------------------
extern "C" void kernel_launch(void* const* d_in, const int* in_sizes, int n_in,
                              void* d_out, int out_size, void* d_ws, size_t ws_size,
                              hipStream_t stream) {
  const float* xyz1   = (const float*)d_in[0];
  const float* xyz2   = (const float*)d_in[1];
  const float* feat1  = (const float*)d_in[2];
  const float* feat2  = (const float*)d_in[3];
  const float* pos_w  = (const float*)d_in[4];
  const float* pos_b  = (const float*)d_in[5];
  const float* pos_g  = (const float*)d_in[6];
  const float* pos_bt = (const float*)d_in[7];
  const float* ek_w   = (const float*)d_in[8];
  const float* ek_b   = (const float*)d_in[9];
  const float* eq_w   = (const float*)d_in[10];
  const float* eq_b   = (const float*)d_in[11];
  const float* ev1_w  = (const float*)d_in[12];
  const float* ev1_b  = (const float*)d_in[13];
  const float* ev2_w  = (const float*)d_in[14];
  const float* ev2_b  = (const float*)d_in[15];
  const float* qk_w   = (const float*)d_in[16];
  const float* v_w    = (const float*)d_in[17];
  const float* ff_w   = (const float*)d_in[18];
  const float* ff_b   = (const float*)d_in[19];
  const float* ff_g   = (const float*)d_in[20];
  const float* ff_bt  = (const float*)d_in[21];
  (void)in_sizes; (void)n_in; (void)out_size; (void)ws_size;

  char* ws = (char*)d_ws;          // ~31 MB used
  float*  feat1p   = (float*)(ws);                        // [B][N1][C] f32   8388608 B
  u16*    feat2pb  = (u16*)  (ws + 8388608);              // [B][N2][C] bf16  4194304 B
  float*  attn_out = (float*)(ws + 12582912);             // feat_new (after knn_tmp dead)
  float*  h_ff     = (float*)(ws + 20971520);             // FF out [B][C][N1]
  u32*    knn_tmp  = (u32*)  (ws + 12582912);             // 16 MiB, consumed pre-attn
  int*    idxb     = (int*)  (ws + 29360128);             // [B][N1][16]      1048576 B
  u16*    wqk      = (u16*)  (ws + 30408704);             // bf16 qk_w        32768 B
  u16*    wv       = (u16*)  (ws + 30441472);             // bf16 v_w         32768 B
  float*  mom      = (float*)(ws + 30474240);             // 36 floats (+pad) 160 B
  float2* gnp      = (float2*)(ws + 30474400);            // 32 float2        256 B
  float*  pstat    = (float*)(ws + 30474656);             // 512*16 floats    32768 B
  float*  gnf      = (float*)(ws + 30507424);             // 32 floats        128 B
  float4* px1      = (float4*)(ws + 30507552);            // [B][N1] packed   262144 B
  float4* px2      = (float4*)(ws + 30769696);            // [B][N2] packed   262144 B

  hipMemsetAsync(mom, 0, 160, stream);
  k_prep<<<256, 256, 0, stream>>>(qk_w, v_w, wqk, wv, xyz1, xyz2, px1, px2, mom);
  k_gnstats<<<1, 512, 0, stream>>>(mom, pos_w, pos_b, gnp);
  k_posenc<<<2048, 256, 0, stream>>>(xyz1, xyz2, feat1, feat2, pos_w, pos_b,
                                     pos_g, pos_bt, gnp, feat1p, feat2pb);
  k_knn1<<<1024, 256, 0, stream>>>(px1, px2, knn_tmp);
  k_knn2<<<64, 256, 0, stream>>>(knn_tmp, idxb);
  k_attn<<<2048, 256, 0, stream>>>(px1, px2, feat1p, feat2pb, idxb, wqk, wv,
                                   eq_w, eq_b, ek_w, ek_b, ev1_w, ev1_b, ev2_w, ev2_b,
                                   attn_out);
  k_ff<<<512, 256, 0, stream>>>(attn_out, ff_w, ff_b, h_ff, pstat);
  k_ffred<<<1, 512, 0, stream>>>(pstat, gnf);
  k_final<<<8384, 256, 0, stream>>>(h_ff, gnf, ff_g, ff_bt, xyz1, (float*)d_out);
}

// Round 13
// 261.692 us; speedup vs baseline: 1.3159x; 1.0225x over previous
//
#include <hip/hip_runtime.h>
#include <hip/hip_bf16.h>

// Problem constants (reference: B,N1,N2,C,COUT,NS = 2,8192,8192,128,128,16)
#define BB  2
#define NN1 8192
#define NN2 8192
#define CC  128
#define SS  16

typedef unsigned short u16;
typedef unsigned int u32;
typedef short bf16x8 __attribute__((ext_vector_type(8)));
typedef float f32x4  __attribute__((ext_vector_type(4)));

__device__ __forceinline__ u16 f2bf(float f) {
  __hip_bfloat16 h = __float2bfloat16(f);      // RNE
  return *(u16*)&h;
}
__device__ __forceinline__ float bf2f(u16 u) {
  union { float f; unsigned int u; } v; v.u = ((unsigned int)u) << 16;
  return v.f;
}
__device__ __forceinline__ float bflo(u32 w) {
  union { float f; unsigned int u; } v; v.u = w << 16; return v.f;
}
__device__ __forceinline__ float bfhi(u32 w) {
  union { float f; unsigned int u; } v; v.u = w & 0xFFFF0000u; return v.f;
}
__device__ __forceinline__ float leaky(float x) { return x >= 0.0f ? x : 0.1f * x; }

// ---------------------------------------------------------------------------
// prep: convert qk_w/v_w to bf16; pack xyz -> float4{x,y,z,|p|2}; accumulate
// per-(cloud,batch) xyz moments (9 sums) for analytic GroupNorm stats.
__global__ __launch_bounds__(256)
void k_prep(const float* __restrict__ qkw, const float* __restrict__ vw,
            u16* __restrict__ oa, u16* __restrict__ ob,
            const float* __restrict__ xyz1, const float* __restrict__ xyz2,
            float4* __restrict__ px1, float4* __restrict__ px2,
            float* __restrict__ mom) {
  int bx = blockIdx.x, t = threadIdx.x;
  if (bx < 128) {
    int e = bx * 256 + t;
    if (e < 16384) oa[e] = f2bf(qkw[e]);
    else ob[e - 16384] = f2bf(vw[e - 16384]);
    return;
  }
  const float* xyz; float4* px; int e, cl;
  if (bx < 192) { e = (bx - 128) * 256 + t; xyz = xyz1; px = px1; cl = 0; }
  else          { e = (bx - 192) * 256 + t; xyz = xyz2; px = px2; cl = 1; }
  int b = e >> 13, n = e & 8191;
  float x = xyz[(b * 3 + 0) * 8192 + n];
  float y = xyz[(b * 3 + 1) * 8192 + n];
  float z = xyz[(b * 3 + 2) * 8192 + n];
  px[e] = make_float4(x, y, z, x * x + y * y + z * z);
  float s0 = x, s1 = y, s2 = z, s3 = x * x, s4 = y * y, s5 = z * z;
  float s6 = x * y, s7 = x * z, s8 = y * z;
#pragma unroll
  for (int o = 1; o < 64; o <<= 1) {
    s0 += __shfl_xor(s0, o); s1 += __shfl_xor(s1, o); s2 += __shfl_xor(s2, o);
    s3 += __shfl_xor(s3, o); s4 += __shfl_xor(s4, o); s5 += __shfl_xor(s5, o);
    s6 += __shfl_xor(s6, o); s7 += __shfl_xor(s7, o); s8 += __shfl_xor(s8, o);
  }
  if ((t & 63) == 0) {
    float* mp = mom + (cl * 2 + b) * 9;
    atomicAdd(&mp[0], s0); atomicAdd(&mp[1], s1); atomicAdd(&mp[2], s2);
    atomicAdd(&mp[3], s3); atomicAdd(&mp[4], s4); atomicAdd(&mp[5], s5);
    atomicAdd(&mp[6], s6); atomicAdd(&mp[7], s7); atomicAdd(&mp[8], s8);
  }
}

// Analytic GN stats for pos-enc.
__global__ __launch_bounds__(512)
void k_gnstats(const float* __restrict__ mom, const float* __restrict__ pw,
               const float* __restrict__ pb, float2* __restrict__ gnp) {
  int t = threadIdx.x;                 // 512: cloud(2) x b(2) x c(128)
  int cl = t >> 8, b = (t >> 7) & 1, c = t & 127;
  const float* M = mom + (cl * 2 + b) * 9;
  const float inv = 1.0f / 8192.0f;
  float mx = M[0] * inv, my = M[1] * inv, mz = M[2] * inv;
  float sxx = M[3] * inv, syy = M[4] * inv, szz = M[5] * inv;
  float sxy = M[6] * inv, sxz = M[7] * inv, syz = M[8] * inv;
  float w0 = pw[c * 3], w1 = pw[c * 3 + 1], w2 = pw[c * 3 + 2], bc = pb[c];
  float wm = w0 * mx + w1 * my + w2 * mz;
  float Eh = wm + bc;
  float wSw = w0 * w0 * sxx + w1 * w1 * syy + w2 * w2 * szz
            + 2.0f * (w0 * w1 * sxy + w0 * w2 * sxz + w1 * w2 * syz);
  float Eh2 = wSw + 2.0f * bc * wm + bc * bc;
#pragma unroll
  for (int o = 1; o < 16; o <<= 1) { Eh += __shfl_xor(Eh, o); Eh2 += __shfl_xor(Eh2, o); }
  if ((c & 15) == 0) {
    float mu = Eh * 0.0625f;
    float var = Eh2 * 0.0625f - mu * mu;
    gnp[cl * 16 + b * 8 + (c >> 4)] = make_float2(mu, rsqrtf(var + 1e-5f));
  }
}

// Fused pos-enc (single pass, both clouds): featp = feat + leaky(GN(W.xyz+b)).
// cloud1 -> f32, cloud2 -> bf16.
__global__ __launch_bounds__(256)
void k_posenc(const float* __restrict__ xyz1, const float* __restrict__ xyz2,
              const float* __restrict__ feat1, const float* __restrict__ feat2,
              const float* __restrict__ pw, const float* __restrict__ pb,
              const float* __restrict__ gam, const float* __restrict__ bet,
              const float2* __restrict__ gnp,
              float* __restrict__ outf, u16* __restrict__ outb) {
  int t = threadIdx.x, bx = blockIdx.x;
  const float* xyz; const float* feat; const float2* gp; int asbf;
  if (bx < 1024) { xyz = xyz1; feat = feat1; gp = gnp;      asbf = 0; }
  else           { xyz = xyz2; feat = feat2; gp = gnp + 16; asbf = 1; bx -= 1024; }
  const int N = 8192;
  int b = bx / 512, n0 = (bx % 512) * 16;
  __shared__ float T[128][17];
  for (int it = 0; it < 8; ++it) {
    int j = t & 15, c = it * 16 + (t >> 4);
    T[c][j] = feat[(b * 128 + c) * N + n0 + j];
  }
  int c = t & 127;
  float w0 = pw[c * 3], w1 = pw[c * 3 + 1], w2 = pw[c * 3 + 2], bc = pb[c];
  float2 g2 = gp[b * 8 + (c >> 4)];
  float gm = gam[c], b2 = bet[c];
  __syncthreads();
  for (int it = 0; it < 8; ++it) {
    int j = it * 2 + (t >> 7);
    int n = n0 + j;
    float xs = xyz[(b * 3 + 0) * N + n];
    float ys = xyz[(b * 3 + 1) * N + n];
    float zs = xyz[(b * 3 + 2) * N + n];
    float hv = w0 * xs + w1 * ys + w2 * zs + bc;
    float xo = (hv - g2.x) * g2.y * gm + b2;
    float r = T[c][j] + leaky(xo);
    if (asbf) outb[(size_t)(b * N + n) * 128 + c] = f2bf(r);
    else      outf[(size_t)(b * N + n) * 128 + c] = r;
  }
}

// ---------------------------------------------------------------------------
// KNN, wave-per-query with ballot filtering. Packed key:
// (f32 distance^2 bits & 0xFFFFE000) | index (13 bits) — smaller key ==
// (smaller distance, then smaller index), matching top_k's stable order.

__device__ __forceinline__ u32 knnkey(float4 qv, float4 c, u32 idx) {
  float m = fmaf(qv.x, c.x, fmaf(qv.y, c.y, qv.z * c.z));
  float d = fmaf(-2.0f, m, qv.w + c.w);
  d = fmaxf(d, 0.0f);
  return (__float_as_uint(d) & 0xFFFFE000u) | idx;
}

__device__ __forceinline__ void ce_x(u32& v, int j, bool up, int l) {
  u32 p = __shfl_xor(v, j);
  u32 mn = v < p ? v : p;
  u32 mx = v < p ? p : v;
  bool lower = ((l & j) == 0);
  v = (lower == up) ? mn : mx;
}

// Bitonic sort of 128 keys (2 regs/lane, element i = reg*64 + lane), ascending.
__device__ __forceinline__ void sort128(u32& v0, u32& v1, int l) {
#pragma unroll
  for (int k = 2; k <= 64; k <<= 1) {
#pragma unroll
    for (int j = k >> 1; j > 0; j >>= 1) {
      ce_x(v0, j, ((l & k) == 0), l);
      ce_x(v1, j, (((l + 64) & k) == 0), l);
    }
  }
  // k = 128 merge: j = 64 stage is the in-lane CE (up = true everywhere)
  { u32 mn = v0 < v1 ? v0 : v1; u32 mx = v0 < v1 ? v1 : v0; v0 = mn; v1 = mx; }
#pragma unroll
  for (int j = 32; j > 0; j >>= 1) {
    ce_x(v0, j, true, l);
    ce_x(v1, j, true, l);
  }
}

// One wave per query; lanes scan 64 candidates/batch. Survivors (key < kth)
// are compacted into a 128-slot LDS buffer; wave-bitonic sort refreshes the
// top-16 + kth when the buffer passes 64. ~200 survivors per query total.
__global__ __launch_bounds__(256)
void k_knn(const float4* __restrict__ px1, const float4* __restrict__ px2,
           int* __restrict__ idxout) {
  __shared__ u32 buf[4][128];
  int t = threadIdx.x, w = t >> 6, l = t & 63;
  int q = blockIdx.x * 4 + w;          // 0..16383
  int b = q >> 13;
  float4 qv = px1[q];
  const float4* cp = px2 + (b << 13);
  u32* wb = buf[w];
  u32 kth = 0xFFFFFFFFu;
  int cnt = 0;
  const unsigned long long below = (1ull << l) - 1ull;
  for (int it = 0; it < 128; ++it) {
    float4 c = cp[it * 64 + l];
    u32 key = knnkey(qv, c, (u32)(it * 64 + l));
    bool pass = key < kth;
    unsigned long long mask = __ballot(pass);
    if (mask) {
      int off = cnt + (int)__popcll(mask & below);
      if (pass) wb[off] = key;
      cnt += (int)__popcll(mask);
      if (cnt > 64) {                  // before append cnt<=64 -> cnt<=128 here
        u32 v0 = (l < cnt) ? wb[l] : 0xFFFFFFFFu;
        u32 v1 = (64 + l < cnt) ? wb[64 + l] : 0xFFFFFFFFu;
        sort128(v0, v1, l);
        if (l < 16) wb[l] = v0;
        cnt = 16;
        kth = __shfl(v0, 15);
      }
    }
  }
  u32 v0 = (l < cnt) ? wb[l] : 0xFFFFFFFFu;
  u32 v1 = (64 + l < cnt) ? wb[64 + l] : 0xFFFFFFFFu;
  sort128(v0, v1, l);
  if (l < 16) idxout[q * 16 + l] = (int)(v0 & 8191u);
}

// ---------------------------------------------------------------------------
// Fused attention (r6/r9 structure + swapped GEMM2 epilogue): wave-local,
// 2 points per wave, f2 read directly from global. GEMM2 computes
// D = vin^T . Wv^T so each lane holds v[m=mt*16+l15][s=l4*4+r]; the
// sum-over-s becomes 4 local adds + 2 shuffles, ev2 params load once per mt,
// and stores are coalesced 64B segments.
__device__ __forceinline__ float4 ld_enc(const float* encS, int e, int c) {
  int xe = e ^ ((c >> 3) & 3);
  return *(const float4*)&encS[c * 16 + xe * 4];
}

__global__ __launch_bounds__(256, 2)
void k_attn(const float4* __restrict__ px1, const float4* __restrict__ px2,
            const float* __restrict__ f1p, const u16* __restrict__ f2p,
            const int* __restrict__ idxb,
            const u16* __restrict__ wq, const u16* __restrict__ wvm,
            const float* __restrict__ eqw, const float* __restrict__ eqb,
            const float* __restrict__ ekw, const float* __restrict__ ekb,
            const float* __restrict__ ev1w, const float* __restrict__ ev1b,
            const float* __restrict__ ev2w, const float* __restrict__ ev2b,
            float* __restrict__ outp) {
  const int t = threadIdx.x, bx = blockIdx.x;
  const int b = bx >> 10;              // 1024 blocks per batch
  const int base8 = (bx & 1023) * 8;   // 8 points per block (2 per wave)
  const int w = t >> 6, l = t & 63, l15 = l & 15, l4 = l >> 4;

  __shared__ float encS[128 * 16];     // 8 KB: eq, ek, ev1 (XOR slots)
  __shared__ float f1s[8 * 132];       // 4.2 KB
  __shared__ float4 e3S[128];          // 2 KB: ev2 {w0,w1,w2,b}, stride-4
  __shared__ float4 relS[8 * 16];      // 2 KB: per (pt-in-block, s) {r0,r1,r2,aw}

  // stage encoder params (eq,ek,ev1 in encS; ev2 in e3S) + f1 rows
  for (int i = t; i < 384; i += 256) {
    int e = i >> 7, c = i & 127;
    const float* wsrc = (e == 0) ? eqw : (e == 1) ? ekw : ev1w;
    const float* bsrc = (e == 0) ? eqb : (e == 1) ? ekb : ev1b;
    int xe = e ^ ((c >> 3) & 3);
    float* dst = &encS[c * 16 + xe * 4];
    dst[0] = wsrc[c * 3]; dst[1] = wsrc[c * 3 + 1];
    dst[2] = wsrc[c * 3 + 2]; dst[3] = bsrc[c];
  }
  if (t < 128)
    e3S[t] = make_float4(ev2w[t * 3], ev2w[t * 3 + 1], ev2w[t * 3 + 2], ev2b[t]);
  for (int i = t; i < 1024; i += 256) {
    int p = i >> 7, c = i & 127;
    f1s[p * 132 + c] = f1p[(size_t)(b * NN1 + base8 + p) * 128 + c];
  }

  // per-lane neighbor indices + relative coords (sample = l15)
  const int pt0 = base8 + w * 2, pt1 = pt0 + 1;
  const int j0 = idxb[(b * NN1 + pt0) * 16 + l15];
  const int j1 = idxb[(b * NN1 + pt1) * 16 + l15];
  float4 qc0 = px1[b * NN1 + pt0];
  float4 qc1 = px1[b * NN1 + pt1];
  float4 cc0 = px2[b * NN2 + j0];
  float4 cc1 = px2[b * NN2 + j1];
  float r0[2], r1[2], r2[2];
  r0[0] = cc0.x - qc0.x; r1[0] = cc0.y - qc0.y; r2[0] = cc0.z - qc0.z;
  r0[1] = cc1.x - qc1.x; r1[1] = cc1.y - qc1.y; r2[1] = cc1.z - qc1.z;

  const u16* row0 = f2p + (size_t)(b * NN2 + j0) * 128;
  const u16* row1 = f2p + (size_t)(b * NN2 + j1) * 128;
  __syncthreads();

  // ---- build bq fragments: qin = f1 * leaky(eq.r + b), B-layout ----
  bf16x8 bq[2][4];
#pragma unroll
  for (int ks = 0; ks < 4; ++ks) {
#pragma unroll
    for (int j = 0; j < 8; ++j) {
      int c = ks * 32 + l4 * 8 + j;
      float4 ew = ld_enc(encS, 0, c);
      float f10 = f1s[(w * 2 + 0) * 132 + c];
      float f11 = f1s[(w * 2 + 1) * 132 + c];
      float e0 = leaky(ew.x * r0[0] + ew.y * r1[0] + ew.z * r2[0] + ew.w);
      float e1 = leaky(ew.x * r0[1] + ew.y * r1[1] + ew.z * r2[1] + ew.w);
      bq[0][ks][j] = (short)f2bf(f10 * e0);
      bq[1][ks][j] = (short)f2bf(f11 * e1);
    }
  }

  // ---- GEMM1 (q = Wq @ qin) interleaved with attention dot per mt;
  //      kd rolling 2-deep prefetch ----
  float dp0 = 0.0f, dp1 = 0.0f;
  uint2 kc0 = *(const uint2*)(row0 + l4 * 4);
  uint2 kc1 = *(const uint2*)(row1 + l4 * 4);
#pragma unroll
  for (int mt = 0; mt < 8; ++mt) {
    uint2 kn0 = kc0, kn1 = kc1;
    if (mt < 7) {
      kn0 = *(const uint2*)(row0 + (mt + 1) * 16 + l4 * 4);
      kn1 = *(const uint2*)(row1 + (mt + 1) * 16 + l4 * 4);
    }
    f32x4 a0 = (f32x4){0.f, 0.f, 0.f, 0.f};
    f32x4 a1 = (f32x4){0.f, 0.f, 0.f, 0.f};
#pragma unroll
    for (int ks = 0; ks < 4; ++ks) {
      bf16x8 af = *(const bf16x8*)&wq[(mt * 16 + l15) * 128 + ks * 32 + l4 * 8];
      a0 = __builtin_amdgcn_mfma_f32_16x16x32_bf16(af, bq[0][ks], a0, 0, 0, 0);
      a1 = __builtin_amdgcn_mfma_f32_16x16x32_bf16(af, bq[1][ks], a1, 0, 0, 0);
    }
    float f2v0[4] = { bflo(kc0.x), bfhi(kc0.x), bflo(kc0.y), bfhi(kc0.y) };
    float f2v1[4] = { bflo(kc1.x), bfhi(kc1.x), bflo(kc1.y), bfhi(kc1.y) };
#pragma unroll
    for (int r = 0; r < 4; ++r) {
      int c = mt * 16 + l4 * 4 + r;
      float4 ew = ld_enc(encS, 1, c);
      float ek0 = leaky(ew.x * r0[0] + ew.y * r1[0] + ew.z * r2[0] + ew.w);
      float ek1 = leaky(ew.x * r0[1] + ew.y * r1[1] + ew.z * r2[1] + ew.w);
      dp0 += a0[r] * (f2v0[r] * ek0);
      dp1 += a1[r] * (f2v1[r] * ek1);
    }
    kc0 = kn0; kc1 = kn1;
  }

  // V-path gather (B-layout fragments), issued before softmax to hide latency
  bf16x8 fB[2][4];
#pragma unroll
  for (int ks = 0; ks < 4; ++ks) {
    fB[0][ks] = *(const bf16x8*)(row0 + ks * 32 + l4 * 8);
    fB[1][ks] = *(const bf16x8*)(row1 + ks * 32 + l4 * 8);
  }

  // reduce dot over l4 groups, then 16-lane softmax
  dp0 += __shfl_xor(dp0, 16); dp0 += __shfl_xor(dp0, 32);
  dp1 += __shfl_xor(dp1, 16); dp1 += __shfl_xor(dp1, 32);
  float aw0, aw1;
  {
    float x = dp0 * 0.08838834764831845f;
    float m = x;
#pragma unroll
    for (int o = 1; o < 16; o <<= 1) m = fmaxf(m, __shfl_xor(m, o));
    float e = __expf(x - m);
    float s = e;
#pragma unroll
    for (int o = 1; o < 16; o <<= 1) s += __shfl_xor(s, o);
    aw0 = e / s;
  }
  {
    float x = dp1 * 0.08838834764831845f;
    float m = x;
#pragma unroll
    for (int o = 1; o < 16; o <<= 1) m = fmaxf(m, __shfl_xor(m, o));
    float e = __expf(x - m);
    float s = e;
#pragma unroll
    for (int o = 1; o < 16; o <<= 1) s += __shfl_xor(s, o);
    aw1 = e / s;
  }

  // stage {rel, aw} per (point, sample) for the transposed epilogue.
  if (l < 16) {
    relS[(w * 2 + 0) * 16 + l] = make_float4(r0[0], r1[0], r2[0], aw0);
    relS[(w * 2 + 1) * 16 + l] = make_float4(r0[1], r1[1], r2[1], aw1);
  }

  // ---- build bv fragments: vin = f2 * leaky(ev1.r + b) ----
  bf16x8 bv[2][4];
#pragma unroll
  for (int ks = 0; ks < 4; ++ks) {
#pragma unroll
    for (int j = 0; j < 8; ++j) {
      int c = ks * 32 + l4 * 8 + j;
      float4 ew = ld_enc(encS, 2, c);
      float e0 = leaky(ew.x * r0[0] + ew.y * r1[0] + ew.z * r2[0] + ew.w);
      float e1 = leaky(ew.x * r0[1] + ew.y * r1[1] + ew.z * r2[1] + ew.w);
      bv[0][ks][j] = (short)f2bf(bf2f((u16)fB[0][ks][j]) * e0);
      bv[1][ks][j] = (short)f2bf(bf2f((u16)fB[1][ks][j]) * e1);
    }
  }

  // ---- GEMM2 swapped: D = vin^T . Wv^T -> lane holds v[m][s=l4*4+r] ----
#pragma unroll
  for (int mt = 0; mt < 8; ++mt) {
    f32x4 a0 = (f32x4){0.f, 0.f, 0.f, 0.f};
    f32x4 a1 = (f32x4){0.f, 0.f, 0.f, 0.f};
#pragma unroll
    for (int ks = 0; ks < 4; ++ks) {
      bf16x8 bf = *(const bf16x8*)&wvm[(mt * 16 + l15) * 128 + ks * 32 + l4 * 8];
      a0 = __builtin_amdgcn_mfma_f32_16x16x32_bf16(bv[0][ks], bf, a0, 0, 0, 0);
      a1 = __builtin_amdgcn_mfma_f32_16x16x32_bf16(bv[1][ks], bf, a1, 0, 0, 0);
    }
    const int m = mt * 16 + l15;
    float4 ew = e3S[m];                 // one ev2-param load per mt
    float acc0 = 0.0f, acc1 = 0.0f;
#pragma unroll
    for (int r = 0; r < 4; ++r) {
      float4 ra = relS[(w * 2 + 0) * 16 + l4 * 4 + r];   // broadcast in group
      float4 rb = relS[(w * 2 + 1) * 16 + l4 * 4 + r];
      float e0 = leaky(ew.x * ra.x + ew.y * ra.y + ew.z * ra.z + ew.w);
      float e1 = leaky(ew.x * rb.x + ew.y * rb.y + ew.z * rb.z + ew.w);
      acc0 += a0[r] * e0 * ra.w;        // .w carries the softmax weight
      acc1 += a1[r] * e1 * rb.w;
    }
    acc0 += __shfl_xor(acc0, 16); acc0 += __shfl_xor(acc0, 32);
    acc1 += __shfl_xor(acc1, 16); acc1 += __shfl_xor(acc1, 32);
    if (l < 16) {                       // coalesced 64B segment per (mt, pt)
      outp[(size_t)(b * NN1 + pt0) * 128 + m] = acc0 + f1s[(w * 2 + 0) * 132 + m];
      outp[(size_t)(b * NN1 + pt1) * 128 + m] = acc1 + f1s[(w * 2 + 1) * 132 + m];
    }
  }
}

// ---------------------------------------------------------------------------
// FF: h[b][d][n] = ff_w[d,:].feat_new[b][n][:] + ff_b[d]; per-block GN
// partials written non-atomically to pstat[block][8][2].
__global__ __launch_bounds__(256)
void k_ff(const float* __restrict__ xin, const float* __restrict__ ffw,
          const float* __restrict__ ffb, float* __restrict__ hout,
          float* __restrict__ pstat) {
  int t = threadIdx.x, bx = blockIdx.x;
  int b = bx / (NN1 / 32), n0 = (bx % (NN1 / 32)) * 32;
  __shared__ float XT[128][34];
  for (int e = t; e < 4096; e += 256) {
    int c = e & 127, nn = e >> 7;
    XT[c][nn] = xin[(b * NN1 + n0 + nn) * 128 + c];
  }
  __syncthreads();
  int d = t >> 1, nh = t & 1;
  float acc[16];
#pragma unroll
  for (int j = 0; j < 16; ++j) acc[j] = 0.0f;
  for (int c0 = 0; c0 < 128; c0 += 4) {
    float4 w4 = *(const float4*)&ffw[d * 128 + c0];
    const float wa[4] = { w4.x, w4.y, w4.z, w4.w };
#pragma unroll
    for (int k = 0; k < 4; ++k) {
      int c = c0 + k;
#pragma unroll
      for (int j2 = 0; j2 < 8; ++j2) {
        float2 xv = *(const float2*)&XT[c][nh * 16 + j2 * 2];
        acc[j2 * 2 + 0] += wa[k] * xv.x;
        acc[j2 * 2 + 1] += wa[k] * xv.y;
      }
    }
  }
  float bias = ffb[d];
  float ls = 0.0f, lss = 0.0f;
  float out[16];
#pragma unroll
  for (int j = 0; j < 16; ++j) { float h = acc[j] + bias; out[j] = h; ls += h; lss += h * h; }
#pragma unroll
  for (int j4 = 0; j4 < 4; ++j4) {
    float4 o = { out[j4 * 4], out[j4 * 4 + 1], out[j4 * 4 + 2], out[j4 * 4 + 3] };
    *(float4*)&hout[(b * 128 + d) * NN1 + n0 + nh * 16 + j4 * 4] = o;
  }
#pragma unroll
  for (int o = 1; o <= 16; o <<= 1) { ls += __shfl_xor(ls, o); lss += __shfl_xor(lss, o); }
  if ((t & 31) == 0) {
    int g = t >> 5;
    pstat[bx * 16 + g * 2 + 0] = ls;
    pstat[bx * 16 + g * 2 + 1] = lss;
  }
}

// Reduce pstat[512][16] -> gnf[2][8][2].
__global__ __launch_bounds__(512)
void k_ffred(const float* __restrict__ pstat, float* __restrict__ gnf) {
  __shared__ float red[512];
  int t = threadIdx.x;
  int b = t >> 8, i = t & 15, chunk = (t >> 4) & 15;
  float s = 0.0f;
#pragma unroll
  for (int k = 0; k < 16; ++k)
    s += pstat[(b * 256 + chunk * 16 + k) * 16 + i];
  red[t] = s;
  __syncthreads();
  if (chunk == 0) {
    float tot = 0.0f;
#pragma unroll
    for (int k2 = 0; k2 < 16; ++k2) tot += red[(b << 8) | (k2 << 4) | i];
    gnf[b * 16 + i] = tot;
  }
}

// Final GN + leaky + f32 store; also writes the xyz1 passthrough (blocks >= 8192).
__global__ __launch_bounds__(256)
void k_final(const float* __restrict__ h, const float* __restrict__ gnf,
             const float* __restrict__ g, const float* __restrict__ bt,
             const float* __restrict__ xyz1, float* __restrict__ out) {
  int bx = blockIdx.x;
  if (bx >= 8192) {
    int e = (bx - 8192) * 256 + threadIdx.x;   // < BB*3*NN1 = 49152
    out[e] = xyz1[e];
    return;
  }
  int e = bx * 256 + threadIdx.x;              // < BB*128*NN1 = 2097152
  int d = (e / NN1) & 127;
  int b = e / (128 * NN1);
  int gi = b * 16 + (d >> 4) * 2;
  float cnt = 16.0f * (float)NN1;
  float mu = gnf[gi] / cnt;
  float var = gnf[gi + 1] / cnt - mu * mu;
  float rs = rsqrtf(var + 1e-5f);
  float x = (h[e] - mu) * rs * g[d] + bt[d];
  out[BB * 3 * NN1 + e] = leaky(x);
}

// ---------------------------------------------------------------------------
extern "C" void kernel_launch(void* const* d_in, const int* in_sizes, int n_in,
                              void* d_out, int out_size, void* d_ws, size_t ws_size,
                              hipStream_t stream) {
  const float* xyz1   = (const float*)d_in[0];
  const float* xyz2   = (const float*)d_in[1];
  const float* feat1  = (const float*)d_in[2];
  const float* feat2  = (const float*)d_in[3];
  const float* pos_w  = (const float*)d_in[4];
  const float* pos_b  = (const float*)d_in[5];
  const float* pos_g  = (const float*)d_in[6];
  const float* pos_bt = (const float*)d_in[7];
  const float* ek_w   = (const float*)d_in[8];
  const float* ek_b   = (const float*)d_in[9];
  const float* eq_w   = (const float*)d_in[10];
  const float* eq_b   = (const float*)d_in[11];
  const float* ev1_w  = (const float*)d_in[12];
  const float* ev1_b  = (const float*)d_in[13];
  const float* ev2_w  = (const float*)d_in[14];
  const float* ev2_b  = (const float*)d_in[15];
  const float* qk_w   = (const float*)d_in[16];
  const float* v_w    = (const float*)d_in[17];
  const float* ff_w   = (const float*)d_in[18];
  const float* ff_b   = (const float*)d_in[19];
  const float* ff_g   = (const float*)d_in[20];
  const float* ff_bt  = (const float*)d_in[21];
  (void)in_sizes; (void)n_in; (void)out_size; (void)ws_size;

  char* ws = (char*)d_ws;          // ~31 MB used
  float*  feat1p   = (float*)(ws);                        // [B][N1][C] f32   8388608 B
  u16*    feat2pb  = (u16*)  (ws + 8388608);              // [B][N2][C] bf16  4194304 B
  float*  attn_out = (float*)(ws + 12582912);             // feat_new [B][N1][C]
  float*  h_ff     = (float*)(ws + 20971520);             // FF out [B][C][N1]
  int*    idxb     = (int*)  (ws + 29360128);             // [B][N1][16]      1048576 B
  u16*    wqk      = (u16*)  (ws + 30408704);             // bf16 qk_w        32768 B
  u16*    wv       = (u16*)  (ws + 30441472);             // bf16 v_w         32768 B
  float*  mom      = (float*)(ws + 30474240);             // 36 floats (+pad) 160 B
  float2* gnp      = (float2*)(ws + 30474400);            // 32 float2        256 B
  float*  pstat    = (float*)(ws + 30474656);             // 512*16 floats    32768 B
  float*  gnf      = (float*)(ws + 30507424);             // 32 floats        128 B
  float4* px1      = (float4*)(ws + 30507552);            // [B][N1] packed   262144 B
  float4* px2      = (float4*)(ws + 30769696);            // [B][N2] packed   262144 B

  hipMemsetAsync(mom, 0, 160, stream);
  k_prep<<<256, 256, 0, stream>>>(qk_w, v_w, wqk, wv, xyz1, xyz2, px1, px2, mom);
  k_gnstats<<<1, 512, 0, stream>>>(mom, pos_w, pos_b, gnp);
  k_posenc<<<2048, 256, 0, stream>>>(xyz1, xyz2, feat1, feat2, pos_w, pos_b,
                                     pos_g, pos_bt, gnp, feat1p, feat2pb);
  k_knn<<<4096, 256, 0, stream>>>(px1, px2, idxb);
  k_attn<<<2048, 256, 0, stream>>>(px1, px2, feat1p, feat2pb, idxb, wqk, wv,
                                   eq_w, eq_b, ek_w, ek_b, ev1_w, ev1_b, ev2_w, ev2_b,
                                   attn_out);
  k_ff<<<512, 256, 0, stream>>>(attn_out, ff_w, ff_b, h_ff, pstat);
  k_ffred<<<1, 512, 0, stream>>>(pstat, gnf);
  k_final<<<8384, 256, 0, stream>>>(h_ff, gnf, ff_g, ff_bt, xyz1, (float*)d_out);
}

// Round 14
// 216.544 us; speedup vs baseline: 1.5902x; 1.2085x over previous
//
#include <hip/hip_runtime.h>
#include <hip/hip_bf16.h>

// Problem constants (reference: B,N1,N2,C,COUT,NS = 2,8192,8192,128,128,16)
#define BB  2
#define NN1 8192
#define NN2 8192
#define CC  128
#define SS  16

typedef unsigned short u16;
typedef unsigned int u32;
typedef short bf16x8 __attribute__((ext_vector_type(8)));
typedef float f32x4  __attribute__((ext_vector_type(4)));

__device__ __forceinline__ u16 f2bf(float f) {
  __hip_bfloat16 h = __float2bfloat16(f);      // RNE
  return *(u16*)&h;
}
__device__ __forceinline__ float bf2f(u16 u) {
  union { float f; unsigned int u; } v; v.u = ((unsigned int)u) << 16;
  return v.f;
}
__device__ __forceinline__ float bflo(u32 w) {
  union { float f; unsigned int u; } v; v.u = w << 16; return v.f;
}
__device__ __forceinline__ float bfhi(u32 w) {
  union { float f; unsigned int u; } v; v.u = w & 0xFFFF0000u; return v.f;
}
__device__ __forceinline__ float leaky(float x) { return x >= 0.0f ? x : 0.1f * x; }

// ---------------------------------------------------------------------------
// prep: convert qk_w/v_w to bf16; pack xyz -> float4{x,y,z,|p|2}; write
// per-block xyz-moment partials (9 sums) non-atomically to mom_part[128][9].
__global__ __launch_bounds__(256)
void k_prep(const float* __restrict__ qkw, const float* __restrict__ vw,
            u16* __restrict__ oa, u16* __restrict__ ob,
            const float* __restrict__ xyz1, const float* __restrict__ xyz2,
            float4* __restrict__ px1, float4* __restrict__ px2,
            float* __restrict__ mom_part) {
  int bx = blockIdx.x, t = threadIdx.x;
  if (bx < 128) {
    int e = bx * 256 + t;
    if (e < 16384) oa[e] = f2bf(qkw[e]);
    else ob[e - 16384] = f2bf(vw[e - 16384]);
    return;
  }
  __shared__ float wred[4][9];
  const float* xyz; float4* px; int e;
  if (bx < 192) { e = (bx - 128) * 256 + t; xyz = xyz1; px = px1; }
  else          { e = (bx - 192) * 256 + t; xyz = xyz2; px = px2; }
  int b = e >> 13, n = e & 8191;
  float x = xyz[(b * 3 + 0) * 8192 + n];
  float y = xyz[(b * 3 + 1) * 8192 + n];
  float z = xyz[(b * 3 + 2) * 8192 + n];
  px[e] = make_float4(x, y, z, x * x + y * y + z * z);
  float s[9] = { x, y, z, x * x, y * y, z * z, x * y, x * z, y * z };
#pragma unroll
  for (int o = 1; o < 64; o <<= 1)
#pragma unroll
    for (int i = 0; i < 9; ++i) s[i] += __shfl_xor(s[i], o);
  int w = t >> 6;
  if ((t & 63) == 0)
#pragma unroll
    for (int i = 0; i < 9; ++i) wred[w][i] = s[i];
  __syncthreads();
  if (t < 9) {
    float tot = wred[0][t] + wred[1][t] + wred[2][t] + wred[3][t];
    mom_part[(bx - 128) * 9 + t] = tot;
  }
}

// Analytic GN stats for pos-enc (reduces mom_part itself).
__global__ __launch_bounds__(512)
void k_gnstats(const float* __restrict__ mom_part, const float* __restrict__ pw,
               const float* __restrict__ pb, float2* __restrict__ gnp) {
  int t = threadIdx.x;                 // 512: cloud(2) x b(2) x c(128)
  int cl = t >> 8, b = (t >> 7) & 1, c = t & 127;
  const float* P = mom_part + (cl * 64 + b * 32) * 9;
  float M[9];
#pragma unroll
  for (int i = 0; i < 9; ++i) {
    float sum = 0.0f;
    for (int k = 0; k < 32; ++k) sum += P[k * 9 + i];
    M[i] = sum;
  }
  const float inv = 1.0f / 8192.0f;
  float mx = M[0] * inv, my = M[1] * inv, mz = M[2] * inv;
  float sxx = M[3] * inv, syy = M[4] * inv, szz = M[5] * inv;
  float sxy = M[6] * inv, sxz = M[7] * inv, syz = M[8] * inv;
  float w0 = pw[c * 3], w1 = pw[c * 3 + 1], w2 = pw[c * 3 + 2], bc = pb[c];
  float wm = w0 * mx + w1 * my + w2 * mz;
  float Eh = wm + bc;
  float wSw = w0 * w0 * sxx + w1 * w1 * syy + w2 * w2 * szz
            + 2.0f * (w0 * w1 * sxy + w0 * w2 * sxz + w1 * w2 * syz);
  float Eh2 = wSw + 2.0f * bc * wm + bc * bc;
#pragma unroll
  for (int o = 1; o < 16; o <<= 1) { Eh += __shfl_xor(Eh, o); Eh2 += __shfl_xor(Eh2, o); }
  if ((c & 15) == 0) {
    float mu = Eh * 0.0625f;
    float var = Eh2 * 0.0625f - mu * mu;
    gnp[cl * 16 + b * 8 + (c >> 4)] = make_float2(mu, rsqrtf(var + 1e-5f));
  }
}

// ---------------------------------------------------------------------------
// KNN helpers. Packed key: (f32 distance^2 bits & 0xFFFFE000) | index (13b).

__device__ __forceinline__ u32 knnkey(float4 qv, float4 c, u32 idx) {
  float m = fmaf(qv.x, c.x, fmaf(qv.y, c.y, qv.z * c.z));
  float d = fmaf(-2.0f, m, qv.w + c.w);
  d = fmaxf(d, 0.0f);
  return (__float_as_uint(d) & 0xFFFFE000u) | idx;
}

__device__ __forceinline__ void ce_x(u32& v, int j, bool up, int l) {
  u32 p = __shfl_xor(v, j);
  u32 mn = v < p ? v : p;
  u32 mx = v < p ? p : v;
  bool lower = ((l & j) == 0);
  v = (lower == up) ? mn : mx;
}

// Bitonic sort of 128 keys (2 regs/lane, element i = reg*64 + lane), ascending.
__device__ __forceinline__ void sort128(u32& v0, u32& v1, int l) {
#pragma unroll
  for (int k = 2; k <= 64; k <<= 1) {
#pragma unroll
    for (int j = k >> 1; j > 0; j >>= 1) {
      ce_x(v0, j, ((l & k) == 0), l);
      ce_x(v1, j, (((l + 64) & k) == 0), l);
    }
  }
  { u32 mn = v0 < v1 ? v0 : v1; u32 mx = v0 < v1 ? v1 : v0; v0 = mn; v1 = mx; }
#pragma unroll
  for (int j = 32; j > 0; j >>= 1) {
    ce_x(v0, j, true, l);
    ce_x(v1, j, true, l);
  }
}

// ---------------------------------------------------------------------------
// Fused KNN + pos-enc. Blocks [0,4096): KNN (wave-per-query, ballot filter,
// rolling prefetch). Blocks [4096,6144): pos-enc (featp = feat + leaky(GN)).
__global__ __launch_bounds__(256)
void k_pk(const float4* __restrict__ px1, const float4* __restrict__ px2,
          int* __restrict__ idxout,
          const float* __restrict__ xyz1, const float* __restrict__ xyz2,
          const float* __restrict__ feat1, const float* __restrict__ feat2,
          const float* __restrict__ pw, const float* __restrict__ pb,
          const float* __restrict__ gam, const float* __restrict__ bet,
          const float2* __restrict__ gnp,
          float* __restrict__ outf, u16* __restrict__ outb) {
  __shared__ float smem[128 * 17];     // posenc T[128][17]; knn reuses 2KB
  int bx = blockIdx.x, t = threadIdx.x;

  if (bx < 4096) {
    // ---------------- KNN part ----------------
    int w = t >> 6, l = t & 63;
    int q = bx * 4 + w;                // 0..16383
    int b = q >> 13;
    float4 qv = px1[q];
    const float4* cp = px2 + (b << 13);
    u32* wb = ((u32*)smem) + w * 128;
    u32 kth = 0xFFFFFFFFu;
    int cnt = 0;
    const unsigned long long below = (1ull << l) - 1ull;
    float4 c_cur = cp[l];
    for (int it = 0; it < 128; ++it) {
      float4 c_nxt = c_cur;
      if (it < 127) c_nxt = cp[(it + 1) * 64 + l];   // rolling prefetch
      u32 key = knnkey(qv, c_cur, (u32)(it * 64 + l));
      bool pass = key < kth;
      unsigned long long mask = __ballot(pass);
      if (mask) {
        int off = cnt + (int)__popcll(mask & below);
        if (pass) wb[off] = key;
        cnt += (int)__popcll(mask);
        if (cnt > 64) {                // before append cnt<=64 -> cnt<=128 here
          u32 v0 = (l < cnt) ? wb[l] : 0xFFFFFFFFu;
          u32 v1 = (64 + l < cnt) ? wb[64 + l] : 0xFFFFFFFFu;
          sort128(v0, v1, l);
          if (l < 16) wb[l] = v0;
          cnt = 16;
          kth = __shfl(v0, 15);
        }
      }
      c_cur = c_nxt;
    }
    u32 v0 = (l < cnt) ? wb[l] : 0xFFFFFFFFu;
    u32 v1 = (64 + l < cnt) ? wb[64 + l] : 0xFFFFFFFFu;
    sort128(v0, v1, l);
    if (l < 16) idxout[q * 16 + l] = (int)(v0 & 8191u);
    return;
  }

  // ---------------- pos-enc part ----------------
  bx -= 4096;
  const float* xyz; const float* feat; const float2* gp; int asbf;
  if (bx < 1024) { xyz = xyz1; feat = feat1; gp = gnp;      asbf = 0; }
  else           { xyz = xyz2; feat = feat2; gp = gnp + 16; asbf = 1; bx -= 1024; }
  const int N = 8192;
  int b = bx / 512, n0 = (bx % 512) * 16;
  for (int it = 0; it < 8; ++it) {
    int j = t & 15, c = it * 16 + (t >> 4);
    smem[c * 17 + j] = feat[(b * 128 + c) * N + n0 + j];
  }
  int c = t & 127;
  float w0 = pw[c * 3], w1 = pw[c * 3 + 1], w2 = pw[c * 3 + 2], bc = pb[c];
  float2 g2 = gp[b * 8 + (c >> 4)];
  float gm = gam[c], b2 = bet[c];
  __syncthreads();
  for (int it = 0; it < 8; ++it) {
    int j = it * 2 + (t >> 7);
    int n = n0 + j;
    float xs = xyz[(b * 3 + 0) * N + n];
    float ys = xyz[(b * 3 + 1) * N + n];
    float zs = xyz[(b * 3 + 2) * N + n];
    float hv = w0 * xs + w1 * ys + w2 * zs + bc;
    float xo = (hv - g2.x) * g2.y * gm + b2;
    float r = smem[c * 17 + j] + leaky(xo);
    if (asbf) outb[(size_t)(b * N + n) * 128 + c] = f2bf(r);
    else      outf[(size_t)(b * N + n) * 128 + c] = r;
  }
}

// ---------------------------------------------------------------------------
// Fused attention (r12 structure, unchanged): wave-local, 2 points per wave,
// f2 read directly from global; GEMM2 swapped so the epilogue is 2 shuffles.
__device__ __forceinline__ float4 ld_enc(const float* encS, int e, int c) {
  int xe = e ^ ((c >> 3) & 3);
  return *(const float4*)&encS[c * 16 + xe * 4];
}

__global__ __launch_bounds__(256, 2)
void k_attn(const float4* __restrict__ px1, const float4* __restrict__ px2,
            const float* __restrict__ f1p, const u16* __restrict__ f2p,
            const int* __restrict__ idxb,
            const u16* __restrict__ wq, const u16* __restrict__ wvm,
            const float* __restrict__ eqw, const float* __restrict__ eqb,
            const float* __restrict__ ekw, const float* __restrict__ ekb,
            const float* __restrict__ ev1w, const float* __restrict__ ev1b,
            const float* __restrict__ ev2w, const float* __restrict__ ev2b,
            float* __restrict__ outp) {
  const int t = threadIdx.x, bx = blockIdx.x;
  const int b = bx >> 10;              // 1024 blocks per batch
  const int base8 = (bx & 1023) * 8;   // 8 points per block (2 per wave)
  const int w = t >> 6, l = t & 63, l15 = l & 15, l4 = l >> 4;

  __shared__ float encS[128 * 16];     // 8 KB: eq, ek, ev1 (XOR slots)
  __shared__ float f1s[8 * 132];       // 4.2 KB
  __shared__ float4 e3S[128];          // 2 KB: ev2 {w0,w1,w2,b}
  __shared__ float4 relS[8 * 16];      // 2 KB: per (pt, s) {r0,r1,r2,aw}

  for (int i = t; i < 384; i += 256) {
    int e = i >> 7, c = i & 127;
    const float* wsrc = (e == 0) ? eqw : (e == 1) ? ekw : ev1w;
    const float* bsrc = (e == 0) ? eqb : (e == 1) ? ekb : ev1b;
    int xe = e ^ ((c >> 3) & 3);
    float* dst = &encS[c * 16 + xe * 4];
    dst[0] = wsrc[c * 3]; dst[1] = wsrc[c * 3 + 1];
    dst[2] = wsrc[c * 3 + 2]; dst[3] = bsrc[c];
  }
  if (t < 128)
    e3S[t] = make_float4(ev2w[t * 3], ev2w[t * 3 + 1], ev2w[t * 3 + 2], ev2b[t]);
  for (int i = t; i < 1024; i += 256) {
    int p = i >> 7, c = i & 127;
    f1s[p * 132 + c] = f1p[(size_t)(b * NN1 + base8 + p) * 128 + c];
  }

  const int pt0 = base8 + w * 2, pt1 = pt0 + 1;
  const int j0 = idxb[(b * NN1 + pt0) * 16 + l15];
  const int j1 = idxb[(b * NN1 + pt1) * 16 + l15];
  float4 qc0 = px1[b * NN1 + pt0];
  float4 qc1 = px1[b * NN1 + pt1];
  float4 cc0 = px2[b * NN2 + j0];
  float4 cc1 = px2[b * NN2 + j1];
  float r0[2], r1[2], r2[2];
  r0[0] = cc0.x - qc0.x; r1[0] = cc0.y - qc0.y; r2[0] = cc0.z - qc0.z;
  r0[1] = cc1.x - qc1.x; r1[1] = cc1.y - qc1.y; r2[1] = cc1.z - qc1.z;

  const u16* row0 = f2p + (size_t)(b * NN2 + j0) * 128;
  const u16* row1 = f2p + (size_t)(b * NN2 + j1) * 128;
  __syncthreads();

  // ---- bq fragments: qin = f1 * leaky(eq.r + b), B-layout ----
  bf16x8 bq[2][4];
#pragma unroll
  for (int ks = 0; ks < 4; ++ks) {
#pragma unroll
    for (int j = 0; j < 8; ++j) {
      int c = ks * 32 + l4 * 8 + j;
      float4 ew = ld_enc(encS, 0, c);
      float f10 = f1s[(w * 2 + 0) * 132 + c];
      float f11 = f1s[(w * 2 + 1) * 132 + c];
      float e0 = leaky(ew.x * r0[0] + ew.y * r1[0] + ew.z * r2[0] + ew.w);
      float e1 = leaky(ew.x * r0[1] + ew.y * r1[1] + ew.z * r2[1] + ew.w);
      bq[0][ks][j] = (short)f2bf(f10 * e0);
      bq[1][ks][j] = (short)f2bf(f11 * e1);
    }
  }

  // ---- GEMM1 + attention dot per mt; kd rolling 2-deep prefetch ----
  float dp0 = 0.0f, dp1 = 0.0f;
  uint2 kc0 = *(const uint2*)(row0 + l4 * 4);
  uint2 kc1 = *(const uint2*)(row1 + l4 * 4);
#pragma unroll
  for (int mt = 0; mt < 8; ++mt) {
    uint2 kn0 = kc0, kn1 = kc1;
    if (mt < 7) {
      kn0 = *(const uint2*)(row0 + (mt + 1) * 16 + l4 * 4);
      kn1 = *(const uint2*)(row1 + (mt + 1) * 16 + l4 * 4);
    }
    f32x4 a0 = (f32x4){0.f, 0.f, 0.f, 0.f};
    f32x4 a1 = (f32x4){0.f, 0.f, 0.f, 0.f};
#pragma unroll
    for (int ks = 0; ks < 4; ++ks) {
      bf16x8 af = *(const bf16x8*)&wq[(mt * 16 + l15) * 128 + ks * 32 + l4 * 8];
      a0 = __builtin_amdgcn_mfma_f32_16x16x32_bf16(af, bq[0][ks], a0, 0, 0, 0);
      a1 = __builtin_amdgcn_mfma_f32_16x16x32_bf16(af, bq[1][ks], a1, 0, 0, 0);
    }
    float f2v0[4] = { bflo(kc0.x), bfhi(kc0.x), bflo(kc0.y), bfhi(kc0.y) };
    float f2v1[4] = { bflo(kc1.x), bfhi(kc1.x), bflo(kc1.y), bfhi(kc1.y) };
#pragma unroll
    for (int r = 0; r < 4; ++r) {
      int c = mt * 16 + l4 * 4 + r;
      float4 ew = ld_enc(encS, 1, c);
      float ek0 = leaky(ew.x * r0[0] + ew.y * r1[0] + ew.z * r2[0] + ew.w);
      float ek1 = leaky(ew.x * r0[1] + ew.y * r1[1] + ew.z * r2[1] + ew.w);
      dp0 += a0[r] * (f2v0[r] * ek0);
      dp1 += a1[r] * (f2v1[r] * ek1);
    }
    kc0 = kn0; kc1 = kn1;
  }

  // V-path gather, issued before softmax to hide latency
  bf16x8 fB[2][4];
#pragma unroll
  for (int ks = 0; ks < 4; ++ks) {
    fB[0][ks] = *(const bf16x8*)(row0 + ks * 32 + l4 * 8);
    fB[1][ks] = *(const bf16x8*)(row1 + ks * 32 + l4 * 8);
  }

  dp0 += __shfl_xor(dp0, 16); dp0 += __shfl_xor(dp0, 32);
  dp1 += __shfl_xor(dp1, 16); dp1 += __shfl_xor(dp1, 32);
  float aw0, aw1;
  {
    float x = dp0 * 0.08838834764831845f;
    float m = x;
#pragma unroll
    for (int o = 1; o < 16; o <<= 1) m = fmaxf(m, __shfl_xor(m, o));
    float e = __expf(x - m);
    float s = e;
#pragma unroll
    for (int o = 1; o < 16; o <<= 1) s += __shfl_xor(s, o);
    aw0 = e / s;
  }
  {
    float x = dp1 * 0.08838834764831845f;
    float m = x;
#pragma unroll
    for (int o = 1; o < 16; o <<= 1) m = fmaxf(m, __shfl_xor(m, o));
    float e = __expf(x - m);
    float s = e;
#pragma unroll
    for (int o = 1; o < 16; o <<= 1) s += __shfl_xor(s, o);
    aw1 = e / s;
  }

  if (l < 16) {
    relS[(w * 2 + 0) * 16 + l] = make_float4(r0[0], r1[0], r2[0], aw0);
    relS[(w * 2 + 1) * 16 + l] = make_float4(r0[1], r1[1], r2[1], aw1);
  }

  // ---- bv fragments: vin = f2 * leaky(ev1.r + b) ----
  bf16x8 bv[2][4];
#pragma unroll
  for (int ks = 0; ks < 4; ++ks) {
#pragma unroll
    for (int j = 0; j < 8; ++j) {
      int c = ks * 32 + l4 * 8 + j;
      float4 ew = ld_enc(encS, 2, c);
      float e0 = leaky(ew.x * r0[0] + ew.y * r1[0] + ew.z * r2[0] + ew.w);
      float e1 = leaky(ew.x * r0[1] + ew.y * r1[1] + ew.z * r2[1] + ew.w);
      bv[0][ks][j] = (short)f2bf(bf2f((u16)fB[0][ks][j]) * e0);
      bv[1][ks][j] = (short)f2bf(bf2f((u16)fB[1][ks][j]) * e1);
    }
  }

  // ---- GEMM2 swapped: D = vin^T . Wv^T -> lane holds v[m][s=l4*4+r] ----
#pragma unroll
  for (int mt = 0; mt < 8; ++mt) {
    f32x4 a0 = (f32x4){0.f, 0.f, 0.f, 0.f};
    f32x4 a1 = (f32x4){0.f, 0.f, 0.f, 0.f};
#pragma unroll
    for (int ks = 0; ks < 4; ++ks) {
      bf16x8 bf = *(const bf16x8*)&wvm[(mt * 16 + l15) * 128 + ks * 32 + l4 * 8];
      a0 = __builtin_amdgcn_mfma_f32_16x16x32_bf16(bv[0][ks], bf, a0, 0, 0, 0);
      a1 = __builtin_amdgcn_mfma_f32_16x16x32_bf16(bv[1][ks], bf, a1, 0, 0, 0);
    }
    const int m = mt * 16 + l15;
    float4 ew = e3S[m];
    float acc0 = 0.0f, acc1 = 0.0f;
#pragma unroll
    for (int r = 0; r < 4; ++r) {
      float4 ra = relS[(w * 2 + 0) * 16 + l4 * 4 + r];
      float4 rb = relS[(w * 2 + 1) * 16 + l4 * 4 + r];
      float e0 = leaky(ew.x * ra.x + ew.y * ra.y + ew.z * ra.z + ew.w);
      float e1 = leaky(ew.x * rb.x + ew.y * rb.y + ew.z * rb.z + ew.w);
      acc0 += a0[r] * e0 * ra.w;
      acc1 += a1[r] * e1 * rb.w;
    }
    acc0 += __shfl_xor(acc0, 16); acc0 += __shfl_xor(acc0, 32);
    acc1 += __shfl_xor(acc1, 16); acc1 += __shfl_xor(acc1, 32);
    if (l < 16) {
      outp[(size_t)(b * NN1 + pt0) * 128 + m] = acc0 + f1s[(w * 2 + 0) * 132 + m];
      outp[(size_t)(b * NN1 + pt1) * 128 + m] = acc1 + f1s[(w * 2 + 1) * 132 + m];
    }
  }
}

// ---------------------------------------------------------------------------
// FF: h[b][d][n] = ff_w[d,:].feat_new[b][n][:] + ff_b[d]; per-block GN
// partials written non-atomically to pstat[block][8][2].
__global__ __launch_bounds__(256)
void k_ff(const float* __restrict__ xin, const float* __restrict__ ffw,
          const float* __restrict__ ffb, float* __restrict__ hout,
          float* __restrict__ pstat) {
  int t = threadIdx.x, bx = blockIdx.x;
  int b = bx / (NN1 / 32), n0 = (bx % (NN1 / 32)) * 32;
  __shared__ float XT[128][34];
  for (int e = t; e < 4096; e += 256) {
    int c = e & 127, nn = e >> 7;
    XT[c][nn] = xin[(b * NN1 + n0 + nn) * 128 + c];
  }
  __syncthreads();
  int d = t >> 1, nh = t & 1;
  float acc[16];
#pragma unroll
  for (int j = 0; j < 16; ++j) acc[j] = 0.0f;
  for (int c0 = 0; c0 < 128; c0 += 4) {
    float4 w4 = *(const float4*)&ffw[d * 128 + c0];
    const float wa[4] = { w4.x, w4.y, w4.z, w4.w };
#pragma unroll
    for (int k = 0; k < 4; ++k) {
      int c = c0 + k;
#pragma unroll
      for (int j2 = 0; j2 < 8; ++j2) {
        float2 xv = *(const float2*)&XT[c][nh * 16 + j2 * 2];
        acc[j2 * 2 + 0] += wa[k] * xv.x;
        acc[j2 * 2 + 1] += wa[k] * xv.y;
      }
    }
  }
  float bias = ffb[d];
  float ls = 0.0f, lss = 0.0f;
  float out[16];
#pragma unroll
  for (int j = 0; j < 16; ++j) { float h = acc[j] + bias; out[j] = h; ls += h; lss += h * h; }
#pragma unroll
  for (int j4 = 0; j4 < 4; ++j4) {
    float4 o = { out[j4 * 4], out[j4 * 4 + 1], out[j4 * 4 + 2], out[j4 * 4 + 3] };
    *(float4*)&hout[(b * 128 + d) * NN1 + n0 + nh * 16 + j4 * 4] = o;
  }
#pragma unroll
  for (int o = 1; o <= 16; o <<= 1) { ls += __shfl_xor(ls, o); lss += __shfl_xor(lss, o); }
  if ((t & 31) == 0) {
    int g = t >> 5;
    pstat[bx * 16 + g * 2 + 0] = ls;
    pstat[bx * 16 + g * 2 + 1] = lss;
  }
}

// Reduce pstat[512][16] -> gnf[2][8][2].
__global__ __launch_bounds__(512)
void k_ffred(const float* __restrict__ pstat, float* __restrict__ gnf) {
  __shared__ float red[512];
  int t = threadIdx.x;
  int b = t >> 8, i = t & 15, chunk = (t >> 4) & 15;
  float s = 0.0f;
#pragma unroll
  for (int k = 0; k < 16; ++k)
    s += pstat[(b * 256 + chunk * 16 + k) * 16 + i];
  red[t] = s;
  __syncthreads();
  if (chunk == 0) {
    float tot = 0.0f;
#pragma unroll
    for (int k2 = 0; k2 < 16; ++k2) tot += red[(b << 8) | (k2 << 4) | i];
    gnf[b * 16 + i] = tot;
  }
}

// Final GN + leaky + f32 store; also writes the xyz1 passthrough (blocks >= 8192).
__global__ __launch_bounds__(256)
void k_final(const float* __restrict__ h, const float* __restrict__ gnf,
             const float* __restrict__ g, const float* __restrict__ bt,
             const float* __restrict__ xyz1, float* __restrict__ out) {
  int bx = blockIdx.x;
  if (bx >= 8192) {
    int e = (bx - 8192) * 256 + threadIdx.x;   // < BB*3*NN1 = 49152
    out[e] = xyz1[e];
    return;
  }
  int e = bx * 256 + threadIdx.x;              // < BB*128*NN1 = 2097152
  int d = (e / NN1) & 127;
  int b = e / (128 * NN1);
  int gi = b * 16 + (d >> 4) * 2;
  float cnt = 16.0f * (float)NN1;
  float mu = gnf[gi] / cnt;
  float var = gnf[gi + 1] / cnt - mu * mu;
  float rs = rsqrtf(var + 1e-5f);
  float x = (h[e] - mu) * rs * g[d] + bt[d];
  out[BB * 3 * NN1 + e] = leaky(x);
}

// ---------------------------------------------------------------------------
extern "C" void kernel_launch(void* const* d_in, const int* in_sizes, int n_in,
                              void* d_out, int out_size, void* d_ws, size_t ws_size,
                              hipStream_t stream) {
  const float* xyz1   = (const float*)d_in[0];
  const float* xyz2   = (const float*)d_in[1];
  const float* feat1  = (const float*)d_in[2];
  const float* feat2  = (const float*)d_in[3];
  const float* pos_w  = (const float*)d_in[4];
  const float* pos_b  = (const float*)d_in[5];
  const float* pos_g  = (const float*)d_in[6];
  const float* pos_bt = (const float*)d_in[7];
  const float* ek_w   = (const float*)d_in[8];
  const float* ek_b   = (const float*)d_in[9];
  const float* eq_w   = (const float*)d_in[10];
  const float* eq_b   = (const float*)d_in[11];
  const float* ev1_w  = (const float*)d_in[12];
  const float* ev1_b  = (const float*)d_in[13];
  const float* ev2_w  = (const float*)d_in[14];
  const float* ev2_b  = (const float*)d_in[15];
  const float* qk_w   = (const float*)d_in[16];
  const float* v_w    = (const float*)d_in[17];
  const float* ff_w   = (const float*)d_in[18];
  const float* ff_b   = (const float*)d_in[19];
  const float* ff_g   = (const float*)d_in[20];
  const float* ff_bt  = (const float*)d_in[21];
  (void)in_sizes; (void)n_in; (void)out_size; (void)ws_size;

  char* ws = (char*)d_ws;          // ~31 MB used
  float*  feat1p   = (float*)(ws);                        // [B][N1][C] f32   8388608 B
  u16*    feat2pb  = (u16*)  (ws + 8388608);              // [B][N2][C] bf16  4194304 B
  float*  attn_out = (float*)(ws + 12582912);             // feat_new [B][N1][C]
  float*  h_ff     = (float*)(ws + 20971520);             // FF out [B][C][N1]
  int*    idxb     = (int*)  (ws + 29360128);             // [B][N1][16]      1048576 B
  u16*    wqk      = (u16*)  (ws + 30408704);             // bf16 qk_w        32768 B
  u16*    wv       = (u16*)  (ws + 30441472);             // bf16 v_w         32768 B
  float*  mom_part = (float*)(ws + 30474240);             // 128*9 floats     4608 B
  float2* gnp      = (float2*)(ws + 30478848);            // 32 float2        256 B
  float*  pstat    = (float*)(ws + 30479104);             // 512*16 floats    32768 B
  float*  gnf      = (float*)(ws + 30511872);             // 32 floats        128 B
  float4* px1      = (float4*)(ws + 30512000);            // [B][N1] packed   262144 B
  float4* px2      = (float4*)(ws + 30774144);            // [B][N2] packed   262144 B

  k_prep<<<256, 256, 0, stream>>>(qk_w, v_w, wqk, wv, xyz1, xyz2, px1, px2, mom_part);
  k_gnstats<<<1, 512, 0, stream>>>(mom_part, pos_w, pos_b, gnp);
  k_pk<<<6144, 256, 0, stream>>>(px1, px2, idxb, xyz1, xyz2, feat1, feat2,
                                 pos_w, pos_b, pos_g, pos_bt, gnp, feat1p, feat2pb);
  k_attn<<<2048, 256, 0, stream>>>(px1, px2, feat1p, feat2pb, idxb, wqk, wv,
                                   eq_w, eq_b, ek_w, ek_b, ev1_w, ev1_b, ev2_w, ev2_b,
                                   attn_out);
  k_ff<<<512, 256, 0, stream>>>(attn_out, ff_w, ff_b, h_ff, pstat);
  k_ffred<<<1, 512, 0, stream>>>(pstat, gnf);
  k_final<<<8384, 256, 0, stream>>>(h_ff, gnf, ff_g, ff_bt, xyz1, (float*)d_out);
}

// Round 15
// 208.392 us; speedup vs baseline: 1.6524x; 1.0391x over previous
//
#include <hip/hip_runtime.h>
#include <hip/hip_bf16.h>

// Problem constants (reference: B,N1,N2,C,COUT,NS = 2,8192,8192,128,128,16)
#define BB  2
#define NN1 8192
#define NN2 8192
#define CC  128
#define SS  16

typedef unsigned short u16;
typedef unsigned int u32;
typedef short bf16x8 __attribute__((ext_vector_type(8)));
typedef float f32x4  __attribute__((ext_vector_type(4)));

__device__ __forceinline__ u16 f2bf(float f) {
  __hip_bfloat16 h = __float2bfloat16(f);      // RNE
  return *(u16*)&h;
}
__device__ __forceinline__ float bf2f(u16 u) {
  union { float f; unsigned int u; } v; v.u = ((unsigned int)u) << 16;
  return v.f;
}
__device__ __forceinline__ float bflo(u32 w) {
  union { float f; unsigned int u; } v; v.u = w << 16; return v.f;
}
__device__ __forceinline__ float bfhi(u32 w) {
  union { float f; unsigned int u; } v; v.u = w & 0xFFFF0000u; return v.f;
}
__device__ __forceinline__ float leaky(float x) { return x >= 0.0f ? x : 0.1f * x; }

// ---------------------------------------------------------------------------
// prep: convert qk_w/v_w/ff_w to bf16; pack xyz -> float4{x,y,z,|p|2}; write
// per-block xyz-moment partials (9 sums) non-atomically to mom_part[128][9].
__global__ __launch_bounds__(256)
void k_prep(const float* __restrict__ qkw, const float* __restrict__ vw,
            const float* __restrict__ ffw,
            u16* __restrict__ oa, u16* __restrict__ ob, u16* __restrict__ of,
            const float* __restrict__ xyz1, const float* __restrict__ xyz2,
            float4* __restrict__ px1, float4* __restrict__ px2,
            float* __restrict__ mom_part) {
  int bx = blockIdx.x, t = threadIdx.x;
  if (bx < 192) {
    int e = bx * 256 + t;
    if (e < 16384) oa[e] = f2bf(qkw[e]);
    else if (e < 32768) ob[e - 16384] = f2bf(vw[e - 16384]);
    else of[e - 32768] = f2bf(ffw[e - 32768]);
    return;
  }
  __shared__ float wred[4][9];
  const float* xyz; float4* px; int e;
  if (bx < 256) { e = (bx - 192) * 256 + t; xyz = xyz1; px = px1; }
  else          { e = (bx - 256) * 256 + t; xyz = xyz2; px = px2; }
  int b = e >> 13, n = e & 8191;
  float x = xyz[(b * 3 + 0) * 8192 + n];
  float y = xyz[(b * 3 + 1) * 8192 + n];
  float z = xyz[(b * 3 + 2) * 8192 + n];
  px[e] = make_float4(x, y, z, x * x + y * y + z * z);
  float s[9] = { x, y, z, x * x, y * y, z * z, x * y, x * z, y * z };
#pragma unroll
  for (int o = 1; o < 64; o <<= 1)
#pragma unroll
    for (int i = 0; i < 9; ++i) s[i] += __shfl_xor(s[i], o);
  int w = t >> 6;
  if ((t & 63) == 0)
#pragma unroll
    for (int i = 0; i < 9; ++i) wred[w][i] = s[i];
  __syncthreads();
  if (t < 9) {
    float tot = wred[0][t] + wred[1][t] + wred[2][t] + wred[3][t];
    mom_part[(bx - 192) * 9 + t] = tot;
  }
}

// Analytic GN stats for pos-enc (reduces mom_part itself).
__global__ __launch_bounds__(512)
void k_gnstats(const float* __restrict__ mom_part, const float* __restrict__ pw,
               const float* __restrict__ pb, float2* __restrict__ gnp) {
  int t = threadIdx.x;                 // 512: cloud(2) x b(2) x c(128)
  int cl = t >> 8, b = (t >> 7) & 1, c = t & 127;
  const float* P = mom_part + (cl * 64 + b * 32) * 9;
  float M[9];
#pragma unroll
  for (int i = 0; i < 9; ++i) {
    float sum = 0.0f;
    for (int k = 0; k < 32; ++k) sum += P[k * 9 + i];
    M[i] = sum;
  }
  const float inv = 1.0f / 8192.0f;
  float mx = M[0] * inv, my = M[1] * inv, mz = M[2] * inv;
  float sxx = M[3] * inv, syy = M[4] * inv, szz = M[5] * inv;
  float sxy = M[6] * inv, sxz = M[7] * inv, syz = M[8] * inv;
  float w0 = pw[c * 3], w1 = pw[c * 3 + 1], w2 = pw[c * 3 + 2], bc = pb[c];
  float wm = w0 * mx + w1 * my + w2 * mz;
  float Eh = wm + bc;
  float wSw = w0 * w0 * sxx + w1 * w1 * syy + w2 * w2 * szz
            + 2.0f * (w0 * w1 * sxy + w0 * w2 * sxz + w1 * w2 * syz);
  float Eh2 = wSw + 2.0f * bc * wm + bc * bc;
#pragma unroll
  for (int o = 1; o < 16; o <<= 1) { Eh += __shfl_xor(Eh, o); Eh2 += __shfl_xor(Eh2, o); }
  if ((c & 15) == 0) {
    float mu = Eh * 0.0625f;
    float var = Eh2 * 0.0625f - mu * mu;
    gnp[cl * 16 + b * 8 + (c >> 4)] = make_float2(mu, rsqrtf(var + 1e-5f));
  }
}

// ---------------------------------------------------------------------------
// KNN helpers. Packed key: (f32 distance^2 bits & 0xFFFFE000) | index (13b).

__device__ __forceinline__ u32 knnkey(float4 qv, float4 c, u32 idx) {
  float m = fmaf(qv.x, c.x, fmaf(qv.y, c.y, qv.z * c.z));
  float d = fmaf(-2.0f, m, qv.w + c.w);
  d = fmaxf(d, 0.0f);
  return (__float_as_uint(d) & 0xFFFFE000u) | idx;
}

__device__ __forceinline__ void ce_x(u32& v, int j, bool up, int l) {
  u32 p = __shfl_xor(v, j);
  u32 mn = v < p ? v : p;
  u32 mx = v < p ? p : v;
  bool lower = ((l & j) == 0);
  v = (lower == up) ? mn : mx;
}

// Bitonic sort of 128 keys (2 regs/lane, element i = reg*64 + lane), ascending.
__device__ __forceinline__ void sort128(u32& v0, u32& v1, int l) {
#pragma unroll
  for (int k = 2; k <= 64; k <<= 1) {
#pragma unroll
    for (int j = k >> 1; j > 0; j >>= 1) {
      ce_x(v0, j, ((l & k) == 0), l);
      ce_x(v1, j, (((l + 64) & k) == 0), l);
    }
  }
  { u32 mn = v0 < v1 ? v0 : v1; u32 mx = v0 < v1 ? v1 : v0; v0 = mn; v1 = mx; }
#pragma unroll
  for (int j = 32; j > 0; j >>= 1) {
    ce_x(v0, j, true, l);
    ce_x(v1, j, true, l);
  }
}

// ---------------------------------------------------------------------------
// Fused KNN + pos-enc. Blocks [0,4096): KNN (wave-per-query, ballot filter,
// rolling prefetch). Blocks [4096,6144): pos-enc (featp = feat + leaky(GN)).
__global__ __launch_bounds__(256)
void k_pk(const float4* __restrict__ px1, const float4* __restrict__ px2,
          int* __restrict__ idxout,
          const float* __restrict__ xyz1, const float* __restrict__ xyz2,
          const float* __restrict__ feat1, const float* __restrict__ feat2,
          const float* __restrict__ pw, const float* __restrict__ pb,
          const float* __restrict__ gam, const float* __restrict__ bet,
          const float2* __restrict__ gnp,
          float* __restrict__ outf, u16* __restrict__ outb) {
  __shared__ float smem[128 * 17];     // posenc T[128][17]; knn reuses 2KB
  int bx = blockIdx.x, t = threadIdx.x;

  if (bx < 4096) {
    // ---------------- KNN part ----------------
    int w = t >> 6, l = t & 63;
    int q = bx * 4 + w;                // 0..16383
    int b = q >> 13;
    float4 qv = px1[q];
    const float4* cp = px2 + (b << 13);
    u32* wb = ((u32*)smem) + w * 128;
    u32 kth = 0xFFFFFFFFu;
    int cnt = 0;
    const unsigned long long below = (1ull << l) - 1ull;
    float4 c_cur = cp[l];
    for (int it = 0; it < 128; ++it) {
      float4 c_nxt = c_cur;
      if (it < 127) c_nxt = cp[(it + 1) * 64 + l];   // rolling prefetch
      u32 key = knnkey(qv, c_cur, (u32)(it * 64 + l));
      bool pass = key < kth;
      unsigned long long mask = __ballot(pass);
      if (mask) {
        int off = cnt + (int)__popcll(mask & below);
        if (pass) wb[off] = key;
        cnt += (int)__popcll(mask);
        if (cnt > 64) {                // before append cnt<=64 -> cnt<=128 here
          u32 v0 = (l < cnt) ? wb[l] : 0xFFFFFFFFu;
          u32 v1 = (64 + l < cnt) ? wb[64 + l] : 0xFFFFFFFFu;
          sort128(v0, v1, l);
          if (l < 16) wb[l] = v0;
          cnt = 16;
          kth = __shfl(v0, 15);
        }
      }
      c_cur = c_nxt;
    }
    u32 v0 = (l < cnt) ? wb[l] : 0xFFFFFFFFu;
    u32 v1 = (64 + l < cnt) ? wb[64 + l] : 0xFFFFFFFFu;
    sort128(v0, v1, l);
    if (l < 16) idxout[q * 16 + l] = (int)(v0 & 8191u);
    return;
  }

  // ---------------- pos-enc part ----------------
  bx -= 4096;
  const float* xyz; const float* feat; const float2* gp; int asbf;
  if (bx < 1024) { xyz = xyz1; feat = feat1; gp = gnp;      asbf = 0; }
  else           { xyz = xyz2; feat = feat2; gp = gnp + 16; asbf = 1; bx -= 1024; }
  const int N = 8192;
  int b = bx / 512, n0 = (bx % 512) * 16;
  for (int it = 0; it < 8; ++it) {
    int j = t & 15, c = it * 16 + (t >> 4);
    smem[c * 17 + j] = feat[(b * 128 + c) * N + n0 + j];
  }
  int c = t & 127;
  float w0 = pw[c * 3], w1 = pw[c * 3 + 1], w2 = pw[c * 3 + 2], bc = pb[c];
  float2 g2 = gp[b * 8 + (c >> 4)];
  float gm = gam[c], b2 = bet[c];
  __syncthreads();
  for (int it = 0; it < 8; ++it) {
    int j = it * 2 + (t >> 7);
    int n = n0 + j;
    float xs = xyz[(b * 3 + 0) * N + n];
    float ys = xyz[(b * 3 + 1) * N + n];
    float zs = xyz[(b * 3 + 2) * N + n];
    float hv = w0 * xs + w1 * ys + w2 * zs + bc;
    float xo = (hv - g2.x) * g2.y * gm + b2;
    float r = smem[c * 17 + j] + leaky(xo);
    if (asbf) outb[(size_t)(b * N + n) * 128 + c] = f2bf(r);
    else      outf[(size_t)(b * N + n) * 128 + c] = r;
  }
}

// ---------------------------------------------------------------------------
// Fused attention: wave-local, 2 points per wave, f2 read from global; GEMM2
// swapped. bv built BEFORE softmax (fB transient) to shrink live registers;
// kd loaded per-mt (no explicit prefetch). Output bf16.
__device__ __forceinline__ float4 ld_enc(const float* encS, int e, int c) {
  int xe = e ^ ((c >> 3) & 3);
  return *(const float4*)&encS[c * 16 + xe * 4];
}

__global__ __launch_bounds__(256, 2)
void k_attn(const float4* __restrict__ px1, const float4* __restrict__ px2,
            const float* __restrict__ f1p, const u16* __restrict__ f2p,
            const int* __restrict__ idxb,
            const u16* __restrict__ wq, const u16* __restrict__ wvm,
            const float* __restrict__ eqw, const float* __restrict__ eqb,
            const float* __restrict__ ekw, const float* __restrict__ ekb,
            const float* __restrict__ ev1w, const float* __restrict__ ev1b,
            const float* __restrict__ ev2w, const float* __restrict__ ev2b,
            u16* __restrict__ outp) {
  const int t = threadIdx.x, bx = blockIdx.x;
  const int b = bx >> 10;              // 1024 blocks per batch
  const int base8 = (bx & 1023) * 8;   // 8 points per block (2 per wave)
  const int w = t >> 6, l = t & 63, l15 = l & 15, l4 = l >> 4;

  __shared__ float encS[128 * 16];     // 8 KB: eq, ek, ev1 (XOR slots)
  __shared__ float f1s[8 * 132];       // 4.2 KB
  __shared__ float4 e3S[128];          // 2 KB: ev2 {w0,w1,w2,b}
  __shared__ float4 relS[8 * 16];      // 2 KB: per (pt, s) {r0,r1,r2,aw}

  for (int i = t; i < 384; i += 256) {
    int e = i >> 7, c = i & 127;
    const float* wsrc = (e == 0) ? eqw : (e == 1) ? ekw : ev1w;
    const float* bsrc = (e == 0) ? eqb : (e == 1) ? ekb : ev1b;
    int xe = e ^ ((c >> 3) & 3);
    float* dst = &encS[c * 16 + xe * 4];
    dst[0] = wsrc[c * 3]; dst[1] = wsrc[c * 3 + 1];
    dst[2] = wsrc[c * 3 + 2]; dst[3] = bsrc[c];
  }
  if (t < 128)
    e3S[t] = make_float4(ev2w[t * 3], ev2w[t * 3 + 1], ev2w[t * 3 + 2], ev2b[t]);
  for (int i = t; i < 1024; i += 256) {
    int p = i >> 7, c = i & 127;
    f1s[p * 132 + c] = f1p[(size_t)(b * NN1 + base8 + p) * 128 + c];
  }

  const int pt0 = base8 + w * 2, pt1 = pt0 + 1;
  const int j0 = idxb[(b * NN1 + pt0) * 16 + l15];
  const int j1 = idxb[(b * NN1 + pt1) * 16 + l15];
  float4 qc0 = px1[b * NN1 + pt0];
  float4 qc1 = px1[b * NN1 + pt1];
  float4 cc0 = px2[b * NN2 + j0];
  float4 cc1 = px2[b * NN2 + j1];
  float r0[2], r1[2], r2[2];
  r0[0] = cc0.x - qc0.x; r1[0] = cc0.y - qc0.y; r2[0] = cc0.z - qc0.z;
  r0[1] = cc1.x - qc1.x; r1[1] = cc1.y - qc1.y; r2[1] = cc1.z - qc1.z;

  const u16* row0 = f2p + (size_t)(b * NN2 + j0) * 128;
  const u16* row1 = f2p + (size_t)(b * NN2 + j1) * 128;
  __syncthreads();

  // ---- bq fragments: qin = f1 * leaky(eq.r + b), B-layout ----
  bf16x8 bq[2][4];
#pragma unroll
  for (int ks = 0; ks < 4; ++ks) {
#pragma unroll
    for (int j = 0; j < 8; ++j) {
      int c = ks * 32 + l4 * 8 + j;
      float4 ew = ld_enc(encS, 0, c);
      float f10 = f1s[(w * 2 + 0) * 132 + c];
      float f11 = f1s[(w * 2 + 1) * 132 + c];
      float e0 = leaky(ew.x * r0[0] + ew.y * r1[0] + ew.z * r2[0] + ew.w);
      float e1 = leaky(ew.x * r0[1] + ew.y * r1[1] + ew.z * r2[1] + ew.w);
      bq[0][ks][j] = (short)f2bf(f10 * e0);
      bq[1][ks][j] = (short)f2bf(f11 * e1);
    }
  }

  // ---- GEMM1 + attention dot per mt (kd loaded per-mt) ----
  float dp0 = 0.0f, dp1 = 0.0f;
#pragma unroll
  for (int mt = 0; mt < 8; ++mt) {
    uint2 kc0 = *(const uint2*)(row0 + mt * 16 + l4 * 4);
    uint2 kc1 = *(const uint2*)(row1 + mt * 16 + l4 * 4);
    f32x4 a0 = (f32x4){0.f, 0.f, 0.f, 0.f};
    f32x4 a1 = (f32x4){0.f, 0.f, 0.f, 0.f};
#pragma unroll
    for (int ks = 0; ks < 4; ++ks) {
      bf16x8 af = *(const bf16x8*)&wq[(mt * 16 + l15) * 128 + ks * 32 + l4 * 8];
      a0 = __builtin_amdgcn_mfma_f32_16x16x32_bf16(af, bq[0][ks], a0, 0, 0, 0);
      a1 = __builtin_amdgcn_mfma_f32_16x16x32_bf16(af, bq[1][ks], a1, 0, 0, 0);
    }
    float f2v0[4] = { bflo(kc0.x), bfhi(kc0.x), bflo(kc0.y), bfhi(kc0.y) };
    float f2v1[4] = { bflo(kc1.x), bfhi(kc1.x), bflo(kc1.y), bfhi(kc1.y) };
#pragma unroll
    for (int r = 0; r < 4; ++r) {
      int c = mt * 16 + l4 * 4 + r;
      float4 ew = ld_enc(encS, 1, c);
      float ek0 = leaky(ew.x * r0[0] + ew.y * r1[0] + ew.z * r2[0] + ew.w);
      float ek1 = leaky(ew.x * r0[1] + ew.y * r1[1] + ew.z * r2[1] + ew.w);
      dp0 += a0[r] * (f2v0[r] * ek0);
      dp1 += a1[r] * (f2v1[r] * ek1);
    }
  }

  // ---- bv fragments BEFORE softmax: vin = f2 * leaky(ev1.r + b); fB
  //      transient (one bf16x8 at a time) to keep live registers low ----
  bf16x8 bv[2][4];
#pragma unroll
  for (int ks = 0; ks < 4; ++ks) {
    bf16x8 fb0 = *(const bf16x8*)(row0 + ks * 32 + l4 * 8);
    bf16x8 fb1 = *(const bf16x8*)(row1 + ks * 32 + l4 * 8);
#pragma unroll
    for (int j = 0; j < 8; ++j) {
      int c = ks * 32 + l4 * 8 + j;
      float4 ew = ld_enc(encS, 2, c);
      float e0 = leaky(ew.x * r0[0] + ew.y * r1[0] + ew.z * r2[0] + ew.w);
      float e1 = leaky(ew.x * r0[1] + ew.y * r1[1] + ew.z * r2[1] + ew.w);
      bv[0][ks][j] = (short)f2bf(bf2f((u16)fb0[j]) * e0);
      bv[1][ks][j] = (short)f2bf(bf2f((u16)fb1[j]) * e1);
    }
  }

  // reduce dot over l4 groups, then 16-lane softmax
  dp0 += __shfl_xor(dp0, 16); dp0 += __shfl_xor(dp0, 32);
  dp1 += __shfl_xor(dp1, 16); dp1 += __shfl_xor(dp1, 32);
  float aw0, aw1;
  {
    float x = dp0 * 0.08838834764831845f;
    float m = x;
#pragma unroll
    for (int o = 1; o < 16; o <<= 1) m = fmaxf(m, __shfl_xor(m, o));
    float e = __expf(x - m);
    float s = e;
#pragma unroll
    for (int o = 1; o < 16; o <<= 1) s += __shfl_xor(s, o);
    aw0 = e / s;
  }
  {
    float x = dp1 * 0.08838834764831845f;
    float m = x;
#pragma unroll
    for (int o = 1; o < 16; o <<= 1) m = fmaxf(m, __shfl_xor(m, o));
    float e = __expf(x - m);
    float s = e;
#pragma unroll
    for (int o = 1; o < 16; o <<= 1) s += __shfl_xor(s, o);
    aw1 = e / s;
  }

  if (l < 16) {
    relS[(w * 2 + 0) * 16 + l] = make_float4(r0[0], r1[0], r2[0], aw0);
    relS[(w * 2 + 1) * 16 + l] = make_float4(r0[1], r1[1], r2[1], aw1);
  }

  // ---- GEMM2 swapped: D = vin^T . Wv^T -> lane holds v[m][s=l4*4+r] ----
#pragma unroll
  for (int mt = 0; mt < 8; ++mt) {
    f32x4 a0 = (f32x4){0.f, 0.f, 0.f, 0.f};
    f32x4 a1 = (f32x4){0.f, 0.f, 0.f, 0.f};
#pragma unroll
    for (int ks = 0; ks < 4; ++ks) {
      bf16x8 bf = *(const bf16x8*)&wvm[(mt * 16 + l15) * 128 + ks * 32 + l4 * 8];
      a0 = __builtin_amdgcn_mfma_f32_16x16x32_bf16(bv[0][ks], bf, a0, 0, 0, 0);
      a1 = __builtin_amdgcn_mfma_f32_16x16x32_bf16(bv[1][ks], bf, a1, 0, 0, 0);
    }
    const int m = mt * 16 + l15;
    float4 ew = e3S[m];
    float acc0 = 0.0f, acc1 = 0.0f;
#pragma unroll
    for (int r = 0; r < 4; ++r) {
      float4 ra = relS[(w * 2 + 0) * 16 + l4 * 4 + r];
      float4 rb = relS[(w * 2 + 1) * 16 + l4 * 4 + r];
      float e0 = leaky(ew.x * ra.x + ew.y * ra.y + ew.z * ra.z + ew.w);
      float e1 = leaky(ew.x * rb.x + ew.y * rb.y + ew.z * rb.z + ew.w);
      acc0 += a0[r] * e0 * ra.w;
      acc1 += a1[r] * e1 * rb.w;
    }
    acc0 += __shfl_xor(acc0, 16); acc0 += __shfl_xor(acc0, 32);
    acc1 += __shfl_xor(acc1, 16); acc1 += __shfl_xor(acc1, 32);
    if (l < 16) {
      outp[(size_t)(b * NN1 + pt0) * 128 + m] =
          f2bf(acc0 + f1s[(w * 2 + 0) * 132 + m]);
      outp[(size_t)(b * NN1 + pt1) * 128 + m] =
          f2bf(acc1 + f1s[(w * 2 + 1) * 132 + m]);
    }
  }
}

// ---------------------------------------------------------------------------
// FF via MFMA: h[b][d][n] = ff_w[d,:].feat_new[b][n][:] + ff_b[d].
// Block = 64 points, wave = 16 points (same fragment pattern as k_attn).
// Per-block GN partials -> pstat[block][8][2].
__global__ __launch_bounds__(256)
void k_ff(const u16* __restrict__ xb, const u16* __restrict__ wfb,
          const float* __restrict__ ffb, float* __restrict__ hout,
          float* __restrict__ pstat) {
  const int t = threadIdx.x, bx = blockIdx.x;
  const int w = t >> 6, l = t & 63, l15 = l & 15, l4 = l >> 4;
  __shared__ float bS[128];
  __shared__ float red[4][16];
  if (t < 128) bS[t] = ffb[t];
  const int pt = bx * 64 + w * 16 + l15;     // global point 0..16383
  const int b = pt >> 13, n = pt & 8191;
  const u16* row = xb + (size_t)pt * 128;
  bf16x8 bfrag[4];
#pragma unroll
  for (int ks = 0; ks < 4; ++ks)
    bfrag[ks] = *(const bf16x8*)(row + ks * 32 + l4 * 8);
  __syncthreads();
  float gs[8], gss[8];
#pragma unroll
  for (int mt = 0; mt < 8; ++mt) {
    f32x4 a = (f32x4){0.f, 0.f, 0.f, 0.f};
#pragma unroll
    for (int ks = 0; ks < 4; ++ks) {
      bf16x8 af = *(const bf16x8*)&wfb[(mt * 16 + l15) * 128 + ks * 32 + l4 * 8];
      a = __builtin_amdgcn_mfma_f32_16x16x32_bf16(af, bfrag[ks], a, 0, 0, 0);
    }
    int d0 = mt * 16 + l4 * 4;
    float s = 0.0f, ss = 0.0f;
#pragma unroll
    for (int r = 0; r < 4; ++r) {
      float h = a[r] + bS[d0 + r];
      hout[(size_t)(b * 128 + d0 + r) * 8192 + n] = h;
      s += h; ss += h * h;
    }
    gs[mt] = s; gss[mt] = ss;
  }
#pragma unroll
  for (int mt = 0; mt < 8; ++mt) {
#pragma unroll
    for (int o = 1; o < 64; o <<= 1) {
      gs[mt] += __shfl_xor(gs[mt], o);
      gss[mt] += __shfl_xor(gss[mt], o);
    }
  }
  if (l == 0) {
#pragma unroll
    for (int mt = 0; mt < 8; ++mt) {
      red[w][mt * 2 + 0] = gs[mt];
      red[w][mt * 2 + 1] = gss[mt];
    }
  }
  __syncthreads();
  if (t < 16) {
    float tot = red[0][t] + red[1][t] + red[2][t] + red[3][t];
    pstat[bx * 16 + t] = tot;
  }
}

// Reduce pstat[256][16] -> gnf[2][8][2]. (128 blocks per batch.)
__global__ __launch_bounds__(512)
void k_ffred(const float* __restrict__ pstat, float* __restrict__ gnf) {
  __shared__ float red[512];
  int t = threadIdx.x;
  int b = t >> 8, i = t & 15, chunk = (t >> 4) & 15;
  float s = 0.0f;
#pragma unroll
  for (int k = 0; k < 8; ++k)
    s += pstat[(b * 128 + chunk * 8 + k) * 16 + i];
  red[t] = s;
  __syncthreads();
  if (chunk == 0) {
    float tot = 0.0f;
#pragma unroll
    for (int k2 = 0; k2 < 16; ++k2) tot += red[(b << 8) | (k2 << 4) | i];
    gnf[b * 16 + i] = tot;
  }
}

// Final GN + leaky + f32 store; also writes the xyz1 passthrough (blocks >= 8192).
__global__ __launch_bounds__(256)
void k_final(const float* __restrict__ h, const float* __restrict__ gnf,
             const float* __restrict__ g, const float* __restrict__ bt,
             const float* __restrict__ xyz1, float* __restrict__ out) {
  int bx = blockIdx.x;
  if (bx >= 8192) {
    int e = (bx - 8192) * 256 + threadIdx.x;   // < BB*3*NN1 = 49152
    out[e] = xyz1[e];
    return;
  }
  int e = bx * 256 + threadIdx.x;              // < BB*128*NN1 = 2097152
  int d = (e / NN1) & 127;
  int b = e / (128 * NN1);
  int gi = b * 16 + (d >> 4) * 2;
  float cnt = 16.0f * (float)NN1;
  float mu = gnf[gi] / cnt;
  float var = gnf[gi + 1] / cnt - mu * mu;
  float rs = rsqrtf(var + 1e-5f);
  float x = (h[e] - mu) * rs * g[d] + bt[d];
  out[BB * 3 * NN1 + e] = leaky(x);
}

// ---------------------------------------------------------------------------
extern "C" void kernel_launch(void* const* d_in, const int* in_sizes, int n_in,
                              void* d_out, int out_size, void* d_ws, size_t ws_size,
                              hipStream_t stream) {
  const float* xyz1   = (const float*)d_in[0];
  const float* xyz2   = (const float*)d_in[1];
  const float* feat1  = (const float*)d_in[2];
  const float* feat2  = (const float*)d_in[3];
  const float* pos_w  = (const float*)d_in[4];
  const float* pos_b  = (const float*)d_in[5];
  const float* pos_g  = (const float*)d_in[6];
  const float* pos_bt = (const float*)d_in[7];
  const float* ek_w   = (const float*)d_in[8];
  const float* ek_b   = (const float*)d_in[9];
  const float* eq_w   = (const float*)d_in[10];
  const float* eq_b   = (const float*)d_in[11];
  const float* ev1_w  = (const float*)d_in[12];
  const float* ev1_b  = (const float*)d_in[13];
  const float* ev2_w  = (const float*)d_in[14];
  const float* ev2_b  = (const float*)d_in[15];
  const float* qk_w   = (const float*)d_in[16];
  const float* v_w    = (const float*)d_in[17];
  const float* ff_w   = (const float*)d_in[18];
  const float* ff_b   = (const float*)d_in[19];
  const float* ff_g   = (const float*)d_in[20];
  const float* ff_bt  = (const float*)d_in[21];
  (void)in_sizes; (void)n_in; (void)out_size; (void)ws_size;

  char* ws = (char*)d_ws;          // ~26.9 MB used
  float*  feat1p   = (float*)(ws);                        // [B][N1][C] f32   8388608 B
  u16*    feat2pb  = (u16*)  (ws + 8388608);              // [B][N2][C] bf16  4194304 B
  u16*    attn_out = (u16*)  (ws + 12582912);             // feat_new bf16    4194304 B
  float*  h_ff     = (float*)(ws + 16777216);             // FF out [B][C][N1] 8388608 B
  int*    idxb     = (int*)  (ws + 25165824);             // [B][N1][16]      1048576 B
  u16*    wqk      = (u16*)  (ws + 26214400);             // bf16 qk_w        32768 B
  u16*    wv       = (u16*)  (ws + 26247168);             // bf16 v_w         32768 B
  u16*    wff      = (u16*)  (ws + 26279936);             // bf16 ff_w        32768 B
  float*  mom_part = (float*)(ws + 26312704);             // 128*9 floats     4608 B
  float2* gnp      = (float2*)(ws + 26317312);            // 32 float2        256 B
  float*  pstat    = (float*)(ws + 26317568);             // 256*16 floats    16384 B
  float*  gnf      = (float*)(ws + 26333952);             // 32 floats        128 B
  float4* px1      = (float4*)(ws + 26334080);            // [B][N1] packed   262144 B
  float4* px2      = (float4*)(ws + 26596224);            // [B][N2] packed   262144 B

  k_prep<<<320, 256, 0, stream>>>(qk_w, v_w, ff_w, wqk, wv, wff,
                                  xyz1, xyz2, px1, px2, mom_part);
  k_gnstats<<<1, 512, 0, stream>>>(mom_part, pos_w, pos_b, gnp);
  k_pk<<<6144, 256, 0, stream>>>(px1, px2, idxb, xyz1, xyz2, feat1, feat2,
                                 pos_w, pos_b, pos_g, pos_bt, gnp, feat1p, feat2pb);
  k_attn<<<2048, 256, 0, stream>>>(px1, px2, feat1p, feat2pb, idxb, wqk, wv,
                                   eq_w, eq_b, ek_w, ek_b, ev1_w, ev1_b, ev2_w, ev2_b,
                                   attn_out);
  k_ff<<<256, 256, 0, stream>>>(attn_out, wff, ff_b, h_ff, pstat);
  k_ffred<<<1, 512, 0, stream>>>(pstat, gnf);
  k_final<<<8384, 256, 0, stream>>>(h_ff, gnf, ff_g, ff_bt, xyz1, (float*)d_out);
}

// Round 16
// 204.482 us; speedup vs baseline: 1.6840x; 1.0191x over previous
//
#include <hip/hip_runtime.h>
#include <hip/hip_bf16.h>

// Problem constants (reference: B,N1,N2,C,COUT,NS = 2,8192,8192,128,128,16)
#define BB  2
#define NN1 8192
#define NN2 8192
#define CC  128
#define SS  16

typedef unsigned short u16;
typedef unsigned int u32;
typedef short bf16x8 __attribute__((ext_vector_type(8)));
typedef float f32x4  __attribute__((ext_vector_type(4)));

__device__ __forceinline__ u16 f2bf(float f) {
  __hip_bfloat16 h = __float2bfloat16(f);      // RNE
  return *(u16*)&h;
}
__device__ __forceinline__ float bf2f(u16 u) {
  union { float f; unsigned int u; } v; v.u = ((unsigned int)u) << 16;
  return v.f;
}
__device__ __forceinline__ float bflo(u32 w) {
  union { float f; unsigned int u; } v; v.u = w << 16; return v.f;
}
__device__ __forceinline__ float bfhi(u32 w) {
  union { float f; unsigned int u; } v; v.u = w & 0xFFFF0000u; return v.f;
}
__device__ __forceinline__ float leaky(float x) { return x >= 0.0f ? x : 0.1f * x; }

// ---------------------------------------------------------------------------
// prep: convert qk_w/v_w/ff_w to bf16; pack xyz -> float4{x,y,z,|p|2}; write
// per-block xyz-moment partials (9 sums) non-atomically to mom_part[128][9].
__global__ __launch_bounds__(256)
void k_prep(const float* __restrict__ qkw, const float* __restrict__ vw,
            const float* __restrict__ ffw,
            u16* __restrict__ oa, u16* __restrict__ ob, u16* __restrict__ of,
            const float* __restrict__ xyz1, const float* __restrict__ xyz2,
            float4* __restrict__ px1, float4* __restrict__ px2,
            float* __restrict__ mom_part) {
  int bx = blockIdx.x, t = threadIdx.x;
  if (bx < 192) {
    int e = bx * 256 + t;
    if (e < 16384) oa[e] = f2bf(qkw[e]);
    else if (e < 32768) ob[e - 16384] = f2bf(vw[e - 16384]);
    else of[e - 32768] = f2bf(ffw[e - 32768]);
    return;
  }
  __shared__ float wred[4][9];
  const float* xyz; float4* px; int e;
  if (bx < 256) { e = (bx - 192) * 256 + t; xyz = xyz1; px = px1; }
  else          { e = (bx - 256) * 256 + t; xyz = xyz2; px = px2; }
  int b = e >> 13, n = e & 8191;
  float x = xyz[(b * 3 + 0) * 8192 + n];
  float y = xyz[(b * 3 + 1) * 8192 + n];
  float z = xyz[(b * 3 + 2) * 8192 + n];
  px[e] = make_float4(x, y, z, x * x + y * y + z * z);
  float s[9] = { x, y, z, x * x, y * y, z * z, x * y, x * z, y * z };
#pragma unroll
  for (int o = 1; o < 64; o <<= 1)
#pragma unroll
    for (int i = 0; i < 9; ++i) s[i] += __shfl_xor(s[i], o);
  int w = t >> 6;
  if ((t & 63) == 0)
#pragma unroll
    for (int i = 0; i < 9; ++i) wred[w][i] = s[i];
  __syncthreads();
  if (t < 9) {
    float tot = wred[0][t] + wred[1][t] + wred[2][t] + wred[3][t];
    mom_part[(bx - 192) * 9 + t] = tot;
  }
}

// Analytic GN stats for pos-enc (reduces mom_part itself).
__global__ __launch_bounds__(512)
void k_gnstats(const float* __restrict__ mom_part, const float* __restrict__ pw,
               const float* __restrict__ pb, float2* __restrict__ gnp) {
  int t = threadIdx.x;                 // 512: cloud(2) x b(2) x c(128)
  int cl = t >> 8, b = (t >> 7) & 1, c = t & 127;
  const float* P = mom_part + (cl * 64 + b * 32) * 9;
  float M[9];
#pragma unroll
  for (int i = 0; i < 9; ++i) {
    float sum = 0.0f;
    for (int k = 0; k < 32; ++k) sum += P[k * 9 + i];
    M[i] = sum;
  }
  const float inv = 1.0f / 8192.0f;
  float mx = M[0] * inv, my = M[1] * inv, mz = M[2] * inv;
  float sxx = M[3] * inv, syy = M[4] * inv, szz = M[5] * inv;
  float sxy = M[6] * inv, sxz = M[7] * inv, syz = M[8] * inv;
  float w0 = pw[c * 3], w1 = pw[c * 3 + 1], w2 = pw[c * 3 + 2], bc = pb[c];
  float wm = w0 * mx + w1 * my + w2 * mz;
  float Eh = wm + bc;
  float wSw = w0 * w0 * sxx + w1 * w1 * syy + w2 * w2 * szz
            + 2.0f * (w0 * w1 * sxy + w0 * w2 * sxz + w1 * w2 * syz);
  float Eh2 = wSw + 2.0f * bc * wm + bc * bc;
#pragma unroll
  for (int o = 1; o < 16; o <<= 1) { Eh += __shfl_xor(Eh, o); Eh2 += __shfl_xor(Eh2, o); }
  if ((c & 15) == 0) {
    float mu = Eh * 0.0625f;
    float var = Eh2 * 0.0625f - mu * mu;
    gnp[cl * 16 + b * 8 + (c >> 4)] = make_float2(mu, rsqrtf(var + 1e-5f));
  }
}

// ---------------------------------------------------------------------------
// KNN helpers. Packed key: (f32 distance^2 bits & 0xFFFFE000) | index (13b).

__device__ __forceinline__ u32 knnkey(float4 qv, float4 c, u32 idx) {
  float m = fmaf(qv.x, c.x, fmaf(qv.y, c.y, qv.z * c.z));
  float d = fmaf(-2.0f, m, qv.w + c.w);
  d = fmaxf(d, 0.0f);
  return (__float_as_uint(d) & 0xFFFFE000u) | idx;
}

__device__ __forceinline__ void ce_x(u32& v, int j, bool up, int l) {
  u32 p = __shfl_xor(v, j);
  u32 mn = v < p ? v : p;
  u32 mx = v < p ? p : v;
  bool lower = ((l & j) == 0);
  v = (lower == up) ? mn : mx;
}

// Bitonic sort of 128 keys (2 regs/lane, element i = reg*64 + lane), ascending.
__device__ __forceinline__ void sort128(u32& v0, u32& v1, int l) {
#pragma unroll
  for (int k = 2; k <= 64; k <<= 1) {
#pragma unroll
    for (int j = k >> 1; j > 0; j >>= 1) {
      ce_x(v0, j, ((l & k) == 0), l);
      ce_x(v1, j, (((l + 64) & k) == 0), l);
    }
  }
  { u32 mn = v0 < v1 ? v0 : v1; u32 mx = v0 < v1 ? v1 : v0; v0 = mn; v1 = mx; }
#pragma unroll
  for (int j = 32; j > 0; j >>= 1) {
    ce_x(v0, j, true, l);
    ce_x(v1, j, true, l);
  }
}

// ---------------------------------------------------------------------------
// Fused KNN + pos-enc. Blocks [0,4096): KNN (wave-per-query, ballot filter,
// rolling prefetch). Blocks [4096,6144): pos-enc (featp = feat + leaky(GN)).
__global__ __launch_bounds__(256)
void k_pk(const float4* __restrict__ px1, const float4* __restrict__ px2,
          int* __restrict__ idxout,
          const float* __restrict__ xyz1, const float* __restrict__ xyz2,
          const float* __restrict__ feat1, const float* __restrict__ feat2,
          const float* __restrict__ pw, const float* __restrict__ pb,
          const float* __restrict__ gam, const float* __restrict__ bet,
          const float2* __restrict__ gnp,
          float* __restrict__ outf, u16* __restrict__ outb) {
  __shared__ float smem[128 * 17];     // posenc T[128][17]; knn reuses 2KB
  int bx = blockIdx.x, t = threadIdx.x;

  if (bx < 4096) {
    // ---------------- KNN part ----------------
    int w = t >> 6, l = t & 63;
    int q = bx * 4 + w;                // 0..16383
    int b = q >> 13;
    float4 qv = px1[q];
    const float4* cp = px2 + (b << 13);
    u32* wb = ((u32*)smem) + w * 128;
    u32 kth = 0xFFFFFFFFu;
    int cnt = 0;
    const unsigned long long below = (1ull << l) - 1ull;
    float4 c_cur = cp[l];
    for (int it = 0; it < 128; ++it) {
      float4 c_nxt = c_cur;
      if (it < 127) c_nxt = cp[(it + 1) * 64 + l];   // rolling prefetch
      u32 key = knnkey(qv, c_cur, (u32)(it * 64 + l));
      bool pass = key < kth;
      unsigned long long mask = __ballot(pass);
      if (mask) {
        int off = cnt + (int)__popcll(mask & below);
        if (pass) wb[off] = key;
        cnt += (int)__popcll(mask);
        if (cnt > 64) {                // before append cnt<=64 -> cnt<=128 here
          u32 v0 = (l < cnt) ? wb[l] : 0xFFFFFFFFu;
          u32 v1 = (64 + l < cnt) ? wb[64 + l] : 0xFFFFFFFFu;
          sort128(v0, v1, l);
          if (l < 16) wb[l] = v0;
          cnt = 16;
          kth = __shfl(v0, 15);
        }
      }
      c_cur = c_nxt;
    }
    u32 v0 = (l < cnt) ? wb[l] : 0xFFFFFFFFu;
    u32 v1 = (64 + l < cnt) ? wb[64 + l] : 0xFFFFFFFFu;
    sort128(v0, v1, l);
    if (l < 16) idxout[q * 16 + l] = (int)(v0 & 8191u);
    return;
  }

  // ---------------- pos-enc part ----------------
  bx -= 4096;
  const float* xyz; const float* feat; const float2* gp; int asbf;
  if (bx < 1024) { xyz = xyz1; feat = feat1; gp = gnp;      asbf = 0; }
  else           { xyz = xyz2; feat = feat2; gp = gnp + 16; asbf = 1; bx -= 1024; }
  const int N = 8192;
  int b = bx / 512, n0 = (bx % 512) * 16;
  for (int it = 0; it < 8; ++it) {
    int j = t & 15, c = it * 16 + (t >> 4);
    smem[c * 17 + j] = feat[(b * 128 + c) * N + n0 + j];
  }
  int c = t & 127;
  float w0 = pw[c * 3], w1 = pw[c * 3 + 1], w2 = pw[c * 3 + 2], bc = pb[c];
  float2 g2 = gp[b * 8 + (c >> 4)];
  float gm = gam[c], b2 = bet[c];
  __syncthreads();
  for (int it = 0; it < 8; ++it) {
    int j = it * 2 + (t >> 7);
    int n = n0 + j;
    float xs = xyz[(b * 3 + 0) * N + n];
    float ys = xyz[(b * 3 + 1) * N + n];
    float zs = xyz[(b * 3 + 2) * N + n];
    float hv = w0 * xs + w1 * ys + w2 * zs + bc;
    float xo = (hv - g2.x) * g2.y * gm + b2;
    float r = smem[c * 17 + j] + leaky(xo);
    if (asbf) outb[(size_t)(b * N + n) * 128 + c] = f2bf(r);
    else      outf[(size_t)(b * N + n) * 128 + c] = r;
  }
}

// ---------------------------------------------------------------------------
// Fused attention (r12 structure, proven VGPR=80/109us config): wave-local,
// 2 points per wave, f2 read from global; GEMM2 swapped so the epilogue is
// 2 shuffles; fB gathered between GEMM1 and softmax; bv after softmax; kd
// rolling 2-deep prefetch. ONLY delta vs r12: output stored as bf16.
__device__ __forceinline__ float4 ld_enc(const float* encS, int e, int c) {
  int xe = e ^ ((c >> 3) & 3);
  return *(const float4*)&encS[c * 16 + xe * 4];
}

__global__ __launch_bounds__(256, 2)
void k_attn(const float4* __restrict__ px1, const float4* __restrict__ px2,
            const float* __restrict__ f1p, const u16* __restrict__ f2p,
            const int* __restrict__ idxb,
            const u16* __restrict__ wq, const u16* __restrict__ wvm,
            const float* __restrict__ eqw, const float* __restrict__ eqb,
            const float* __restrict__ ekw, const float* __restrict__ ekb,
            const float* __restrict__ ev1w, const float* __restrict__ ev1b,
            const float* __restrict__ ev2w, const float* __restrict__ ev2b,
            u16* __restrict__ outp) {
  const int t = threadIdx.x, bx = blockIdx.x;
  const int b = bx >> 10;              // 1024 blocks per batch
  const int base8 = (bx & 1023) * 8;   // 8 points per block (2 per wave)
  const int w = t >> 6, l = t & 63, l15 = l & 15, l4 = l >> 4;

  __shared__ float encS[128 * 16];     // 8 KB: eq, ek, ev1 (XOR slots)
  __shared__ float f1s[8 * 132];       // 4.2 KB
  __shared__ float4 e3S[128];          // 2 KB: ev2 {w0,w1,w2,b}
  __shared__ float4 relS[8 * 16];      // 2 KB: per (pt, s) {r0,r1,r2,aw}

  for (int i = t; i < 384; i += 256) {
    int e = i >> 7, c = i & 127;
    const float* wsrc = (e == 0) ? eqw : (e == 1) ? ekw : ev1w;
    const float* bsrc = (e == 0) ? eqb : (e == 1) ? ekb : ev1b;
    int xe = e ^ ((c >> 3) & 3);
    float* dst = &encS[c * 16 + xe * 4];
    dst[0] = wsrc[c * 3]; dst[1] = wsrc[c * 3 + 1];
    dst[2] = wsrc[c * 3 + 2]; dst[3] = bsrc[c];
  }
  if (t < 128)
    e3S[t] = make_float4(ev2w[t * 3], ev2w[t * 3 + 1], ev2w[t * 3 + 2], ev2b[t]);
  for (int i = t; i < 1024; i += 256) {
    int p = i >> 7, c = i & 127;
    f1s[p * 132 + c] = f1p[(size_t)(b * NN1 + base8 + p) * 128 + c];
  }

  const int pt0 = base8 + w * 2, pt1 = pt0 + 1;
  const int j0 = idxb[(b * NN1 + pt0) * 16 + l15];
  const int j1 = idxb[(b * NN1 + pt1) * 16 + l15];
  float4 qc0 = px1[b * NN1 + pt0];
  float4 qc1 = px1[b * NN1 + pt1];
  float4 cc0 = px2[b * NN2 + j0];
  float4 cc1 = px2[b * NN2 + j1];
  float r0[2], r1[2], r2[2];
  r0[0] = cc0.x - qc0.x; r1[0] = cc0.y - qc0.y; r2[0] = cc0.z - qc0.z;
  r0[1] = cc1.x - qc1.x; r1[1] = cc1.y - qc1.y; r2[1] = cc1.z - qc1.z;

  const u16* row0 = f2p + (size_t)(b * NN2 + j0) * 128;
  const u16* row1 = f2p + (size_t)(b * NN2 + j1) * 128;
  __syncthreads();

  // ---- bq fragments: qin = f1 * leaky(eq.r + b), B-layout ----
  bf16x8 bq[2][4];
#pragma unroll
  for (int ks = 0; ks < 4; ++ks) {
#pragma unroll
    for (int j = 0; j < 8; ++j) {
      int c = ks * 32 + l4 * 8 + j;
      float4 ew = ld_enc(encS, 0, c);
      float f10 = f1s[(w * 2 + 0) * 132 + c];
      float f11 = f1s[(w * 2 + 1) * 132 + c];
      float e0 = leaky(ew.x * r0[0] + ew.y * r1[0] + ew.z * r2[0] + ew.w);
      float e1 = leaky(ew.x * r0[1] + ew.y * r1[1] + ew.z * r2[1] + ew.w);
      bq[0][ks][j] = (short)f2bf(f10 * e0);
      bq[1][ks][j] = (short)f2bf(f11 * e1);
    }
  }

  // ---- GEMM1 (q = Wq @ qin) interleaved with attention dot per mt;
  //      kd rolling 2-deep prefetch ----
  float dp0 = 0.0f, dp1 = 0.0f;
  uint2 kc0 = *(const uint2*)(row0 + l4 * 4);
  uint2 kc1 = *(const uint2*)(row1 + l4 * 4);
#pragma unroll
  for (int mt = 0; mt < 8; ++mt) {
    uint2 kn0 = kc0, kn1 = kc1;
    if (mt < 7) {
      kn0 = *(const uint2*)(row0 + (mt + 1) * 16 + l4 * 4);
      kn1 = *(const uint2*)(row1 + (mt + 1) * 16 + l4 * 4);
    }
    f32x4 a0 = (f32x4){0.f, 0.f, 0.f, 0.f};
    f32x4 a1 = (f32x4){0.f, 0.f, 0.f, 0.f};
#pragma unroll
    for (int ks = 0; ks < 4; ++ks) {
      bf16x8 af = *(const bf16x8*)&wq[(mt * 16 + l15) * 128 + ks * 32 + l4 * 8];
      a0 = __builtin_amdgcn_mfma_f32_16x16x32_bf16(af, bq[0][ks], a0, 0, 0, 0);
      a1 = __builtin_amdgcn_mfma_f32_16x16x32_bf16(af, bq[1][ks], a1, 0, 0, 0);
    }
    float f2v0[4] = { bflo(kc0.x), bfhi(kc0.x), bflo(kc0.y), bfhi(kc0.y) };
    float f2v1[4] = { bflo(kc1.x), bfhi(kc1.x), bflo(kc1.y), bfhi(kc1.y) };
#pragma unroll
    for (int r = 0; r < 4; ++r) {
      int c = mt * 16 + l4 * 4 + r;
      float4 ew = ld_enc(encS, 1, c);
      float ek0 = leaky(ew.x * r0[0] + ew.y * r1[0] + ew.z * r2[0] + ew.w);
      float ek1 = leaky(ew.x * r0[1] + ew.y * r1[1] + ew.z * r2[1] + ew.w);
      dp0 += a0[r] * (f2v0[r] * ek0);
      dp1 += a1[r] * (f2v1[r] * ek1);
    }
    kc0 = kn0; kc1 = kn1;
  }

  // V-path gather (B-layout fragments), issued before softmax to hide latency
  bf16x8 fB[2][4];
#pragma unroll
  for (int ks = 0; ks < 4; ++ks) {
    fB[0][ks] = *(const bf16x8*)(row0 + ks * 32 + l4 * 8);
    fB[1][ks] = *(const bf16x8*)(row1 + ks * 32 + l4 * 8);
  }

  // reduce dot over l4 groups, then 16-lane softmax
  dp0 += __shfl_xor(dp0, 16); dp0 += __shfl_xor(dp0, 32);
  dp1 += __shfl_xor(dp1, 16); dp1 += __shfl_xor(dp1, 32);
  float aw0, aw1;
  {
    float x = dp0 * 0.08838834764831845f;
    float m = x;
#pragma unroll
    for (int o = 1; o < 16; o <<= 1) m = fmaxf(m, __shfl_xor(m, o));
    float e = __expf(x - m);
    float s = e;
#pragma unroll
    for (int o = 1; o < 16; o <<= 1) s += __shfl_xor(s, o);
    aw0 = e / s;
  }
  {
    float x = dp1 * 0.08838834764831845f;
    float m = x;
#pragma unroll
    for (int o = 1; o < 16; o <<= 1) m = fmaxf(m, __shfl_xor(m, o));
    float e = __expf(x - m);
    float s = e;
#pragma unroll
    for (int o = 1; o < 16; o <<= 1) s += __shfl_xor(s, o);
    aw1 = e / s;
  }

  // stage {rel, aw} per (point, sample) for the transposed epilogue.
  if (l < 16) {
    relS[(w * 2 + 0) * 16 + l] = make_float4(r0[0], r1[0], r2[0], aw0);
    relS[(w * 2 + 1) * 16 + l] = make_float4(r0[1], r1[1], r2[1], aw1);
  }

  // ---- bv fragments: vin = f2 * leaky(ev1.r + b) ----
  bf16x8 bv[2][4];
#pragma unroll
  for (int ks = 0; ks < 4; ++ks) {
#pragma unroll
    for (int j = 0; j < 8; ++j) {
      int c = ks * 32 + l4 * 8 + j;
      float4 ew = ld_enc(encS, 2, c);
      float e0 = leaky(ew.x * r0[0] + ew.y * r1[0] + ew.z * r2[0] + ew.w);
      float e1 = leaky(ew.x * r0[1] + ew.y * r1[1] + ew.z * r2[1] + ew.w);
      bv[0][ks][j] = (short)f2bf(bf2f((u16)fB[0][ks][j]) * e0);
      bv[1][ks][j] = (short)f2bf(bf2f((u16)fB[1][ks][j]) * e1);
    }
  }

  // ---- GEMM2 swapped: D = vin^T . Wv^T -> lane holds v[m][s=l4*4+r] ----
#pragma unroll
  for (int mt = 0; mt < 8; ++mt) {
    f32x4 a0 = (f32x4){0.f, 0.f, 0.f, 0.f};
    f32x4 a1 = (f32x4){0.f, 0.f, 0.f, 0.f};
#pragma unroll
    for (int ks = 0; ks < 4; ++ks) {
      bf16x8 bf = *(const bf16x8*)&wvm[(mt * 16 + l15) * 128 + ks * 32 + l4 * 8];
      a0 = __builtin_amdgcn_mfma_f32_16x16x32_bf16(bv[0][ks], bf, a0, 0, 0, 0);
      a1 = __builtin_amdgcn_mfma_f32_16x16x32_bf16(bv[1][ks], bf, a1, 0, 0, 0);
    }
    const int m = mt * 16 + l15;
    float4 ew = e3S[m];                 // one ev2-param load per mt
    float acc0 = 0.0f, acc1 = 0.0f;
#pragma unroll
    for (int r = 0; r < 4; ++r) {
      float4 ra = relS[(w * 2 + 0) * 16 + l4 * 4 + r];
      float4 rb = relS[(w * 2 + 1) * 16 + l4 * 4 + r];
      float e0 = leaky(ew.x * ra.x + ew.y * ra.y + ew.z * ra.z + ew.w);
      float e1 = leaky(ew.x * rb.x + ew.y * rb.y + ew.z * rb.z + ew.w);
      acc0 += a0[r] * e0 * ra.w;        // .w carries the softmax weight
      acc1 += a1[r] * e1 * rb.w;
    }
    acc0 += __shfl_xor(acc0, 16); acc0 += __shfl_xor(acc0, 32);
    acc1 += __shfl_xor(acc1, 16); acc1 += __shfl_xor(acc1, 32);
    if (l < 16) {                       // coalesced 32B segment per (mt, pt)
      outp[(size_t)(b * NN1 + pt0) * 128 + m] =
          f2bf(acc0 + f1s[(w * 2 + 0) * 132 + m]);
      outp[(size_t)(b * NN1 + pt1) * 128 + m] =
          f2bf(acc1 + f1s[(w * 2 + 1) * 132 + m]);
    }
  }
}

// ---------------------------------------------------------------------------
// FF via MFMA: h[b][d][n] = ff_w[d,:].feat_new[b][n][:] + ff_b[d].
// Block = 64 points, wave = 16 points. Per-block GN partials -> pstat.
__global__ __launch_bounds__(256)
void k_ff(const u16* __restrict__ xb, const u16* __restrict__ wfb,
          const float* __restrict__ ffb, float* __restrict__ hout,
          float* __restrict__ pstat) {
  const int t = threadIdx.x, bx = blockIdx.x;
  const int w = t >> 6, l = t & 63, l15 = l & 15, l4 = l >> 4;
  __shared__ float bS[128];
  __shared__ float red[4][16];
  if (t < 128) bS[t] = ffb[t];
  const int pt = bx * 64 + w * 16 + l15;     // global point 0..16383
  const int b = pt >> 13, n = pt & 8191;
  const u16* row = xb + (size_t)pt * 128;
  bf16x8 bfrag[4];
#pragma unroll
  for (int ks = 0; ks < 4; ++ks)
    bfrag[ks] = *(const bf16x8*)(row + ks * 32 + l4 * 8);
  __syncthreads();
  float gs[8], gss[8];
#pragma unroll
  for (int mt = 0; mt < 8; ++mt) {
    f32x4 a = (f32x4){0.f, 0.f, 0.f, 0.f};
#pragma unroll
    for (int ks = 0; ks < 4; ++ks) {
      bf16x8 af = *(const bf16x8*)&wfb[(mt * 16 + l15) * 128 + ks * 32 + l4 * 8];
      a = __builtin_amdgcn_mfma_f32_16x16x32_bf16(af, bfrag[ks], a, 0, 0, 0);
    }
    int d0 = mt * 16 + l4 * 4;
    float s = 0.0f, ss = 0.0f;
#pragma unroll
    for (int r = 0; r < 4; ++r) {
      float h = a[r] + bS[d0 + r];
      hout[(size_t)(b * 128 + d0 + r) * 8192 + n] = h;
      s += h; ss += h * h;
    }
    gs[mt] = s; gss[mt] = ss;
  }
#pragma unroll
  for (int mt = 0; mt < 8; ++mt) {
#pragma unroll
    for (int o = 1; o < 64; o <<= 1) {
      gs[mt] += __shfl_xor(gs[mt], o);
      gss[mt] += __shfl_xor(gss[mt], o);
    }
  }
  if (l == 0) {
#pragma unroll
    for (int mt = 0; mt < 8; ++mt) {
      red[w][mt * 2 + 0] = gs[mt];
      red[w][mt * 2 + 1] = gss[mt];
    }
  }
  __syncthreads();
  if (t < 16) {
    float tot = red[0][t] + red[1][t] + red[2][t] + red[3][t];
    pstat[bx * 16 + t] = tot;
  }
}

// Reduce pstat[256][16] -> gnf[2][8][2]. (128 blocks per batch.)
__global__ __launch_bounds__(512)
void k_ffred(const float* __restrict__ pstat, float* __restrict__ gnf) {
  __shared__ float red[512];
  int t = threadIdx.x;
  int b = t >> 8, i = t & 15, chunk = (t >> 4) & 15;
  float s = 0.0f;
#pragma unroll
  for (int k = 0; k < 8; ++k)
    s += pstat[(b * 128 + chunk * 8 + k) * 16 + i];
  red[t] = s;
  __syncthreads();
  if (chunk == 0) {
    float tot = 0.0f;
#pragma unroll
    for (int k2 = 0; k2 < 16; ++k2) tot += red[(b << 8) | (k2 << 4) | i];
    gnf[b * 16 + i] = tot;
  }
}

// Final GN + leaky + f32 store; also writes the xyz1 passthrough (blocks >= 8192).
__global__ __launch_bounds__(256)
void k_final(const float* __restrict__ h, const float* __restrict__ gnf,
             const float* __restrict__ g, const float* __restrict__ bt,
             const float* __restrict__ xyz1, float* __restrict__ out) {
  int bx = blockIdx.x;
  if (bx >= 8192) {
    int e = (bx - 8192) * 256 + threadIdx.x;   // < BB*3*NN1 = 49152
    out[e] = xyz1[e];
    return;
  }
  int e = bx * 256 + threadIdx.x;              // < BB*128*NN1 = 2097152
  int d = (e / NN1) & 127;
  int b = e / (128 * NN1);
  int gi = b * 16 + (d >> 4) * 2;
  float cnt = 16.0f * (float)NN1;
  float mu = gnf[gi] / cnt;
  float var = gnf[gi + 1] / cnt - mu * mu;
  float rs = rsqrtf(var + 1e-5f);
  float x = (h[e] - mu) * rs * g[d] + bt[d];
  out[BB * 3 * NN1 + e] = leaky(x);
}

// ---------------------------------------------------------------------------
extern "C" void kernel_launch(void* const* d_in, const int* in_sizes, int n_in,
                              void* d_out, int out_size, void* d_ws, size_t ws_size,
                              hipStream_t stream) {
  const float* xyz1   = (const float*)d_in[0];
  const float* xyz2   = (const float*)d_in[1];
  const float* feat1  = (const float*)d_in[2];
  const float* feat2  = (const float*)d_in[3];
  const float* pos_w  = (const float*)d_in[4];
  const float* pos_b  = (const float*)d_in[5];
  const float* pos_g  = (const float*)d_in[6];
  const float* pos_bt = (const float*)d_in[7];
  const float* ek_w   = (const float*)d_in[8];
  const float* ek_b   = (const float*)d_in[9];
  const float* eq_w   = (const float*)d_in[10];
  const float* eq_b   = (const float*)d_in[11];
  const float* ev1_w  = (const float*)d_in[12];
  const float* ev1_b  = (const float*)d_in[13];
  const float* ev2_w  = (const float*)d_in[14];
  const float* ev2_b  = (const float*)d_in[15];
  const float* qk_w   = (const float*)d_in[16];
  const float* v_w    = (const float*)d_in[17];
  const float* ff_w   = (const float*)d_in[18];
  const float* ff_b   = (const float*)d_in[19];
  const float* ff_g   = (const float*)d_in[20];
  const float* ff_bt  = (const float*)d_in[21];
  (void)in_sizes; (void)n_in; (void)out_size; (void)ws_size;

  char* ws = (char*)d_ws;          // ~26.9 MB used
  float*  feat1p   = (float*)(ws);                        // [B][N1][C] f32   8388608 B
  u16*    feat2pb  = (u16*)  (ws + 8388608);              // [B][N2][C] bf16  4194304 B
  u16*    attn_out = (u16*)  (ws + 12582912);             // feat_new bf16    4194304 B
  float*  h_ff     = (float*)(ws + 16777216);             // FF out [B][C][N1] 8388608 B
  int*    idxb     = (int*)  (ws + 25165824);             // [B][N1][16]      1048576 B
  u16*    wqk      = (u16*)  (ws + 26214400);             // bf16 qk_w        32768 B
  u16*    wv       = (u16*)  (ws + 26247168);             // bf16 v_w         32768 B
  u16*    wff      = (u16*)  (ws + 26279936);             // bf16 ff_w        32768 B
  float*  mom_part = (float*)(ws + 26312704);             // 128*9 floats     4608 B
  float2* gnp      = (float2*)(ws + 26317312);            // 32 float2        256 B
  float*  pstat    = (float*)(ws + 26317568);             // 256*16 floats    16384 B
  float*  gnf      = (float*)(ws + 26333952);             // 32 floats        128 B
  float4* px1      = (float4*)(ws + 26334080);            // [B][N1] packed   262144 B
  float4* px2      = (float4*)(ws + 26596224);            // [B][N2] packed   262144 B

  k_prep<<<320, 256, 0, stream>>>(qk_w, v_w, ff_w, wqk, wv, wff,
                                  xyz1, xyz2, px1, px2, mom_part);
  k_gnstats<<<1, 512, 0, stream>>>(mom_part, pos_w, pos_b, gnp);
  k_pk<<<6144, 256, 0, stream>>>(px1, px2, idxb, xyz1, xyz2, feat1, feat2,
                                 pos_w, pos_b, pos_g, pos_bt, gnp, feat1p, feat2pb);
  k_attn<<<2048, 256, 0, stream>>>(px1, px2, feat1p, feat2pb, idxb, wqk, wv,
                                   eq_w, eq_b, ek_w, ek_b, ev1_w, ev1_b, ev2_w, ev2_b,
                                   attn_out);
  k_ff<<<256, 256, 0, stream>>>(attn_out, wff, ff_b, h_ff, pstat);
  k_ffred<<<1, 512, 0, stream>>>(pstat, gnf);
  k_final<<<8384, 256, 0, stream>>>(h_ff, gnf, ff_g, ff_bt, xyz1, (float*)d_out);
}

// Round 17
// 201.321 us; speedup vs baseline: 1.7105x; 1.0157x over previous
//
#include <hip/hip_runtime.h>
#include <hip/hip_bf16.h>

// Problem constants (reference: B,N1,N2,C,COUT,NS = 2,8192,8192,128,128,16)
#define BB  2
#define NN1 8192
#define NN2 8192
#define CC  128
#define SS  16

typedef unsigned short u16;
typedef unsigned int u32;
typedef short bf16x8 __attribute__((ext_vector_type(8)));
typedef float f32x4  __attribute__((ext_vector_type(4)));

__device__ __forceinline__ u16 f2bf(float f) {
  __hip_bfloat16 h = __float2bfloat16(f);      // RNE
  return *(u16*)&h;
}
__device__ __forceinline__ float bf2f(u16 u) {
  union { float f; unsigned int u; } v; v.u = ((unsigned int)u) << 16;
  return v.f;
}
__device__ __forceinline__ float bflo(u32 w) {
  union { float f; unsigned int u; } v; v.u = w << 16; return v.f;
}
__device__ __forceinline__ float bfhi(u32 w) {
  union { float f; unsigned int u; } v; v.u = w & 0xFFFF0000u; return v.f;
}
__device__ __forceinline__ float leaky(float x) { return x >= 0.0f ? x : 0.1f * x; }

// ---------------------------------------------------------------------------
// prep: convert qk_w/v_w/ff_w to bf16; pack xyz -> float4{x,y,z,|p|2}; write
// per-block xyz-moment partials (9 sums) non-atomically to mom_part[128][9].
__global__ __launch_bounds__(256)
void k_prep(const float* __restrict__ qkw, const float* __restrict__ vw,
            const float* __restrict__ ffw,
            u16* __restrict__ oa, u16* __restrict__ ob, u16* __restrict__ of,
            const float* __restrict__ xyz1, const float* __restrict__ xyz2,
            float4* __restrict__ px1, float4* __restrict__ px2,
            float* __restrict__ mom_part) {
  int bx = blockIdx.x, t = threadIdx.x;
  if (bx < 192) {
    int e = bx * 256 + t;
    if (e < 16384) oa[e] = f2bf(qkw[e]);
    else if (e < 32768) ob[e - 16384] = f2bf(vw[e - 16384]);
    else of[e - 32768] = f2bf(ffw[e - 32768]);
    return;
  }
  __shared__ float wred[4][9];
  const float* xyz; float4* px; int e;
  if (bx < 256) { e = (bx - 192) * 256 + t; xyz = xyz1; px = px1; }
  else          { e = (bx - 256) * 256 + t; xyz = xyz2; px = px2; }
  int b = e >> 13, n = e & 8191;
  float x = xyz[(b * 3 + 0) * 8192 + n];
  float y = xyz[(b * 3 + 1) * 8192 + n];
  float z = xyz[(b * 3 + 2) * 8192 + n];
  px[e] = make_float4(x, y, z, x * x + y * y + z * z);
  float s[9] = { x, y, z, x * x, y * y, z * z, x * y, x * z, y * z };
#pragma unroll
  for (int o = 1; o < 64; o <<= 1)
#pragma unroll
    for (int i = 0; i < 9; ++i) s[i] += __shfl_xor(s[i], o);
  int w = t >> 6;
  if ((t & 63) == 0)
#pragma unroll
    for (int i = 0; i < 9; ++i) wred[w][i] = s[i];
  __syncthreads();
  if (t < 9) {
    float tot = wred[0][t] + wred[1][t] + wred[2][t] + wred[3][t];
    mom_part[(bx - 192) * 9 + t] = tot;
  }
}

// Analytic GN stats for pos-enc (reduces mom_part itself).
__global__ __launch_bounds__(512)
void k_gnstats(const float* __restrict__ mom_part, const float* __restrict__ pw,
               const float* __restrict__ pb, float2* __restrict__ gnp) {
  int t = threadIdx.x;                 // 512: cloud(2) x b(2) x c(128)
  int cl = t >> 8, b = (t >> 7) & 1, c = t & 127;
  const float* P = mom_part + (cl * 64 + b * 32) * 9;
  float M[9];
#pragma unroll
  for (int i = 0; i < 9; ++i) {
    float sum = 0.0f;
    for (int k = 0; k < 32; ++k) sum += P[k * 9 + i];
    M[i] = sum;
  }
  const float inv = 1.0f / 8192.0f;
  float mx = M[0] * inv, my = M[1] * inv, mz = M[2] * inv;
  float sxx = M[3] * inv, syy = M[4] * inv, szz = M[5] * inv;
  float sxy = M[6] * inv, sxz = M[7] * inv, syz = M[8] * inv;
  float w0 = pw[c * 3], w1 = pw[c * 3 + 1], w2 = pw[c * 3 + 2], bc = pb[c];
  float wm = w0 * mx + w1 * my + w2 * mz;
  float Eh = wm + bc;
  float wSw = w0 * w0 * sxx + w1 * w1 * syy + w2 * w2 * szz
            + 2.0f * (w0 * w1 * sxy + w0 * w2 * sxz + w1 * w2 * syz);
  float Eh2 = wSw + 2.0f * bc * wm + bc * bc;
#pragma unroll
  for (int o = 1; o < 16; o <<= 1) { Eh += __shfl_xor(Eh, o); Eh2 += __shfl_xor(Eh2, o); }
  if ((c & 15) == 0) {
    float mu = Eh * 0.0625f;
    float var = Eh2 * 0.0625f - mu * mu;
    gnp[cl * 16 + b * 8 + (c >> 4)] = make_float2(mu, rsqrtf(var + 1e-5f));
  }
}

// ---------------------------------------------------------------------------
// KNN helpers. Packed key: (f32 distance^2 bits & 0xFFFFE000) | index (13b).

__device__ __forceinline__ u32 knnkey(float4 qv, float4 c, u32 idx) {
  float m = fmaf(qv.x, c.x, fmaf(qv.y, c.y, qv.z * c.z));
  float d = fmaf(-2.0f, m, qv.w + c.w);
  d = fmaxf(d, 0.0f);
  return (__float_as_uint(d) & 0xFFFFE000u) | idx;
}

__device__ __forceinline__ void ce_x(u32& v, int j, bool up, int l) {
  u32 p = __shfl_xor(v, j);
  u32 mn = v < p ? v : p;
  u32 mx = v < p ? p : v;
  bool lower = ((l & j) == 0);
  v = (lower == up) ? mn : mx;
}

// Bitonic sort of 128 keys (2 regs/lane, element i = reg*64 + lane), ascending.
__device__ __forceinline__ void sort128(u32& v0, u32& v1, int l) {
#pragma unroll
  for (int k = 2; k <= 64; k <<= 1) {
#pragma unroll
    for (int j = k >> 1; j > 0; j >>= 1) {
      ce_x(v0, j, ((l & k) == 0), l);
      ce_x(v1, j, (((l + 64) & k) == 0), l);
    }
  }
  { u32 mn = v0 < v1 ? v0 : v1; u32 mx = v0 < v1 ? v1 : v0; v0 = mn; v1 = mx; }
#pragma unroll
  for (int j = 32; j > 0; j >>= 1) {
    ce_x(v0, j, true, l);
    ce_x(v1, j, true, l);
  }
}

// ---------------------------------------------------------------------------
// Fused KNN + pos-enc. Blocks [0,4096): KNN (wave-per-query, ballot filter,
// rolling prefetch). Blocks [4096,6144): pos-enc (featp = feat + leaky(GN)),
// both clouds written bf16.
__global__ __launch_bounds__(256)
void k_pk(const float4* __restrict__ px1, const float4* __restrict__ px2,
          int* __restrict__ idxout,
          const float* __restrict__ xyz1, const float* __restrict__ xyz2,
          const float* __restrict__ feat1, const float* __restrict__ feat2,
          const float* __restrict__ pw, const float* __restrict__ pb,
          const float* __restrict__ gam, const float* __restrict__ bet,
          const float2* __restrict__ gnp,
          u16* __restrict__ outb1, u16* __restrict__ outb2) {
  __shared__ float smem[128 * 17];     // posenc T[128][17]; knn reuses 2KB
  int bx = blockIdx.x, t = threadIdx.x;

  if (bx < 4096) {
    // ---------------- KNN part ----------------
    int w = t >> 6, l = t & 63;
    int q = bx * 4 + w;                // 0..16383
    int b = q >> 13;
    float4 qv = px1[q];
    const float4* cp = px2 + (b << 13);
    u32* wb = ((u32*)smem) + w * 128;
    u32 kth = 0xFFFFFFFFu;
    int cnt = 0;
    const unsigned long long below = (1ull << l) - 1ull;
    float4 c_cur = cp[l];
    for (int it = 0; it < 128; ++it) {
      float4 c_nxt = c_cur;
      if (it < 127) c_nxt = cp[(it + 1) * 64 + l];   // rolling prefetch
      u32 key = knnkey(qv, c_cur, (u32)(it * 64 + l));
      bool pass = key < kth;
      unsigned long long mask = __ballot(pass);
      if (mask) {
        int off = cnt + (int)__popcll(mask & below);
        if (pass) wb[off] = key;
        cnt += (int)__popcll(mask);
        if (cnt > 64) {                // before append cnt<=64 -> cnt<=128 here
          u32 v0 = (l < cnt) ? wb[l] : 0xFFFFFFFFu;
          u32 v1 = (64 + l < cnt) ? wb[64 + l] : 0xFFFFFFFFu;
          sort128(v0, v1, l);
          if (l < 16) wb[l] = v0;
          cnt = 16;
          kth = __shfl(v0, 15);
        }
      }
      c_cur = c_nxt;
    }
    u32 v0 = (l < cnt) ? wb[l] : 0xFFFFFFFFu;
    u32 v1 = (64 + l < cnt) ? wb[64 + l] : 0xFFFFFFFFu;
    sort128(v0, v1, l);
    if (l < 16) idxout[q * 16 + l] = (int)(v0 & 8191u);
    return;
  }

  // ---------------- pos-enc part ----------------
  bx -= 4096;
  const float* xyz; const float* feat; const float2* gp; u16* outb;
  if (bx < 1024) { xyz = xyz1; feat = feat1; gp = gnp;      outb = outb1; }
  else           { xyz = xyz2; feat = feat2; gp = gnp + 16; outb = outb2; bx -= 1024; }
  const int N = 8192;
  int b = bx / 512, n0 = (bx % 512) * 16;
  for (int it = 0; it < 8; ++it) {
    int j = t & 15, c = it * 16 + (t >> 4);
    smem[c * 17 + j] = feat[(b * 128 + c) * N + n0 + j];
  }
  int c = t & 127;
  float w0 = pw[c * 3], w1 = pw[c * 3 + 1], w2 = pw[c * 3 + 2], bc = pb[c];
  float2 g2 = gp[b * 8 + (c >> 4)];
  float gm = gam[c], b2 = bet[c];
  __syncthreads();
  for (int it = 0; it < 8; ++it) {
    int j = it * 2 + (t >> 7);
    int n = n0 + j;
    float xs = xyz[(b * 3 + 0) * N + n];
    float ys = xyz[(b * 3 + 1) * N + n];
    float zs = xyz[(b * 3 + 2) * N + n];
    float hv = w0 * xs + w1 * ys + w2 * zs + bc;
    float xo = (hv - g2.x) * g2.y * gm + b2;
    float r = smem[c * 17 + j] + leaky(xo);
    outb[(size_t)(b * N + n) * 128 + c] = f2bf(r);
  }
}

// ---------------------------------------------------------------------------
// Fused attention (r12 structure, proven VGPR=80 config): wave-local, 2 points
// per wave, f2 read from global; GEMM2 swapped; fB gathered between GEMM1 and
// softmax; bv after softmax; kd rolling 2-deep prefetch. f1 input bf16,
// output bf16.
__device__ __forceinline__ float4 ld_enc(const float* encS, int e, int c) {
  int xe = e ^ ((c >> 3) & 3);
  return *(const float4*)&encS[c * 16 + xe * 4];
}

__global__ __launch_bounds__(256, 2)
void k_attn(const float4* __restrict__ px1, const float4* __restrict__ px2,
            const u16* __restrict__ f1p, const u16* __restrict__ f2p,
            const int* __restrict__ idxb,
            const u16* __restrict__ wq, const u16* __restrict__ wvm,
            const float* __restrict__ eqw, const float* __restrict__ eqb,
            const float* __restrict__ ekw, const float* __restrict__ ekb,
            const float* __restrict__ ev1w, const float* __restrict__ ev1b,
            const float* __restrict__ ev2w, const float* __restrict__ ev2b,
            u16* __restrict__ outp) {
  const int t = threadIdx.x, bx = blockIdx.x;
  const int b = bx >> 10;              // 1024 blocks per batch
  const int base8 = (bx & 1023) * 8;   // 8 points per block (2 per wave)
  const int w = t >> 6, l = t & 63, l15 = l & 15, l4 = l >> 4;

  __shared__ float encS[128 * 16];     // 8 KB: eq, ek, ev1 (XOR slots)
  __shared__ float f1s[8 * 132];       // 4.2 KB
  __shared__ float4 e3S[128];          // 2 KB: ev2 {w0,w1,w2,b}
  __shared__ float4 relS[8 * 16];      // 2 KB: per (pt, s) {r0,r1,r2,aw}

  for (int i = t; i < 384; i += 256) {
    int e = i >> 7, c = i & 127;
    const float* wsrc = (e == 0) ? eqw : (e == 1) ? ekw : ev1w;
    const float* bsrc = (e == 0) ? eqb : (e == 1) ? ekb : ev1b;
    int xe = e ^ ((c >> 3) & 3);
    float* dst = &encS[c * 16 + xe * 4];
    dst[0] = wsrc[c * 3]; dst[1] = wsrc[c * 3 + 1];
    dst[2] = wsrc[c * 3 + 2]; dst[3] = bsrc[c];
  }
  if (t < 128)
    e3S[t] = make_float4(ev2w[t * 3], ev2w[t * 3 + 1], ev2w[t * 3 + 2], ev2b[t]);
  for (int i = t; i < 1024; i += 256) {
    int p = i >> 7, c = i & 127;
    f1s[p * 132 + c] = bf2f(f1p[(size_t)(b * NN1 + base8 + p) * 128 + c]);
  }

  const int pt0 = base8 + w * 2, pt1 = pt0 + 1;
  const int j0 = idxb[(b * NN1 + pt0) * 16 + l15];
  const int j1 = idxb[(b * NN1 + pt1) * 16 + l15];
  float4 qc0 = px1[b * NN1 + pt0];
  float4 qc1 = px1[b * NN1 + pt1];
  float4 cc0 = px2[b * NN2 + j0];
  float4 cc1 = px2[b * NN2 + j1];
  float r0[2], r1[2], r2[2];
  r0[0] = cc0.x - qc0.x; r1[0] = cc0.y - qc0.y; r2[0] = cc0.z - qc0.z;
  r0[1] = cc1.x - qc1.x; r1[1] = cc1.y - qc1.y; r2[1] = cc1.z - qc1.z;

  const u16* row0 = f2p + (size_t)(b * NN2 + j0) * 128;
  const u16* row1 = f2p + (size_t)(b * NN2 + j1) * 128;
  __syncthreads();

  // ---- bq fragments: qin = f1 * leaky(eq.r + b), B-layout ----
  bf16x8 bq[2][4];
#pragma unroll
  for (int ks = 0; ks < 4; ++ks) {
#pragma unroll
    for (int j = 0; j < 8; ++j) {
      int c = ks * 32 + l4 * 8 + j;
      float4 ew = ld_enc(encS, 0, c);
      float f10 = f1s[(w * 2 + 0) * 132 + c];
      float f11 = f1s[(w * 2 + 1) * 132 + c];
      float e0 = leaky(ew.x * r0[0] + ew.y * r1[0] + ew.z * r2[0] + ew.w);
      float e1 = leaky(ew.x * r0[1] + ew.y * r1[1] + ew.z * r2[1] + ew.w);
      bq[0][ks][j] = (short)f2bf(f10 * e0);
      bq[1][ks][j] = (short)f2bf(f11 * e1);
    }
  }

  // ---- GEMM1 (q = Wq @ qin) interleaved with attention dot per mt;
  //      kd rolling 2-deep prefetch ----
  float dp0 = 0.0f, dp1 = 0.0f;
  uint2 kc0 = *(const uint2*)(row0 + l4 * 4);
  uint2 kc1 = *(const uint2*)(row1 + l4 * 4);
#pragma unroll
  for (int mt = 0; mt < 8; ++mt) {
    uint2 kn0 = kc0, kn1 = kc1;
    if (mt < 7) {
      kn0 = *(const uint2*)(row0 + (mt + 1) * 16 + l4 * 4);
      kn1 = *(const uint2*)(row1 + (mt + 1) * 16 + l4 * 4);
    }
    f32x4 a0 = (f32x4){0.f, 0.f, 0.f, 0.f};
    f32x4 a1 = (f32x4){0.f, 0.f, 0.f, 0.f};
#pragma unroll
    for (int ks = 0; ks < 4; ++ks) {
      bf16x8 af = *(const bf16x8*)&wq[(mt * 16 + l15) * 128 + ks * 32 + l4 * 8];
      a0 = __builtin_amdgcn_mfma_f32_16x16x32_bf16(af, bq[0][ks], a0, 0, 0, 0);
      a1 = __builtin_amdgcn_mfma_f32_16x16x32_bf16(af, bq[1][ks], a1, 0, 0, 0);
    }
    float f2v0[4] = { bflo(kc0.x), bfhi(kc0.x), bflo(kc0.y), bfhi(kc0.y) };
    float f2v1[4] = { bflo(kc1.x), bfhi(kc1.x), bflo(kc1.y), bfhi(kc1.y) };
#pragma unroll
    for (int r = 0; r < 4; ++r) {
      int c = mt * 16 + l4 * 4 + r;
      float4 ew = ld_enc(encS, 1, c);
      float ek0 = leaky(ew.x * r0[0] + ew.y * r1[0] + ew.z * r2[0] + ew.w);
      float ek1 = leaky(ew.x * r0[1] + ew.y * r1[1] + ew.z * r2[1] + ew.w);
      dp0 += a0[r] * (f2v0[r] * ek0);
      dp1 += a1[r] * (f2v1[r] * ek1);
    }
    kc0 = kn0; kc1 = kn1;
  }

  // V-path gather (B-layout fragments), issued before softmax to hide latency
  bf16x8 fB[2][4];
#pragma unroll
  for (int ks = 0; ks < 4; ++ks) {
    fB[0][ks] = *(const bf16x8*)(row0 + ks * 32 + l4 * 8);
    fB[1][ks] = *(const bf16x8*)(row1 + ks * 32 + l4 * 8);
  }

  // reduce dot over l4 groups, then 16-lane softmax
  dp0 += __shfl_xor(dp0, 16); dp0 += __shfl_xor(dp0, 32);
  dp1 += __shfl_xor(dp1, 16); dp1 += __shfl_xor(dp1, 32);
  float aw0, aw1;
  {
    float x = dp0 * 0.08838834764831845f;
    float m = x;
#pragma unroll
    for (int o = 1; o < 16; o <<= 1) m = fmaxf(m, __shfl_xor(m, o));
    float e = __expf(x - m);
    float s = e;
#pragma unroll
    for (int o = 1; o < 16; o <<= 1) s += __shfl_xor(s, o);
    aw0 = e / s;
  }
  {
    float x = dp1 * 0.08838834764831845f;
    float m = x;
#pragma unroll
    for (int o = 1; o < 16; o <<= 1) m = fmaxf(m, __shfl_xor(m, o));
    float e = __expf(x - m);
    float s = e;
#pragma unroll
    for (int o = 1; o < 16; o <<= 1) s += __shfl_xor(s, o);
    aw1 = e / s;
  }

  // stage {rel, aw} per (point, sample) for the transposed epilogue.
  if (l < 16) {
    relS[(w * 2 + 0) * 16 + l] = make_float4(r0[0], r1[0], r2[0], aw0);
    relS[(w * 2 + 1) * 16 + l] = make_float4(r0[1], r1[1], r2[1], aw1);
  }

  // ---- bv fragments: vin = f2 * leaky(ev1.r + b) ----
  bf16x8 bv[2][4];
#pragma unroll
  for (int ks = 0; ks < 4; ++ks) {
#pragma unroll
    for (int j = 0; j < 8; ++j) {
      int c = ks * 32 + l4 * 8 + j;
      float4 ew = ld_enc(encS, 2, c);
      float e0 = leaky(ew.x * r0[0] + ew.y * r1[0] + ew.z * r2[0] + ew.w);
      float e1 = leaky(ew.x * r0[1] + ew.y * r1[1] + ew.z * r2[1] + ew.w);
      bv[0][ks][j] = (short)f2bf(bf2f((u16)fB[0][ks][j]) * e0);
      bv[1][ks][j] = (short)f2bf(bf2f((u16)fB[1][ks][j]) * e1);
    }
  }

  // ---- GEMM2 swapped: D = vin^T . Wv^T -> lane holds v[m][s=l4*4+r] ----
#pragma unroll
  for (int mt = 0; mt < 8; ++mt) {
    f32x4 a0 = (f32x4){0.f, 0.f, 0.f, 0.f};
    f32x4 a1 = (f32x4){0.f, 0.f, 0.f, 0.f};
#pragma unroll
    for (int ks = 0; ks < 4; ++ks) {
      bf16x8 bf = *(const bf16x8*)&wvm[(mt * 16 + l15) * 128 + ks * 32 + l4 * 8];
      a0 = __builtin_amdgcn_mfma_f32_16x16x32_bf16(bv[0][ks], bf, a0, 0, 0, 0);
      a1 = __builtin_amdgcn_mfma_f32_16x16x32_bf16(bv[1][ks], bf, a1, 0, 0, 0);
    }
    const int m = mt * 16 + l15;
    float4 ew = e3S[m];                 // one ev2-param load per mt
    float acc0 = 0.0f, acc1 = 0.0f;
#pragma unroll
    for (int r = 0; r < 4; ++r) {
      float4 ra = relS[(w * 2 + 0) * 16 + l4 * 4 + r];
      float4 rb = relS[(w * 2 + 1) * 16 + l4 * 4 + r];
      float e0 = leaky(ew.x * ra.x + ew.y * ra.y + ew.z * ra.z + ew.w);
      float e1 = leaky(ew.x * rb.x + ew.y * rb.y + ew.z * rb.z + ew.w);
      acc0 += a0[r] * e0 * ra.w;        // .w carries the softmax weight
      acc1 += a1[r] * e1 * rb.w;
    }
    acc0 += __shfl_xor(acc0, 16); acc0 += __shfl_xor(acc0, 32);
    acc1 += __shfl_xor(acc1, 16); acc1 += __shfl_xor(acc1, 32);
    if (l < 16) {                       // coalesced 32B segment per (mt, pt)
      outp[(size_t)(b * NN1 + pt0) * 128 + m] =
          f2bf(acc0 + f1s[(w * 2 + 0) * 132 + m]);
      outp[(size_t)(b * NN1 + pt1) * 128 + m] =
          f2bf(acc1 + f1s[(w * 2 + 1) * 132 + m]);
    }
  }
}

// ---------------------------------------------------------------------------
// FF via MFMA: h[b][d][n] = ff_w[d,:].feat_new[b][n][:] + ff_b[d], bf16 out.
// Block = 64 points, wave = 16 points. Per-block GN partials -> pstat (f32,
// computed before the bf16 rounding).
__global__ __launch_bounds__(256)
void k_ff(const u16* __restrict__ xb, const u16* __restrict__ wfb,
          const float* __restrict__ ffb, u16* __restrict__ hout,
          float* __restrict__ pstat) {
  const int t = threadIdx.x, bx = blockIdx.x;
  const int w = t >> 6, l = t & 63, l15 = l & 15, l4 = l >> 4;
  __shared__ float bS[128];
  __shared__ float red[4][16];
  if (t < 128) bS[t] = ffb[t];
  const int pt = bx * 64 + w * 16 + l15;     // global point 0..16383
  const int b = pt >> 13, n = pt & 8191;
  const u16* row = xb + (size_t)pt * 128;
  bf16x8 bfrag[4];
#pragma unroll
  for (int ks = 0; ks < 4; ++ks)
    bfrag[ks] = *(const bf16x8*)(row + ks * 32 + l4 * 8);
  __syncthreads();
  float gs[8], gss[8];
#pragma unroll
  for (int mt = 0; mt < 8; ++mt) {
    f32x4 a = (f32x4){0.f, 0.f, 0.f, 0.f};
#pragma unroll
    for (int ks = 0; ks < 4; ++ks) {
      bf16x8 af = *(const bf16x8*)&wfb[(mt * 16 + l15) * 128 + ks * 32 + l4 * 8];
      a = __builtin_amdgcn_mfma_f32_16x16x32_bf16(af, bfrag[ks], a, 0, 0, 0);
    }
    int d0 = mt * 16 + l4 * 4;
    float s = 0.0f, ss = 0.0f;
#pragma unroll
    for (int r = 0; r < 4; ++r) {
      float h = a[r] + bS[d0 + r];
      hout[(size_t)(b * 128 + d0 + r) * 8192 + n] = f2bf(h);
      s += h; ss += h * h;
    }
    gs[mt] = s; gss[mt] = ss;
  }
#pragma unroll
  for (int mt = 0; mt < 8; ++mt) {
#pragma unroll
    for (int o = 1; o < 64; o <<= 1) {
      gs[mt] += __shfl_xor(gs[mt], o);
      gss[mt] += __shfl_xor(gss[mt], o);
    }
  }
  if (l == 0) {
#pragma unroll
    for (int mt = 0; mt < 8; ++mt) {
      red[w][mt * 2 + 0] = gs[mt];
      red[w][mt * 2 + 1] = gss[mt];
    }
  }
  __syncthreads();
  if (t < 16) {
    float tot = red[0][t] + red[1][t] + red[2][t] + red[3][t];
    pstat[bx * 16 + t] = tot;
  }
}

// Reduce pstat[256][16] -> gnf[2][8][2]. (128 blocks per batch.)
__global__ __launch_bounds__(512)
void k_ffred(const float* __restrict__ pstat, float* __restrict__ gnf) {
  __shared__ float red[512];
  int t = threadIdx.x;
  int b = t >> 8, i = t & 15, chunk = (t >> 4) & 15;
  float s = 0.0f;
#pragma unroll
  for (int k = 0; k < 8; ++k)
    s += pstat[(b * 128 + chunk * 8 + k) * 16 + i];
  red[t] = s;
  __syncthreads();
  if (chunk == 0) {
    float tot = 0.0f;
#pragma unroll
    for (int k2 = 0; k2 < 16; ++k2) tot += red[(b << 8) | (k2 << 4) | i];
    gnf[b * 16 + i] = tot;
  }
}

// Final GN + leaky + f32 store (2 elems/thread, bf16 input); also writes the
// xyz1 passthrough (blocks >= 4096).
__global__ __launch_bounds__(256)
void k_final(const u16* __restrict__ h, const float* __restrict__ gnf,
             const float* __restrict__ g, const float* __restrict__ bt,
             const float* __restrict__ xyz1, float* __restrict__ out) {
  int bx = blockIdx.x;
  if (bx >= 4096) {
    int e = (bx - 4096) * 256 + threadIdx.x;   // < BB*3*NN1 = 49152
    out[e] = xyz1[e];
    return;
  }
  int e2 = (bx * 256 + threadIdx.x) * 2;       // < BB*128*NN1 = 2097152
  int d = (e2 >> 13) & 127;
  int b = e2 >> 20;
  int gi = b * 16 + (d >> 4) * 2;
  float cnt = 16.0f * (float)NN1;
  float mu = gnf[gi] / cnt;
  float var = gnf[gi + 1] / cnt - mu * mu;
  float rs = rsqrtf(var + 1e-5f);
  u32 hw = *(const u32*)&h[e2];
  float x0 = (bflo(hw) - mu) * rs * g[d] + bt[d];
  float x1 = (bfhi(hw) - mu) * rs * g[d] + bt[d];
  float2 ov = { leaky(x0), leaky(x1) };
  *(float2*)&out[BB * 3 * NN1 + e2] = ov;
}

// ---------------------------------------------------------------------------
extern "C" void kernel_launch(void* const* d_in, const int* in_sizes, int n_in,
                              void* d_out, int out_size, void* d_ws, size_t ws_size,
                              hipStream_t stream) {
  const float* xyz1   = (const float*)d_in[0];
  const float* xyz2   = (const float*)d_in[1];
  const float* feat1  = (const float*)d_in[2];
  const float* feat2  = (const float*)d_in[3];
  const float* pos_w  = (const float*)d_in[4];
  const float* pos_b  = (const float*)d_in[5];
  const float* pos_g  = (const float*)d_in[6];
  const float* pos_bt = (const float*)d_in[7];
  const float* ek_w   = (const float*)d_in[8];
  const float* ek_b   = (const float*)d_in[9];
  const float* eq_w   = (const float*)d_in[10];
  const float* eq_b   = (const float*)d_in[11];
  const float* ev1_w  = (const float*)d_in[12];
  const float* ev1_b  = (const float*)d_in[13];
  const float* ev2_w  = (const float*)d_in[14];
  const float* ev2_b  = (const float*)d_in[15];
  const float* qk_w   = (const float*)d_in[16];
  const float* v_w    = (const float*)d_in[17];
  const float* ff_w   = (const float*)d_in[18];
  const float* ff_b   = (const float*)d_in[19];
  const float* ff_g   = (const float*)d_in[20];
  const float* ff_bt  = (const float*)d_in[21];
  (void)in_sizes; (void)n_in; (void)out_size; (void)ws_size;

  char* ws = (char*)d_ws;          // ~18.5 MB used
  u16*    f1pb     = (u16*)  (ws);                        // [B][N1][C] bf16  4194304 B
  u16*    feat2pb  = (u16*)  (ws + 4194304);              // [B][N2][C] bf16  4194304 B
  u16*    attn_out = (u16*)  (ws + 8388608);              // feat_new bf16    4194304 B
  u16*    h_ffb    = (u16*)  (ws + 12582912);             // FF out bf16      4194304 B
  int*    idxb     = (int*)  (ws + 16777216);             // [B][N1][16]      1048576 B
  u16*    wqk      = (u16*)  (ws + 17825792);             // bf16 qk_w        32768 B
  u16*    wv       = (u16*)  (ws + 17858560);             // bf16 v_w         32768 B
  u16*    wff      = (u16*)  (ws + 17891328);             // bf16 ff_w        32768 B
  float*  mom_part = (float*)(ws + 17924096);             // 128*9 floats     4608 B
  float2* gnp      = (float2*)(ws + 17928704);            // 32 float2        256 B
  float*  pstat    = (float*)(ws + 17928960);             // 256*16 floats    16384 B
  float*  gnf      = (float*)(ws + 17945344);             // 32 floats        128 B
  float4* px1      = (float4*)(ws + 17945472);            // [B][N1] packed   262144 B
  float4* px2      = (float4*)(ws + 18207616);            // [B][N2] packed   262144 B

  k_prep<<<320, 256, 0, stream>>>(qk_w, v_w, ff_w, wqk, wv, wff,
                                  xyz1, xyz2, px1, px2, mom_part);
  k_gnstats<<<1, 512, 0, stream>>>(mom_part, pos_w, pos_b, gnp);
  k_pk<<<6144, 256, 0, stream>>>(px1, px2, idxb, xyz1, xyz2, feat1, feat2,
                                 pos_w, pos_b, pos_g, pos_bt, gnp, f1pb, feat2pb);
  k_attn<<<2048, 256, 0, stream>>>(px1, px2, f1pb, feat2pb, idxb, wqk, wv,
                                   eq_w, eq_b, ek_w, ek_b, ev1_w, ev1_b, ev2_w, ev2_b,
                                   attn_out);
  k_ff<<<256, 256, 0, stream>>>(attn_out, wff, ff_b, h_ffb, pstat);
  k_ffred<<<1, 512, 0, stream>>>(pstat, gnf);
  k_final<<<4288, 256, 0, stream>>>(h_ffb, gnf, ff_g, ff_bt, xyz1, (float*)d_out);
}

// Round 18
// 201.136 us; speedup vs baseline: 1.7120x; 1.0009x over previous
//
#include <hip/hip_runtime.h>
#include <hip/hip_bf16.h>

// Problem constants (reference: B,N1,N2,C,COUT,NS = 2,8192,8192,128,128,16)
#define BB  2
#define NN1 8192
#define NN2 8192
#define CC  128
#define SS  16

typedef unsigned short u16;
typedef unsigned int u32;
typedef short bf16x8 __attribute__((ext_vector_type(8)));
typedef float f32x4  __attribute__((ext_vector_type(4)));

__device__ __forceinline__ u16 f2bf(float f) {
  __hip_bfloat16 h = __float2bfloat16(f);      // RNE
  return *(u16*)&h;
}
__device__ __forceinline__ float bf2f(u16 u) {
  union { float f; unsigned int u; } v; v.u = ((unsigned int)u) << 16;
  return v.f;
}
__device__ __forceinline__ float bflo(u32 w) {
  union { float f; unsigned int u; } v; v.u = w << 16; return v.f;
}
__device__ __forceinline__ float bfhi(u32 w) {
  union { float f; unsigned int u; } v; v.u = w & 0xFFFF0000u; return v.f;
}
__device__ __forceinline__ float leaky(float x) { return x >= 0.0f ? x : 0.1f * x; }

// ---------------------------------------------------------------------------
// prep: convert qk_w/v_w/ff_w to bf16; pack xyz -> float4{x,y,z,|p|2}; write
// per-block xyz-moment partials (9 sums) non-atomically to mom_part[128][9].
__global__ __launch_bounds__(256)
void k_prep(const float* __restrict__ qkw, const float* __restrict__ vw,
            const float* __restrict__ ffw,
            u16* __restrict__ oa, u16* __restrict__ ob, u16* __restrict__ of,
            const float* __restrict__ xyz1, const float* __restrict__ xyz2,
            float4* __restrict__ px1, float4* __restrict__ px2,
            float* __restrict__ mom_part) {
  int bx = blockIdx.x, t = threadIdx.x;
  if (bx < 192) {
    int e = bx * 256 + t;
    if (e < 16384) oa[e] = f2bf(qkw[e]);
    else if (e < 32768) ob[e - 16384] = f2bf(vw[e - 16384]);
    else of[e - 32768] = f2bf(ffw[e - 32768]);
    return;
  }
  __shared__ float wred[4][9];
  const float* xyz; float4* px; int e;
  if (bx < 256) { e = (bx - 192) * 256 + t; xyz = xyz1; px = px1; }
  else          { e = (bx - 256) * 256 + t; xyz = xyz2; px = px2; }
  int b = e >> 13, n = e & 8191;
  float x = xyz[(b * 3 + 0) * 8192 + n];
  float y = xyz[(b * 3 + 1) * 8192 + n];
  float z = xyz[(b * 3 + 2) * 8192 + n];
  px[e] = make_float4(x, y, z, x * x + y * y + z * z);
  float s[9] = { x, y, z, x * x, y * y, z * z, x * y, x * z, y * z };
#pragma unroll
  for (int o = 1; o < 64; o <<= 1)
#pragma unroll
    for (int i = 0; i < 9; ++i) s[i] += __shfl_xor(s[i], o);
  int w = t >> 6;
  if ((t & 63) == 0)
#pragma unroll
    for (int i = 0; i < 9; ++i) wred[w][i] = s[i];
  __syncthreads();
  if (t < 9) {
    float tot = wred[0][t] + wred[1][t] + wred[2][t] + wred[3][t];
    mom_part[(bx - 192) * 9 + t] = tot;
  }
}

// Analytic GN stats for pos-enc (reduces mom_part itself).
__global__ __launch_bounds__(512)
void k_gnstats(const float* __restrict__ mom_part, const float* __restrict__ pw,
               const float* __restrict__ pb, float2* __restrict__ gnp) {
  int t = threadIdx.x;                 // 512: cloud(2) x b(2) x c(128)
  int cl = t >> 8, b = (t >> 7) & 1, c = t & 127;
  const float* P = mom_part + (cl * 64 + b * 32) * 9;
  float M[9];
#pragma unroll
  for (int i = 0; i < 9; ++i) {
    float sum = 0.0f;
    for (int k = 0; k < 32; ++k) sum += P[k * 9 + i];
    M[i] = sum;
  }
  const float inv = 1.0f / 8192.0f;
  float mx = M[0] * inv, my = M[1] * inv, mz = M[2] * inv;
  float sxx = M[3] * inv, syy = M[4] * inv, szz = M[5] * inv;
  float sxy = M[6] * inv, sxz = M[7] * inv, syz = M[8] * inv;
  float w0 = pw[c * 3], w1 = pw[c * 3 + 1], w2 = pw[c * 3 + 2], bc = pb[c];
  float wm = w0 * mx + w1 * my + w2 * mz;
  float Eh = wm + bc;
  float wSw = w0 * w0 * sxx + w1 * w1 * syy + w2 * w2 * szz
            + 2.0f * (w0 * w1 * sxy + w0 * w2 * sxz + w1 * w2 * syz);
  float Eh2 = wSw + 2.0f * bc * wm + bc * bc;
#pragma unroll
  for (int o = 1; o < 16; o <<= 1) { Eh += __shfl_xor(Eh, o); Eh2 += __shfl_xor(Eh2, o); }
  if ((c & 15) == 0) {
    float mu = Eh * 0.0625f;
    float var = Eh2 * 0.0625f - mu * mu;
    gnp[cl * 16 + b * 8 + (c >> 4)] = make_float2(mu, rsqrtf(var + 1e-5f));
  }
}

// ---------------------------------------------------------------------------
// KNN helpers. Packed key: (f32 distance^2 bits & 0xFFFFE000) | index (13b).

__device__ __forceinline__ u32 knnkey(float4 qv, float4 c, u32 idx) {
  float m = fmaf(qv.x, c.x, fmaf(qv.y, c.y, qv.z * c.z));
  float d = fmaf(-2.0f, m, qv.w + c.w);
  d = fmaxf(d, 0.0f);
  return (__float_as_uint(d) & 0xFFFFE000u) | idx;
}

__device__ __forceinline__ void ce_x(u32& v, int j, bool up, int l) {
  u32 p = __shfl_xor(v, j);
  u32 mn = v < p ? v : p;
  u32 mx = v < p ? p : v;
  bool lower = ((l & j) == 0);
  v = (lower == up) ? mn : mx;
}

// Bitonic sort of 128 keys (2 regs/lane, element i = reg*64 + lane), ascending.
__device__ __forceinline__ void sort128(u32& v0, u32& v1, int l) {
#pragma unroll
  for (int k = 2; k <= 64; k <<= 1) {
#pragma unroll
    for (int j = k >> 1; j > 0; j >>= 1) {
      ce_x(v0, j, ((l & k) == 0), l);
      ce_x(v1, j, (((l + 64) & k) == 0), l);
    }
  }
  { u32 mn = v0 < v1 ? v0 : v1; u32 mx = v0 < v1 ? v1 : v0; v0 = mn; v1 = mx; }
#pragma unroll
  for (int j = 32; j > 0; j >>= 1) {
    ce_x(v0, j, true, l);
    ce_x(v1, j, true, l);
  }
}

// ---------------------------------------------------------------------------
// Fused KNN + pos-enc. Blocks [0,4096): KNN (wave-per-query, ballot filter,
// rolling prefetch). Blocks [4096,6144): pos-enc (featp = feat + leaky(GN)),
// both clouds written bf16.
__global__ __launch_bounds__(256)
void k_pk(const float4* __restrict__ px1, const float4* __restrict__ px2,
          int* __restrict__ idxout,
          const float* __restrict__ xyz1, const float* __restrict__ xyz2,
          const float* __restrict__ feat1, const float* __restrict__ feat2,
          const float* __restrict__ pw, const float* __restrict__ pb,
          const float* __restrict__ gam, const float* __restrict__ bet,
          const float2* __restrict__ gnp,
          u16* __restrict__ outb1, u16* __restrict__ outb2) {
  __shared__ float smem[128 * 17];     // posenc T[128][17]; knn reuses 2KB
  int bx = blockIdx.x, t = threadIdx.x;

  if (bx < 4096) {
    // ---------------- KNN part ----------------
    int w = t >> 6, l = t & 63;
    int q = bx * 4 + w;                // 0..16383
    int b = q >> 13;
    float4 qv = px1[q];
    const float4* cp = px2 + (b << 13);
    u32* wb = ((u32*)smem) + w * 128;
    u32 kth = 0xFFFFFFFFu;
    int cnt = 0;
    const unsigned long long below = (1ull << l) - 1ull;
    float4 c_cur = cp[l];
    for (int it = 0; it < 128; ++it) {
      float4 c_nxt = c_cur;
      if (it < 127) c_nxt = cp[(it + 1) * 64 + l];   // rolling prefetch
      u32 key = knnkey(qv, c_cur, (u32)(it * 64 + l));
      bool pass = key < kth;
      unsigned long long mask = __ballot(pass);
      if (mask) {
        int off = cnt + (int)__popcll(mask & below);
        if (pass) wb[off] = key;
        cnt += (int)__popcll(mask);
        if (cnt > 64) {                // before append cnt<=64 -> cnt<=128 here
          u32 v0 = (l < cnt) ? wb[l] : 0xFFFFFFFFu;
          u32 v1 = (64 + l < cnt) ? wb[64 + l] : 0xFFFFFFFFu;
          sort128(v0, v1, l);
          if (l < 16) wb[l] = v0;
          cnt = 16;
          kth = __shfl(v0, 15);
        }
      }
      c_cur = c_nxt;
    }
    u32 v0 = (l < cnt) ? wb[l] : 0xFFFFFFFFu;
    u32 v1 = (64 + l < cnt) ? wb[64 + l] : 0xFFFFFFFFu;
    sort128(v0, v1, l);
    if (l < 16) idxout[q * 16 + l] = (int)(v0 & 8191u);
    return;
  }

  // ---------------- pos-enc part ----------------
  bx -= 4096;
  const float* xyz; const float* feat; const float2* gp; u16* outb;
  if (bx < 1024) { xyz = xyz1; feat = feat1; gp = gnp;      outb = outb1; }
  else           { xyz = xyz2; feat = feat2; gp = gnp + 16; outb = outb2; bx -= 1024; }
  const int N = 8192;
  int b = bx / 512, n0 = (bx % 512) * 16;
  for (int it = 0; it < 8; ++it) {
    int j = t & 15, c = it * 16 + (t >> 4);
    smem[c * 17 + j] = feat[(b * 128 + c) * N + n0 + j];
  }
  int c = t & 127;
  float w0 = pw[c * 3], w1 = pw[c * 3 + 1], w2 = pw[c * 3 + 2], bc = pb[c];
  float2 g2 = gp[b * 8 + (c >> 4)];
  float gm = gam[c], b2 = bet[c];
  __syncthreads();
  for (int it = 0; it < 8; ++it) {
    int j = it * 2 + (t >> 7);
    int n = n0 + j;
    float xs = xyz[(b * 3 + 0) * N + n];
    float ys = xyz[(b * 3 + 1) * N + n];
    float zs = xyz[(b * 3 + 2) * N + n];
    float hv = w0 * xs + w1 * ys + w2 * zs + bc;
    float xo = (hv - g2.x) * g2.y * gm + b2;
    float r = smem[c * 17 + j] + leaky(xo);
    outb[(size_t)(b * N + n) * 128 + c] = f2bf(r);
  }
}

// ---------------------------------------------------------------------------
// Fused attention (r12 structure, proven VGPR=80 config): wave-local, 2 points
// per wave, f2 read from global; GEMM2 swapped; fB gathered between GEMM1 and
// softmax; bv after softmax; kd rolling 2-deep prefetch. f1 input bf16,
// output bf16. NEW: XCD-aware bijective block swizzle (grid 2048 % 8 == 0)
// so each XCD serves a contiguous query range -> clustered f2 gather set.
__device__ __forceinline__ float4 ld_enc(const float* encS, int e, int c) {
  int xe = e ^ ((c >> 3) & 3);
  return *(const float4*)&encS[c * 16 + xe * 4];
}

__global__ __launch_bounds__(256, 2)
void k_attn(const float4* __restrict__ px1, const float4* __restrict__ px2,
            const u16* __restrict__ f1p, const u16* __restrict__ f2p,
            const int* __restrict__ idxb,
            const u16* __restrict__ wq, const u16* __restrict__ wvm,
            const float* __restrict__ eqw, const float* __restrict__ eqb,
            const float* __restrict__ ekw, const float* __restrict__ ekb,
            const float* __restrict__ ev1w, const float* __restrict__ ev1b,
            const float* __restrict__ ev2w, const float* __restrict__ ev2b,
            u16* __restrict__ outp) {
  const int t = threadIdx.x;
  const int bx = ((blockIdx.x & 7) << 8) | (blockIdx.x >> 3);  // XCD swizzle
  const int b = bx >> 10;              // 1024 work-ids per batch
  const int base8 = (bx & 1023) * 8;   // 8 points per block (2 per wave)
  const int w = t >> 6, l = t & 63, l15 = l & 15, l4 = l >> 4;

  __shared__ float encS[128 * 16];     // 8 KB: eq, ek, ev1 (XOR slots)
  __shared__ float f1s[8 * 132];       // 4.2 KB
  __shared__ float4 e3S[128];          // 2 KB: ev2 {w0,w1,w2,b}
  __shared__ float4 relS[8 * 16];      // 2 KB: per (pt, s) {r0,r1,r2,aw}

  for (int i = t; i < 384; i += 256) {
    int e = i >> 7, c = i & 127;
    const float* wsrc = (e == 0) ? eqw : (e == 1) ? ekw : ev1w;
    const float* bsrc = (e == 0) ? eqb : (e == 1) ? ekb : ev1b;
    int xe = e ^ ((c >> 3) & 3);
    float* dst = &encS[c * 16 + xe * 4];
    dst[0] = wsrc[c * 3]; dst[1] = wsrc[c * 3 + 1];
    dst[2] = wsrc[c * 3 + 2]; dst[3] = bsrc[c];
  }
  if (t < 128)
    e3S[t] = make_float4(ev2w[t * 3], ev2w[t * 3 + 1], ev2w[t * 3 + 2], ev2b[t]);
  for (int i = t; i < 1024; i += 256) {
    int p = i >> 7, c = i & 127;
    f1s[p * 132 + c] = bf2f(f1p[(size_t)(b * NN1 + base8 + p) * 128 + c]);
  }

  const int pt0 = base8 + w * 2, pt1 = pt0 + 1;
  const int j0 = idxb[(b * NN1 + pt0) * 16 + l15];
  const int j1 = idxb[(b * NN1 + pt1) * 16 + l15];
  float4 qc0 = px1[b * NN1 + pt0];
  float4 qc1 = px1[b * NN1 + pt1];
  float4 cc0 = px2[b * NN2 + j0];
  float4 cc1 = px2[b * NN2 + j1];
  float r0[2], r1[2], r2[2];
  r0[0] = cc0.x - qc0.x; r1[0] = cc0.y - qc0.y; r2[0] = cc0.z - qc0.z;
  r0[1] = cc1.x - qc1.x; r1[1] = cc1.y - qc1.y; r2[1] = cc1.z - qc1.z;

  const u16* row0 = f2p + (size_t)(b * NN2 + j0) * 128;
  const u16* row1 = f2p + (size_t)(b * NN2 + j1) * 128;
  __syncthreads();

  // ---- bq fragments: qin = f1 * leaky(eq.r + b), B-layout ----
  bf16x8 bq[2][4];
#pragma unroll
  for (int ks = 0; ks < 4; ++ks) {
#pragma unroll
    for (int j = 0; j < 8; ++j) {
      int c = ks * 32 + l4 * 8 + j;
      float4 ew = ld_enc(encS, 0, c);
      float f10 = f1s[(w * 2 + 0) * 132 + c];
      float f11 = f1s[(w * 2 + 1) * 132 + c];
      float e0 = leaky(ew.x * r0[0] + ew.y * r1[0] + ew.z * r2[0] + ew.w);
      float e1 = leaky(ew.x * r0[1] + ew.y * r1[1] + ew.z * r2[1] + ew.w);
      bq[0][ks][j] = (short)f2bf(f10 * e0);
      bq[1][ks][j] = (short)f2bf(f11 * e1);
    }
  }

  // ---- GEMM1 (q = Wq @ qin) interleaved with attention dot per mt;
  //      kd rolling 2-deep prefetch ----
  float dp0 = 0.0f, dp1 = 0.0f;
  uint2 kc0 = *(const uint2*)(row0 + l4 * 4);
  uint2 kc1 = *(const uint2*)(row1 + l4 * 4);
#pragma unroll
  for (int mt = 0; mt < 8; ++mt) {
    uint2 kn0 = kc0, kn1 = kc1;
    if (mt < 7) {
      kn0 = *(const uint2*)(row0 + (mt + 1) * 16 + l4 * 4);
      kn1 = *(const uint2*)(row1 + (mt + 1) * 16 + l4 * 4);
    }
    f32x4 a0 = (f32x4){0.f, 0.f, 0.f, 0.f};
    f32x4 a1 = (f32x4){0.f, 0.f, 0.f, 0.f};
#pragma unroll
    for (int ks = 0; ks < 4; ++ks) {
      bf16x8 af = *(const bf16x8*)&wq[(mt * 16 + l15) * 128 + ks * 32 + l4 * 8];
      a0 = __builtin_amdgcn_mfma_f32_16x16x32_bf16(af, bq[0][ks], a0, 0, 0, 0);
      a1 = __builtin_amdgcn_mfma_f32_16x16x32_bf16(af, bq[1][ks], a1, 0, 0, 0);
    }
    float f2v0[4] = { bflo(kc0.x), bfhi(kc0.x), bflo(kc0.y), bfhi(kc0.y) };
    float f2v1[4] = { bflo(kc1.x), bfhi(kc1.x), bflo(kc1.y), bfhi(kc1.y) };
#pragma unroll
    for (int r = 0; r < 4; ++r) {
      int c = mt * 16 + l4 * 4 + r;
      float4 ew = ld_enc(encS, 1, c);
      float ek0 = leaky(ew.x * r0[0] + ew.y * r1[0] + ew.z * r2[0] + ew.w);
      float ek1 = leaky(ew.x * r0[1] + ew.y * r1[1] + ew.z * r2[1] + ew.w);
      dp0 += a0[r] * (f2v0[r] * ek0);
      dp1 += a1[r] * (f2v1[r] * ek1);
    }
    kc0 = kn0; kc1 = kn1;
  }

  // V-path gather (B-layout fragments), issued before softmax to hide latency
  bf16x8 fB[2][4];
#pragma unroll
  for (int ks = 0; ks < 4; ++ks) {
    fB[0][ks] = *(const bf16x8*)(row0 + ks * 32 + l4 * 8);
    fB[1][ks] = *(const bf16x8*)(row1 + ks * 32 + l4 * 8);
  }

  // reduce dot over l4 groups, then 16-lane softmax
  dp0 += __shfl_xor(dp0, 16); dp0 += __shfl_xor(dp0, 32);
  dp1 += __shfl_xor(dp1, 16); dp1 += __shfl_xor(dp1, 32);
  float aw0, aw1;
  {
    float x = dp0 * 0.08838834764831845f;
    float m = x;
#pragma unroll
    for (int o = 1; o < 16; o <<= 1) m = fmaxf(m, __shfl_xor(m, o));
    float e = __expf(x - m);
    float s = e;
#pragma unroll
    for (int o = 1; o < 16; o <<= 1) s += __shfl_xor(s, o);
    aw0 = e / s;
  }
  {
    float x = dp1 * 0.08838834764831845f;
    float m = x;
#pragma unroll
    for (int o = 1; o < 16; o <<= 1) m = fmaxf(m, __shfl_xor(m, o));
    float e = __expf(x - m);
    float s = e;
#pragma unroll
    for (int o = 1; o < 16; o <<= 1) s += __shfl_xor(s, o);
    aw1 = e / s;
  }

  // stage {rel, aw} per (point, sample) for the transposed epilogue.
  if (l < 16) {
    relS[(w * 2 + 0) * 16 + l] = make_float4(r0[0], r1[0], r2[0], aw0);
    relS[(w * 2 + 1) * 16 + l] = make_float4(r0[1], r1[1], r2[1], aw1);
  }

  // ---- bv fragments: vin = f2 * leaky(ev1.r + b) ----
  bf16x8 bv[2][4];
#pragma unroll
  for (int ks = 0; ks < 4; ++ks) {
#pragma unroll
    for (int j = 0; j < 8; ++j) {
      int c = ks * 32 + l4 * 8 + j;
      float4 ew = ld_enc(encS, 2, c);
      float e0 = leaky(ew.x * r0[0] + ew.y * r1[0] + ew.z * r2[0] + ew.w);
      float e1 = leaky(ew.x * r0[1] + ew.y * r1[1] + ew.z * r2[1] + ew.w);
      bv[0][ks][j] = (short)f2bf(bf2f((u16)fB[0][ks][j]) * e0);
      bv[1][ks][j] = (short)f2bf(bf2f((u16)fB[1][ks][j]) * e1);
    }
  }

  // ---- GEMM2 swapped: D = vin^T . Wv^T -> lane holds v[m][s=l4*4+r] ----
#pragma unroll
  for (int mt = 0; mt < 8; ++mt) {
    f32x4 a0 = (f32x4){0.f, 0.f, 0.f, 0.f};
    f32x4 a1 = (f32x4){0.f, 0.f, 0.f, 0.f};
#pragma unroll
    for (int ks = 0; ks < 4; ++ks) {
      bf16x8 bf = *(const bf16x8*)&wvm[(mt * 16 + l15) * 128 + ks * 32 + l4 * 8];
      a0 = __builtin_amdgcn_mfma_f32_16x16x32_bf16(bv[0][ks], bf, a0, 0, 0, 0);
      a1 = __builtin_amdgcn_mfma_f32_16x16x32_bf16(bv[1][ks], bf, a1, 0, 0, 0);
    }
    const int m = mt * 16 + l15;
    float4 ew = e3S[m];                 // one ev2-param load per mt
    float acc0 = 0.0f, acc1 = 0.0f;
#pragma unroll
    for (int r = 0; r < 4; ++r) {
      float4 ra = relS[(w * 2 + 0) * 16 + l4 * 4 + r];
      float4 rb = relS[(w * 2 + 1) * 16 + l4 * 4 + r];
      float e0 = leaky(ew.x * ra.x + ew.y * ra.y + ew.z * ra.z + ew.w);
      float e1 = leaky(ew.x * rb.x + ew.y * rb.y + ew.z * rb.z + ew.w);
      acc0 += a0[r] * e0 * ra.w;        // .w carries the softmax weight
      acc1 += a1[r] * e1 * rb.w;
    }
    acc0 += __shfl_xor(acc0, 16); acc0 += __shfl_xor(acc0, 32);
    acc1 += __shfl_xor(acc1, 16); acc1 += __shfl_xor(acc1, 32);
    if (l < 16) {                       // coalesced 32B segment per (mt, pt)
      outp[(size_t)(b * NN1 + pt0) * 128 + m] =
          f2bf(acc0 + f1s[(w * 2 + 0) * 132 + m]);
      outp[(size_t)(b * NN1 + pt1) * 128 + m] =
          f2bf(acc1 + f1s[(w * 2 + 1) * 132 + m]);
    }
  }
}

// ---------------------------------------------------------------------------
// FF via MFMA: h[b][d][n] = ff_w[d,:].feat_new[b][n][:] + ff_b[d], bf16 out.
// Block = 64 points, wave = 16 points. Per-block GN partials -> pstat (f32,
// computed before the bf16 rounding).
__global__ __launch_bounds__(256)
void k_ff(const u16* __restrict__ xb, const u16* __restrict__ wfb,
          const float* __restrict__ ffb, u16* __restrict__ hout,
          float* __restrict__ pstat) {
  const int t = threadIdx.x, bx = blockIdx.x;
  const int w = t >> 6, l = t & 63, l15 = l & 15, l4 = l >> 4;
  __shared__ float bS[128];
  __shared__ float red[4][16];
  if (t < 128) bS[t] = ffb[t];
  const int pt = bx * 64 + w * 16 + l15;     // global point 0..16383
  const int b = pt >> 13, n = pt & 8191;
  const u16* row = xb + (size_t)pt * 128;
  bf16x8 bfrag[4];
#pragma unroll
  for (int ks = 0; ks < 4; ++ks)
    bfrag[ks] = *(const bf16x8*)(row + ks * 32 + l4 * 8);
  __syncthreads();
  float gs[8], gss[8];
#pragma unroll
  for (int mt = 0; mt < 8; ++mt) {
    f32x4 a = (f32x4){0.f, 0.f, 0.f, 0.f};
#pragma unroll
    for (int ks = 0; ks < 4; ++ks) {
      bf16x8 af = *(const bf16x8*)&wfb[(mt * 16 + l15) * 128 + ks * 32 + l4 * 8];
      a = __builtin_amdgcn_mfma_f32_16x16x32_bf16(af, bfrag[ks], a, 0, 0, 0);
    }
    int d0 = mt * 16 + l4 * 4;
    float s = 0.0f, ss = 0.0f;
#pragma unroll
    for (int r = 0; r < 4; ++r) {
      float h = a[r] + bS[d0 + r];
      hout[(size_t)(b * 128 + d0 + r) * 8192 + n] = f2bf(h);
      s += h; ss += h * h;
    }
    gs[mt] = s; gss[mt] = ss;
  }
#pragma unroll
  for (int mt = 0; mt < 8; ++mt) {
#pragma unroll
    for (int o = 1; o < 64; o <<= 1) {
      gs[mt] += __shfl_xor(gs[mt], o);
      gss[mt] += __shfl_xor(gss[mt], o);
    }
  }
  if (l == 0) {
#pragma unroll
    for (int mt = 0; mt < 8; ++mt) {
      red[w][mt * 2 + 0] = gs[mt];
      red[w][mt * 2 + 1] = gss[mt];
    }
  }
  __syncthreads();
  if (t < 16) {
    float tot = red[0][t] + red[1][t] + red[2][t] + red[3][t];
    pstat[bx * 16 + t] = tot;
  }
}

// Reduce pstat[256][16] -> gnf[2][8][2]. (128 blocks per batch.)
__global__ __launch_bounds__(512)
void k_ffred(const float* __restrict__ pstat, float* __restrict__ gnf) {
  __shared__ float red[512];
  int t = threadIdx.x;
  int b = t >> 8, i = t & 15, chunk = (t >> 4) & 15;
  float s = 0.0f;
#pragma unroll
  for (int k = 0; k < 8; ++k)
    s += pstat[(b * 128 + chunk * 8 + k) * 16 + i];
  red[t] = s;
  __syncthreads();
  if (chunk == 0) {
    float tot = 0.0f;
#pragma unroll
    for (int k2 = 0; k2 < 16; ++k2) tot += red[(b << 8) | (k2 << 4) | i];
    gnf[b * 16 + i] = tot;
  }
}

// Final GN + leaky + f32 store (2 elems/thread, bf16 input); also writes the
// xyz1 passthrough (blocks >= 4096).
__global__ __launch_bounds__(256)
void k_final(const u16* __restrict__ h, const float* __restrict__ gnf,
             const float* __restrict__ g, const float* __restrict__ bt,
             const float* __restrict__ xyz1, float* __restrict__ out) {
  int bx = blockIdx.x;
  if (bx >= 4096) {
    int e = (bx - 4096) * 256 + threadIdx.x;   // < BB*3*NN1 = 49152
    out[e] = xyz1[e];
    return;
  }
  int e2 = (bx * 256 + threadIdx.x) * 2;       // < BB*128*NN1 = 2097152
  int d = (e2 >> 13) & 127;
  int b = e2 >> 20;
  int gi = b * 16 + (d >> 4) * 2;
  float cnt = 16.0f * (float)NN1;
  float mu = gnf[gi] / cnt;
  float var = gnf[gi + 1] / cnt - mu * mu;
  float rs = rsqrtf(var + 1e-5f);
  u32 hw = *(const u32*)&h[e2];
  float x0 = (bflo(hw) - mu) * rs * g[d] + bt[d];
  float x1 = (bfhi(hw) - mu) * rs * g[d] + bt[d];
  float2 ov = { leaky(x0), leaky(x1) };
  *(float2*)&out[BB * 3 * NN1 + e2] = ov;
}

// ---------------------------------------------------------------------------
extern "C" void kernel_launch(void* const* d_in, const int* in_sizes, int n_in,
                              void* d_out, int out_size, void* d_ws, size_t ws_size,
                              hipStream_t stream) {
  const float* xyz1   = (const float*)d_in[0];
  const float* xyz2   = (const float*)d_in[1];
  const float* feat1  = (const float*)d_in[2];
  const float* feat2  = (const float*)d_in[3];
  const float* pos_w  = (const float*)d_in[4];
  const float* pos_b  = (const float*)d_in[5];
  const float* pos_g  = (const float*)d_in[6];
  const float* pos_bt = (const float*)d_in[7];
  const float* ek_w   = (const float*)d_in[8];
  const float* ek_b   = (const float*)d_in[9];
  const float* eq_w   = (const float*)d_in[10];
  const float* eq_b   = (const float*)d_in[11];
  const float* ev1_w  = (const float*)d_in[12];
  const float* ev1_b  = (const float*)d_in[13];
  const float* ev2_w  = (const float*)d_in[14];
  const float* ev2_b  = (const float*)d_in[15];
  const float* qk_w   = (const float*)d_in[16];
  const float* v_w    = (const float*)d_in[17];
  const float* ff_w   = (const float*)d_in[18];
  const float* ff_b   = (const float*)d_in[19];
  const float* ff_g   = (const float*)d_in[20];
  const float* ff_bt  = (const float*)d_in[21];
  (void)in_sizes; (void)n_in; (void)out_size; (void)ws_size;

  char* ws = (char*)d_ws;          // ~18.5 MB used
  u16*    f1pb     = (u16*)  (ws);                        // [B][N1][C] bf16  4194304 B
  u16*    feat2pb  = (u16*)  (ws + 4194304);              // [B][N2][C] bf16  4194304 B
  u16*    attn_out = (u16*)  (ws + 8388608);              // feat_new bf16    4194304 B
  u16*    h_ffb    = (u16*)  (ws + 12582912);             // FF out bf16      4194304 B
  int*    idxb     = (int*)  (ws + 16777216);             // [B][N1][16]      1048576 B
  u16*    wqk      = (u16*)  (ws + 17825792);             // bf16 qk_w        32768 B
  u16*    wv       = (u16*)  (ws + 17858560);             // bf16 v_w         32768 B
  u16*    wff      = (u16*)  (ws + 17891328);             // bf16 ff_w        32768 B
  float*  mom_part = (float*)(ws + 17924096);             // 128*9 floats     4608 B
  float2* gnp      = (float2*)(ws + 17928704);            // 32 float2        256 B
  float*  pstat    = (float*)(ws + 17928960);             // 256*16 floats    16384 B
  float*  gnf      = (float*)(ws + 17945344);             // 32 floats        128 B
  float4* px1      = (float4*)(ws + 17945472);            // [B][N1] packed   262144 B
  float4* px2      = (float4*)(ws + 18207616);            // [B][N2] packed   262144 B

  k_prep<<<320, 256, 0, stream>>>(qk_w, v_w, ff_w, wqk, wv, wff,
                                  xyz1, xyz2, px1, px2, mom_part);
  k_gnstats<<<1, 512, 0, stream>>>(mom_part, pos_w, pos_b, gnp);
  k_pk<<<6144, 256, 0, stream>>>(px1, px2, idxb, xyz1, xyz2, feat1, feat2,
                                 pos_w, pos_b, pos_g, pos_bt, gnp, f1pb, feat2pb);
  k_attn<<<2048, 256, 0, stream>>>(px1, px2, f1pb, feat2pb, idxb, wqk, wv,
                                   eq_w, eq_b, ek_w, ek_b, ev1_w, ev1_b, ev2_w, ev2_b,
                                   attn_out);
  k_ff<<<256, 256, 0, stream>>>(attn_out, wff, ff_b, h_ffb, pstat);
  k_ffred<<<1, 512, 0, stream>>>(pstat, gnf);
  k_final<<<4288, 256, 0, stream>>>(h_ffb, gnf, ff_g, ff_bt, xyz1, (float*)d_out);
}